// Round 9
// baseline (773.496 us; speedup 1.0000x reference)
//
#include <hip/hip_runtime.h>

#define NU 50000
#define NI 100000
#define NT 150000
#define BB 4096
#define NBUCK 147   // ceil(NT/1024)
#define BCAP 24576  // per-bucket edge capacity: mean 21504, sd ~143 -> +21 sigma
#define NCH 8       // chunks per bucket in CSR build

typedef __attribute__((ext_vector_type(8))) short bf16x8;
typedef __attribute__((ext_vector_type(4))) float f32x4;

__device__ __forceinline__ float softplusf(float x) {
  return fmaxf(x, 0.f) + log1pf(expf(-fabsf(x)));
}
__device__ __forceinline__ float wsum(float v) {
#pragma unroll
  for (int o = 32; o > 0; o >>= 1) v += __shfl_xor(v, o, 64);
  return v;
}
__device__ __forceinline__ float wmax(float v) {
#pragma unroll
  for (int o = 32; o > 0; o >>= 1) v = fmaxf(v, __shfl_xor(v, o, 64));
  return v;
}
__device__ __forceinline__ unsigned short f2b(float x) {
  unsigned u = __float_as_uint(x);
  return (unsigned short)((u + 0x7FFFu + ((u >> 16) & 1u)) >> 16);
}
__device__ __forceinline__ unsigned pack2(float lo, float hi) {
  return ((unsigned)f2b(hi) << 16) | (unsigned)f2b(lo);
}

// ---------------- CSR build ----------------
__global__ __launch_bounds__(256) void k_part(const int* __restrict__ h,
                                              const int* __restrict__ t,
                                              int* __restrict__ gcur,
                                              uint2* __restrict__ part, int E) {
  __shared__ int cnt[NBUCK];
  __shared__ int base[NBUCK];
  for (int b = threadIdx.x; b < NBUCK; b += 256) cnt[b] = 0;
  __syncthreads();
  int e0 = blockIdx.x * 4096 + threadIdx.x * 16;
  int nval = E - e0;
  nval = nval < 0 ? 0 : (nval > 16 ? 16 : nval);
  int hh[16], tt[16];
  if (nval == 16) {
    const int4* hp = (const int4*)(h + e0);
    const int4* tp = (const int4*)(t + e0);
#pragma unroll
    for (int j = 0; j < 4; j++) {
      int4 v = hp[j];
      hh[j * 4] = v.x; hh[j * 4 + 1] = v.y; hh[j * 4 + 2] = v.z; hh[j * 4 + 3] = v.w;
      int4 w = tp[j];
      tt[j * 4] = w.x; tt[j * 4 + 1] = w.y; tt[j * 4 + 2] = w.z; tt[j * 4 + 3] = w.w;
    }
  } else {
    for (int j = 0; j < nval; j++) { hh[j] = h[e0 + j]; tt[j] = t[e0 + j]; }
  }
  for (int j = 0; j < nval; j++) atomicAdd(&cnt[hh[j] >> 10], 1);
  __syncthreads();
  for (int b = threadIdx.x; b < NBUCK; b += 256) {
    int c = cnt[b];
    base[b] = c ? atomicAdd(&gcur[b], c) : 0;
    cnt[b] = 0;
  }
  __syncthreads();
  for (int j = 0; j < nval; j++) {
    int b = hh[j] >> 10;
    int r = atomicAdd(&cnt[b], 1);
    uint2 v; v.x = (unsigned)hh[j]; v.y = (unsigned)tt[j];
    part[(size_t)b * BCAP + base[b] + r] = v;
  }
}

__global__ __launch_bounds__(256) void k_count2(const uint2* __restrict__ part,
                                                const int* __restrict__ gcur,
                                                int* __restrict__ cnt_chunk) {
  __shared__ int hist[1024];
  int b = blockIdx.x, c = blockIdx.y, tid = threadIdx.x;
  for (int i = tid; i < 1024; i += 256) hist[i] = 0;
  __syncthreads();
  int m = gcur[b];
  int lo = (int)(((long long)m * c) >> 3);
  int hi = (int)(((long long)m * (c + 1)) >> 3);
  const uint2* pp = part + (size_t)b * BCAP;
  for (int i = lo + tid; i < hi; i += 256) atomicAdd(&hist[pp[i].x & 1023], 1);
  __syncthreads();
  int* dst = cnt_chunk + (((size_t)b * NCH + c) << 10);
  for (int i = tid; i < 1024; i += 256) dst[i] = hist[i];
}

__global__ __launch_bounds__(256) void k_node(int* __restrict__ cnt_chunk,
                                              int* __restrict__ rloc_g,
                                              float* __restrict__ d_inv,
                                              int* __restrict__ btot) {
  __shared__ int sd[256];
  int b = blockIdx.x, tid = threadIdx.x;
  int n0 = b << 10;
  int pd[4];
  int s = 0;
#pragma unroll
  for (int j = 0; j < 4; j++) {
    int idx = tid * 4 + j;
    int run = 0;
#pragma unroll
    for (int c = 0; c < NCH; c++) {
      size_t a = (((size_t)b * NCH + c) << 10) + idx;
      int v = cnt_chunk[a];
      cnt_chunk[a] = run;
      run += v;
    }
    int n = n0 + idx;
    if (n < NT) {
      d_inv[n] = 1.0f / sqrtf((float)run);  // deg >= 1 (self-loop)
      pd[j] = (run + 15) & ~15;
    } else pd[j] = 0;
    s += pd[j];
  }
  sd[tid] = s;
  __syncthreads();
  for (int o = 1; o < 256; o <<= 1) {
    int x = (tid >= o) ? sd[tid - o] : 0;
    __syncthreads();
    sd[tid] += x;
    __syncthreads();
  }
  int run2 = sd[tid] - s;
#pragma unroll
  for (int j = 0; j < 4; j++) {
    int idx = tid * 4 + j, n = n0 + idx;
    if (n < NT) rloc_g[n] = run2;
    run2 += pd[j];
  }
  if (tid == 255) btot[b] = sd[255];
}

__global__ void k_csr_base(const int* __restrict__ btot, int* __restrict__ bbase,
                           int* __restrict__ row_ptr) {
  __shared__ int sd[256];
  int t = threadIdx.x;
  int v = (t < NBUCK) ? btot[t] : 0;
  sd[t] = v;
  __syncthreads();
  for (int o = 1; o < 256; o <<= 1) {
    int x = (t >= o) ? sd[t - o] : 0;
    __syncthreads();
    sd[t] += x;
    __syncthreads();
  }
  if (t < NBUCK) bbase[t] = sd[t] - v;
  if (t == NBUCK - 1) row_ptr[NT] = sd[t];
}

__global__ void k_rowptr(const int* __restrict__ bbase, const int* __restrict__ rloc_g,
                         int* __restrict__ row_ptr) {
  int n = blockIdx.x * 256 + threadIdx.x;
  if (n < NT) row_ptr[n] = bbase[n >> 10] + rloc_g[n];
}

__global__ __launch_bounds__(256) void k_fill2(const uint2* __restrict__ part,
                                               const int* __restrict__ gcur,
                                               const int* __restrict__ chunkpre,
                                               const int* __restrict__ row_ptr,
                                               const float* __restrict__ d_inv,
                                               uint2* __restrict__ edges) {
  __shared__ int curs[1024];
  __shared__ float dl[1024];
  int b = blockIdx.x, c = blockIdx.y, tid = threadIdx.x;
  int n0 = b << 10;
  const int* pre = chunkpre + (((size_t)b * NCH + c) << 10);
  for (int i = tid; i < 1024; i += 256) {
    int n = n0 + i;
    if (n < NT) {
      curs[i] = row_ptr[n] + pre[i];
      dl[i] = d_inv[n];
    }
  }
  __syncthreads();
  int m = gcur[b];
  int lo = (int)(((long long)m * c) >> 3);
  int hi = (int)(((long long)m * (c + 1)) >> 3);
  const uint2* pp = part + (size_t)b * BCAP;
  for (int i = lo + tid; i < hi; i += 256) {
    uint2 pe = pp[i];
    int slot = atomicAdd(&curs[pe.x & 1023], 1);
    float g = dl[pe.x & 1023] * d_inv[pe.y];
    uint2 v; v.x = pe.y; v.y = __float_as_uint(g);
    edges[slot] = v;
  }
}

// ---------------- propagation ----------------
// cur/nxt rows: 64 bf16 dims packed as 32 uints (dims 2l,2l+1 in uint l).
__global__ void k_init(const float2* __restrict__ ue, const float2* __restrict__ ie,
                       unsigned* __restrict__ cur, int nU2, int nTot2) {
  int i = blockIdx.x * 256 + threadIdx.x;
  if (i >= nTot2) return;
  float2 v = (i < nU2) ? ue[i] : ie[i - nU2];
  cur[i] = pack2(v.x, v.y);
}

// wave = 2 half-waves; each half-wave serves one edge (128B bf16 row).
// Edge lists padded to x16 with (idx=0, g=0) -> branchless.
// NOTE: flat named registers only — register ARRAYS in this loop get spilled
// to scratch (round 7: 2.18 GB HBM writes, 3.2x regression).
__global__ __launch_bounds__(256) void k_agg(const int* __restrict__ row_ptr,
                                             const uint2* __restrict__ edges,
                                             const unsigned* __restrict__ cur,
                                             unsigned* __restrict__ nxt,
                                             float2* __restrict__ acc,
                                             const float2* __restrict__ egoU,
                                             const float2* __restrict__ egoI,
                                             int first) {
  int node = (blockIdx.x << 2) + (threadIdx.x >> 6);
  unsigned lane = threadIdx.x & 63;
  unsigned l32 = lane & 31;
  unsigned half = lane >> 5;
  int s = row_ptr[node], e = row_ptr[node + 1];
  float s0 = 0.f, s1 = 0.f;
  for (int i = s; i < e; i += 16) {
    const uint4* e4 = (const uint4*)(edges + i);
    uint4 A = e4[0], B = e4[1], C = e4[2], D = e4[3];
    uint4 F = e4[4], G = e4[5], H = e4[6], I = e4[7];
    unsigned i0 = half ? A.z : A.x; float g0 = __uint_as_float(half ? A.w : A.y);
    unsigned i1 = half ? B.z : B.x; float g1 = __uint_as_float(half ? B.w : B.y);
    unsigned i2 = half ? C.z : C.x; float g2 = __uint_as_float(half ? C.w : C.y);
    unsigned i3 = half ? D.z : D.x; float g3 = __uint_as_float(half ? D.w : D.y);
    unsigned i4 = half ? F.z : F.x; float g4 = __uint_as_float(half ? F.w : F.y);
    unsigned i5 = half ? G.z : G.x; float g5 = __uint_as_float(half ? G.w : G.y);
    unsigned i6 = half ? H.z : H.x; float g6 = __uint_as_float(half ? H.w : H.y);
    unsigned i7 = half ? I.z : I.x; float g7 = __uint_as_float(half ? I.w : I.y);
    unsigned v0 = cur[(i0 << 5) + l32];
    unsigned v1 = cur[(i1 << 5) + l32];
    unsigned v2 = cur[(i2 << 5) + l32];
    unsigned v3 = cur[(i3 << 5) + l32];
    unsigned v4 = cur[(i4 << 5) + l32];
    unsigned v5 = cur[(i5 << 5) + l32];
    unsigned v6 = cur[(i6 << 5) + l32];
    unsigned v7 = cur[(i7 << 5) + l32];
    s0 = fmaf(g0, __uint_as_float(v0 << 16), s0);
    s1 = fmaf(g0, __uint_as_float(v0 & 0xffff0000u), s1);
    s0 = fmaf(g1, __uint_as_float(v1 << 16), s0);
    s1 = fmaf(g1, __uint_as_float(v1 & 0xffff0000u), s1);
    s0 = fmaf(g2, __uint_as_float(v2 << 16), s0);
    s1 = fmaf(g2, __uint_as_float(v2 & 0xffff0000u), s1);
    s0 = fmaf(g3, __uint_as_float(v3 << 16), s0);
    s1 = fmaf(g3, __uint_as_float(v3 & 0xffff0000u), s1);
    s0 = fmaf(g4, __uint_as_float(v4 << 16), s0);
    s1 = fmaf(g4, __uint_as_float(v4 & 0xffff0000u), s1);
    s0 = fmaf(g5, __uint_as_float(v5 << 16), s0);
    s1 = fmaf(g5, __uint_as_float(v5 & 0xffff0000u), s1);
    s0 = fmaf(g6, __uint_as_float(v6 << 16), s0);
    s1 = fmaf(g6, __uint_as_float(v6 & 0xffff0000u), s1);
    s0 = fmaf(g7, __uint_as_float(v7 << 16), s0);
    s1 = fmaf(g7, __uint_as_float(v7 & 0xffff0000u), s1);
  }
  // combine the two half-waves (same dims, different edge subsets)
  s0 += __shfl_xor(s0, 32, 64);
  s1 += __shfl_xor(s1, 32, 64);
  unsigned ro = ((unsigned)node << 5) + l32;
  if (half == 0) {
    float2 base;
    if (first) {
      base = (node < NU) ? egoU[ro] : egoI[ro - (unsigned)NU * 32u];
    } else {
      base = acc[ro];
    }
    base.x += s0;
    base.y += s1;
    acc[ro] = base;
  } else {
    nxt[ro] = pack2(s0, s1);
  }
}

// ---------------- losses ----------------
// lw hoisted to 32 per-lane registers (constant-indexed unroll -> no spill);
// grid 2048 blocks (512 gave 19% occupancy -> 122 us, round 8 profile).
__global__ __launch_bounds__(256) void k_kl(const float* __restrict__ acc,
                                            const float* __restrict__ lin_w,
                                            const float* __restrict__ lin_b,
                                            double* __restrict__ accums) {
  int lane = threadIdx.x & 63;
  float w[32];
#pragma unroll
  for (int j = 0; j < 32; j++) w[j] = lin_w[lane * 32 + j];
  float lbv = lin_b[lane] + 1e-8f;
  int wv = (blockIdx.x * 256 + threadIdx.x) >> 6;
  int nw = (gridDim.x * 256) >> 6;
  double dsum = 0.0;
  for (int row = wv; row < NT; row += nw) {
    float m = acc[row * 64 + lane];
    float sp = softplusf(m);
    float sd = lbv;
#pragma unroll
    for (int j = 0; j < 32; j++) sd = fmaf(__shfl(sp, j, 64), w[j], sd);
    float e2 = expf(2.f * sd);
    float kl = -0.5f * (1.f + 2.f * sd - m * m - e2);
    if (!isfinite(kl)) kl = 0.f;
    float rs = wsum(kl);
    if (lane == 0) dsum += (double)rs;
  }
  if (lane == 0) atomicAdd(&accums[1], dsum);
}

__global__ __launch_bounds__(256) void k_batch_user(
    const float* __restrict__ acc, const float* __restrict__ user_emb,
    const float* __restrict__ eps, const float* __restrict__ intent,
    const float* __restrict__ lin_w, const float* __restrict__ lin_b,
    const int* __restrict__ users, const int* __restrict__ pos_items,
    const int* __restrict__ neg_items,
    float* __restrict__ gen_o, float* __restrict__ int_o,
    unsigned short* __restrict__ gen_b, unsigned short* __restrict__ int_b,
    double* __restrict__ accums) {
  __shared__ float ui[64 * 130];
  __shared__ float lw[64 * 33];
  __shared__ float lb[64];
  __shared__ double red[8];
  for (int i = threadIdx.x; i < 64 * 128; i += 256) ui[(i >> 7) * 130 + (i & 127)] = intent[i];
  for (int i = threadIdx.x; i < 64 * 32; i += 256) lw[(i >> 5) * 33 + (i & 31)] = lin_w[i];
  if (threadIdx.x < 64) lb[threadIdx.x] = lin_b[threadIdx.x];
  __syncthreads();
  int lane = threadIdx.x & 63;
  int wid = threadIdx.x >> 6;
  int b = (blockIdx.x << 2) + wid;
  int u = users[b];
  float m = acc[u * 64 + lane];
  int k0 = lane * 2;
  float l0 = 0.f, l1 = 0.f;
  for (int d = 0; d < 64; d++) {
    float md = __shfl(m, d, 64);
    l0 = fmaf(md, ui[d * 130 + k0], l0);
    l1 = fmaf(md, ui[d * 130 + k0 + 1], l1);
  }
  float mx = wmax(fmaxf(l0, l1));
  float p0 = expf(l0 - mx), p1 = expf(l1 - mx);
  float tot = wsum(p0 + p1);
  p0 /= tot; p1 /= tot;
  float s = 0.f;
  for (int k = 0; k < 128; k++) {
    float pk = __shfl((k & 1) ? p1 : p0, k >> 1, 64);
    s = fmaf(pk, ui[lane * 130 + k], s);
  }
  float nrm = sqrtf(wsum(s * s));
  float io = s / nrm;
  int_o[b * 64 + lane] = io;
  int_b[b * 64 + lane] = f2b(io);
  float sp = softplusf(m);
  float sd = lb[lane] + 1e-8f;
#pragma unroll
  for (int j = 0; j < 32; j++) sd = fmaf(__shfl(sp, j, 64), lw[lane * 33 + j], sd);
  float ge = m + eps[u * 64 + lane] * sd;
  float gn = sqrtf(wsum(ge * ge));
  float go = ge / gn;
  gen_o[b * 64 + lane] = go;
  gen_b[b * 64 + lane] = f2b(go);
  int pi = pos_items[b], ni = neg_items[b];
  float pv = acc[(NU + pi) * 64 + lane];
  float nv = acc[(NU + ni) * 64 + lane];
  float ps = wsum(m * pv);
  float ns = wsum(m * nv);
  float bpr = softplusf(ns - ps);
  float ue = user_emb[u * 64 + lane];
  float es = wsum(ue * ue);
  if (lane == 0) { red[wid] = (double)bpr; red[4 + wid] = (double)es; }
  __syncthreads();
  if (threadIdx.x == 0) {
    atomicAdd(&accums[0], red[0] + red[1] + red[2] + red[3]);
    atomicAdd(&accums[2], red[4] + red[5] + red[6] + red[7]);
  }
}

__global__ __launch_bounds__(256) void k_batch_item(
    const float* __restrict__ acc, const float* __restrict__ item_emb,
    const float* __restrict__ eps, const float* __restrict__ intent,
    const float* __restrict__ lin_w, const float* __restrict__ lin_b,
    const int* __restrict__ pos_items, const int* __restrict__ neg_items,
    float* __restrict__ gen_o, float* __restrict__ int_o,
    unsigned short* __restrict__ gen_b, unsigned short* __restrict__ int_b,
    double* __restrict__ accums) {
  __shared__ float ui[64 * 130];
  __shared__ float lw[64 * 33];
  __shared__ float lb[64];
  __shared__ double red[4];
  for (int i = threadIdx.x; i < 64 * 128; i += 256) ui[(i >> 7) * 130 + (i & 127)] = intent[i];
  for (int i = threadIdx.x; i < 64 * 32; i += 256) lw[(i >> 5) * 33 + (i & 31)] = lin_w[i];
  if (threadIdx.x < 64) lb[threadIdx.x] = lin_b[threadIdx.x];
  __syncthreads();
  int lane = threadIdx.x & 63;
  int wid = threadIdx.x >> 6;
  int b = (blockIdx.x << 2) + wid;
  int pi = pos_items[b], ni = neg_items[b];
  int row = NU + pi;
  float m = acc[row * 64 + lane];
  int k0 = lane * 2;
  float l0 = 0.f, l1 = 0.f;
  for (int d = 0; d < 64; d++) {
    float md = __shfl(m, d, 64);
    l0 = fmaf(md, ui[d * 130 + k0], l0);
    l1 = fmaf(md, ui[d * 130 + k0 + 1], l1);
  }
  float mx = wmax(fmaxf(l0, l1));
  float p0 = expf(l0 - mx), p1 = expf(l1 - mx);
  float tot = wsum(p0 + p1);
  p0 /= tot; p1 /= tot;
  float s = 0.f;
  for (int k = 0; k < 128; k++) {
    float pk = __shfl((k & 1) ? p1 : p0, k >> 1, 64);
    s = fmaf(pk, ui[lane * 130 + k], s);
  }
  float nrm = sqrtf(wsum(s * s));
  float io = s / nrm;
  int_o[b * 64 + lane] = io;
  int_b[b * 64 + lane] = f2b(io);
  float sp = softplusf(m);
  float sd = lb[lane] + 1e-8f;
#pragma unroll
  for (int j = 0; j < 32; j++) sd = fmaf(__shfl(sp, j, 64), lw[lane * 33 + j], sd);
  float ge = m + eps[row * 64 + lane] * sd;
  float gn = sqrtf(wsum(ge * ge));
  float go = ge / gn;
  gen_o[b * 64 + lane] = go;
  gen_b[b * 64 + lane] = f2b(go);
  float a0 = item_emb[pi * 64 + lane];
  float a1 = item_emb[ni * 64 + lane];
  float es = wsum(a0 * a0 + a1 * a1);
  if (lane == 0) red[wid] = (double)es;
  __syncthreads();
  if (threadIdx.x == 0) atomicAdd(&accums[2], red[0] + red[1] + red[2] + red[3]);
}

__global__ void k_int(const float* __restrict__ ui, const float* __restrict__ ii,
                      double* __restrict__ accums) {
  float s = 0.f;
  for (int i = threadIdx.x; i < 64 * 128; i += 256) {
    float a = ui[i], b = ii[i];
    s = fmaf(a, a, s);
    s = fmaf(b, b, s);
  }
  s = wsum(s);
  __shared__ float red[4];
  if ((threadIdx.x & 63) == 0) red[threadIdx.x >> 6] = s;
  __syncthreads();
  if (threadIdx.x == 0) atomicAdd(&accums[3], (double)(red[0] + red[1] + red[2] + red[3]));
}

// ---------------- InfoNCE negatives via bf16 MFMA ----------------
__global__ __launch_bounds__(256) void k_nce_mfma(
    const unsigned short* __restrict__ e1u, const unsigned short* __restrict__ e2u,
    const unsigned short* __restrict__ e1i, const unsigned short* __restrict__ e2i,
    float* __restrict__ negu, float* __restrict__ negi) {
  int pair = blockIdx.y >> 2, jq = blockIdx.y & 3;
  const unsigned short* e1 = pair ? e1i : e1u;
  const unsigned short* e2 = pair ? e2i : e2u;
  float* nego = pair ? negi : negu;
  int wid = threadIdx.x >> 6, lane = threadIdx.x & 63;
  int q = lane >> 4, n = lane & 15;
  int i0 = blockIdx.x * 64 + wid * 16;
  const bf16x8* arow = (const bf16x8*)(e1 + (size_t)(i0 + n) * 64 + q * 8);
  bf16x8 a0 = arow[0];
  bf16x8 a1 = arow[4];
  f32x4 accv = {0.f, 0.f, 0.f, 0.f};
  int j0 = jq * 1024;
  for (int jt = 0; jt < 64; jt++) {
    const bf16x8* brow = (const bf16x8*)(e2 + (size_t)(j0 + jt * 16 + n) * 64 + q * 8);
    bf16x8 b0 = brow[0];
    bf16x8 b1 = brow[4];
    f32x4 c = {0.f, 0.f, 0.f, 0.f};
    c = __builtin_amdgcn_mfma_f32_16x16x32_bf16(a0, b0, c, 0, 0, 0);
    c = __builtin_amdgcn_mfma_f32_16x16x32_bf16(a1, b1, c, 0, 0, 0);
#pragma unroll
    for (int r = 0; r < 4; r++) accv[r] += __expf(5.0f * c[r]);
  }
#pragma unroll
  for (int o = 1; o < 16; o <<= 1) {
#pragma unroll
    for (int r = 0; r < 4; r++) accv[r] += __shfl_xor(accv[r], o, 64);
  }
  if (n == 0) {
#pragma unroll
    for (int r = 0; r < 4; r++) atomicAdd(&nego[i0 + q * 4 + r], accv[r]);
  }
}

__global__ __launch_bounds__(256) void k_nce_final(
    const float* __restrict__ ugen, const float* __restrict__ uio,
    const float* __restrict__ igen, const float* __restrict__ iio,
    const float* __restrict__ negu, const float* __restrict__ negi,
    double* __restrict__ accums) {
  __shared__ double red[4];
  int lane = threadIdx.x & 63, wid = threadIdx.x >> 6;
  int w = blockIdx.x * 4 + wid;
  int pair = w >> 12, i = w & 4095;
  const float* e1 = pair ? igen : ugen;
  const float* e2 = pair ? iio : uio;
  const float* ng = pair ? negi : negu;
  float dot = wsum(e1[i * 64 + lane] * e2[i * 64 + lane]);
  if (lane == 0) {
    float pos = expf(dot * 5.f);
    red[wid] = (double)(-logf(pos / (ng[i] + 1e-8f) + 1e-8f));
  }
  __syncthreads();
  if (threadIdx.x == 0) atomicAdd(&accums[4], red[0] + red[1] + red[2] + red[3]);
}

__global__ void k_fin(const double* __restrict__ accums, float* __restrict__ out) {
  if (threadIdx.x == 0 && blockIdx.x == 0) {
    double bpr = accums[0] / (double)BB;
    double kl = 0.01 * accums[1] / (double)NT;
    out[0] = (float)(bpr + kl);
    out[1] = (float)(0.1 * accums[4] / (double)BB);
    out[2] = (float)(1e-5 * accums[2]);
    out[3] = (float)(1e-5 * accums[3]);
  }
}

extern "C" void kernel_launch(void* const* d_in, const int* in_sizes, int n_in,
                              void* d_out, int out_size, void* d_ws, size_t ws_size,
                              hipStream_t stream) {
  const float* user_emb = (const float*)d_in[0];
  const float* item_emb = (const float*)d_in[1];
  const float* user_int = (const float*)d_in[2];
  const float* item_int = (const float*)d_in[3];
  const float* lin_w = (const float*)d_in[4];
  const float* lin_b = (const float*)d_in[5];
  const float* eps = (const float*)d_in[6];
  const int* h_list = (const int*)d_in[7];
  const int* t_list = (const int*)d_in[8];
  const int* users = (const int*)d_in[9];
  const int* pos_items = (const int*)d_in[10];
  const int* neg_items = (const int*)d_in[11];
  float* out = (float*)d_out;
  const int E = in_sizes[7];
  const size_t Ecap = (size_t)E + 16 * (size_t)NT;  // x16-padded capacity

  char* ws = (char*)d_ws;
  size_t off = 0;
  auto take = [&](size_t bytes) -> char* {
    char* p = ws + off;
    off = (off + bytes + 255) & ~(size_t)255;
    return p;
  };
  int* row_ptr = (int*)take((size_t)(NT + 1) * 4);
  float* d_inv = (float*)take((size_t)NT * 4);
  int* rloc_g = (int*)take((size_t)NT * 4);
  int* cnt_chunk = (int*)take((size_t)NBUCK * NCH * 1024 * 4);
  int* gcur = (int*)take(NBUCK * 4);
  int* btot = (int*)take(NBUCK * 4);
  int* bbase = (int*)take(NBUCK * 4);
  uint2* edges = (uint2*)take(Ecap * 8);
  unsigned* bufA = (unsigned*)take((size_t)NT * 32 * 4);  // bf16-packed rows
  unsigned* bufB = (unsigned*)take((size_t)NT * 32 * 4);  // contiguous after bufA
  float* acc = (float*)take((size_t)NT * 64 * 4);
  float* ugen = (float*)take((size_t)BB * 64 * 4);
  float* igen = (float*)take((size_t)BB * 64 * 4);
  float* uio = (float*)take((size_t)BB * 64 * 4);
  float* iio = (float*)take((size_t)BB * 64 * 4);
  unsigned short* ugen_b = (unsigned short*)take((size_t)BB * 64 * 2);
  unsigned short* igen_b = (unsigned short*)take((size_t)BB * 64 * 2);
  unsigned short* uio_b = (unsigned short*)take((size_t)BB * 64 * 2);
  unsigned short* iio_b = (unsigned short*)take((size_t)BB * 64 * 2);
  float* negu = (float*)take((size_t)BB * 4);
  float* negi = (float*)take((size_t)BB * 4);
  double* accums = (double*)take(64);
  if (off > ws_size) return;
  // part[] (NBUCK*BCAP uint2 = 28.9MB) aliases bufA+bufB (38.4MB contiguous):
  // last read in k_fill2; bufA first written by k_init (after), bufB by k_agg#1.
  uint2* part = (uint2*)bufA;

  hipMemsetAsync(gcur, 0, NBUCK * 4, stream);
  hipMemsetAsync(edges, 0, Ecap * 8, stream);  // pad slots: idx 0, g = 0
  hipMemsetAsync(negu, 0, (size_t)BB * 4, stream);
  hipMemsetAsync(negi, 0, (size_t)BB * 4, stream);
  hipMemsetAsync(accums, 0, 64, stream);

  int gridP = (E + 4095) / 4096;
  k_part<<<gridP, 256, 0, stream>>>(h_list, t_list, gcur, part, E);
  k_count2<<<dim3(NBUCK, NCH), 256, 0, stream>>>(part, gcur, cnt_chunk);
  k_node<<<NBUCK, 256, 0, stream>>>(cnt_chunk, rloc_g, d_inv, btot);
  k_csr_base<<<1, 256, 0, stream>>>(btot, bbase, row_ptr);
  k_rowptr<<<(NT + 255) / 256, 256, 0, stream>>>(bbase, rloc_g, row_ptr);
  k_fill2<<<dim3(NBUCK, NCH), 256, 0, stream>>>(part, gcur, cnt_chunk, row_ptr,
                                                d_inv, edges);

  int nU2 = NU * 32, nTot2 = NT * 32;
  k_init<<<(nTot2 + 255) / 256, 256, 0, stream>>>((const float2*)user_emb,
                                                  (const float2*)item_emb, bufA, nU2, nTot2);
  int gridAgg = NT / 4;
  k_agg<<<gridAgg, 256, 0, stream>>>(row_ptr, edges, bufA, bufB, (float2*)acc,
                                     (const float2*)user_emb, (const float2*)item_emb, 1);
  k_agg<<<gridAgg, 256, 0, stream>>>(row_ptr, edges, bufB, bufA, (float2*)acc,
                                     (const float2*)user_emb, (const float2*)item_emb, 0);
  k_agg<<<gridAgg, 256, 0, stream>>>(row_ptr, edges, bufA, bufB, (float2*)acc,
                                     (const float2*)user_emb, (const float2*)item_emb, 0);

  k_kl<<<2048, 256, 0, stream>>>(acc, lin_w, lin_b, accums);
  k_batch_user<<<BB / 4, 256, 0, stream>>>(acc, user_emb, eps, user_int, lin_w, lin_b,
                                           users, pos_items, neg_items,
                                           ugen, uio, ugen_b, uio_b, accums);
  k_batch_item<<<BB / 4, 256, 0, stream>>>(acc, item_emb, eps, item_int, lin_w, lin_b,
                                           pos_items, neg_items,
                                           igen, iio, igen_b, iio_b, accums);
  k_int<<<1, 256, 0, stream>>>(user_int, item_int, accums);
  k_nce_mfma<<<dim3(64, 8), 256, 0, stream>>>(ugen_b, uio_b, igen_b, iio_b, negu, negi);
  k_nce_final<<<(2 * BB) / 4, 256, 0, stream>>>(ugen, uio, igen, iio, negu, negi, accums);
  k_fin<<<1, 64, 0, stream>>>(accums, out);
}

// Round 10
// 766.372 us; speedup vs baseline: 1.0093x; 1.0093x over previous
//
#include <hip/hip_runtime.h>

#define NU 50000
#define NI 100000
#define NT 150000
#define BB 4096
#define NBUCK 147   // ceil(NT/1024)
#define BCAP 24576  // per-bucket edge capacity: mean 21504, sd ~143 -> +21 sigma
#define NCH 8       // chunks per bucket in CSR build

typedef __attribute__((ext_vector_type(8))) short bf16x8;
typedef __attribute__((ext_vector_type(4))) float f32x4;

__device__ __forceinline__ float softplusf(float x) {
  return fmaxf(x, 0.f) + log1pf(expf(-fabsf(x)));
}
__device__ __forceinline__ float wsum(float v) {
#pragma unroll
  for (int o = 32; o > 0; o >>= 1) v += __shfl_xor(v, o, 64);
  return v;
}
__device__ __forceinline__ float wmax(float v) {
#pragma unroll
  for (int o = 32; o > 0; o >>= 1) v = fmaxf(v, __shfl_xor(v, o, 64));
  return v;
}
__device__ __forceinline__ unsigned short f2b(float x) {
  unsigned u = __float_as_uint(x);
  return (unsigned short)((u + 0x7FFFu + ((u >> 16) & 1u)) >> 16);
}
__device__ __forceinline__ unsigned pack2(float lo, float hi) {
  return ((unsigned)f2b(hi) << 16) | (unsigned)f2b(lo);
}

// ---------------- CSR build ----------------
__global__ __launch_bounds__(256) void k_part(const int* __restrict__ h,
                                              const int* __restrict__ t,
                                              int* __restrict__ gcur,
                                              uint2* __restrict__ part, int E) {
  __shared__ int cnt[NBUCK];
  __shared__ int base[NBUCK];
  for (int b = threadIdx.x; b < NBUCK; b += 256) cnt[b] = 0;
  __syncthreads();
  int e0 = blockIdx.x * 4096 + threadIdx.x * 16;
  int nval = E - e0;
  nval = nval < 0 ? 0 : (nval > 16 ? 16 : nval);
  int hh[16], tt[16];
  if (nval == 16) {
    const int4* hp = (const int4*)(h + e0);
    const int4* tp = (const int4*)(t + e0);
#pragma unroll
    for (int j = 0; j < 4; j++) {
      int4 v = hp[j];
      hh[j * 4] = v.x; hh[j * 4 + 1] = v.y; hh[j * 4 + 2] = v.z; hh[j * 4 + 3] = v.w;
      int4 w = tp[j];
      tt[j * 4] = w.x; tt[j * 4 + 1] = w.y; tt[j * 4 + 2] = w.z; tt[j * 4 + 3] = w.w;
    }
  } else {
    for (int j = 0; j < nval; j++) { hh[j] = h[e0 + j]; tt[j] = t[e0 + j]; }
  }
  for (int j = 0; j < nval; j++) atomicAdd(&cnt[hh[j] >> 10], 1);
  __syncthreads();
  for (int b = threadIdx.x; b < NBUCK; b += 256) {
    int c = cnt[b];
    base[b] = c ? atomicAdd(&gcur[b], c) : 0;
    cnt[b] = 0;
  }
  __syncthreads();
  for (int j = 0; j < nval; j++) {
    int b = hh[j] >> 10;
    int r = atomicAdd(&cnt[b], 1);
    uint2 v; v.x = (unsigned)hh[j]; v.y = (unsigned)tt[j];
    part[(size_t)b * BCAP + base[b] + r] = v;
  }
}

__global__ __launch_bounds__(256) void k_count2(const uint2* __restrict__ part,
                                                const int* __restrict__ gcur,
                                                int* __restrict__ cnt_chunk) {
  __shared__ int hist[1024];
  int b = blockIdx.x, c = blockIdx.y, tid = threadIdx.x;
  for (int i = tid; i < 1024; i += 256) hist[i] = 0;
  __syncthreads();
  int m = gcur[b];
  int lo = (int)(((long long)m * c) >> 3);
  int hi = (int)(((long long)m * (c + 1)) >> 3);
  const uint2* pp = part + (size_t)b * BCAP;
  for (int i = lo + tid; i < hi; i += 256) atomicAdd(&hist[pp[i].x & 1023], 1);
  __syncthreads();
  int* dst = cnt_chunk + (((size_t)b * NCH + c) << 10);
  for (int i = tid; i < 1024; i += 256) dst[i] = hist[i];
}

__global__ __launch_bounds__(256) void k_node(int* __restrict__ cnt_chunk,
                                              int* __restrict__ rloc_g,
                                              float* __restrict__ d_inv,
                                              int* __restrict__ btot) {
  __shared__ int sd[256];
  int b = blockIdx.x, tid = threadIdx.x;
  int n0 = b << 10;
  int pd[4];
  int s = 0;
#pragma unroll
  for (int j = 0; j < 4; j++) {
    int idx = tid * 4 + j;
    int run = 0;
#pragma unroll
    for (int c = 0; c < NCH; c++) {
      size_t a = (((size_t)b * NCH + c) << 10) + idx;
      int v = cnt_chunk[a];
      cnt_chunk[a] = run;
      run += v;
    }
    int n = n0 + idx;
    if (n < NT) {
      d_inv[n] = 1.0f / sqrtf((float)run);  // deg >= 1 (self-loop)
      pd[j] = (run + 15) & ~15;
    } else pd[j] = 0;
    s += pd[j];
  }
  sd[tid] = s;
  __syncthreads();
  for (int o = 1; o < 256; o <<= 1) {
    int x = (tid >= o) ? sd[tid - o] : 0;
    __syncthreads();
    sd[tid] += x;
    __syncthreads();
  }
  int run2 = sd[tid] - s;
#pragma unroll
  for (int j = 0; j < 4; j++) {
    int idx = tid * 4 + j, n = n0 + idx;
    if (n < NT) rloc_g[n] = run2;
    run2 += pd[j];
  }
  if (tid == 255) btot[b] = sd[255];
}

__global__ void k_csr_base(const int* __restrict__ btot, int* __restrict__ bbase,
                           int* __restrict__ row_ptr) {
  __shared__ int sd[256];
  int t = threadIdx.x;
  int v = (t < NBUCK) ? btot[t] : 0;
  sd[t] = v;
  __syncthreads();
  for (int o = 1; o < 256; o <<= 1) {
    int x = (t >= o) ? sd[t - o] : 0;
    __syncthreads();
    sd[t] += x;
    __syncthreads();
  }
  if (t < NBUCK) bbase[t] = sd[t] - v;
  if (t == NBUCK - 1) row_ptr[NT] = sd[t];
}

__global__ void k_rowptr(const int* __restrict__ bbase, const int* __restrict__ rloc_g,
                         int* __restrict__ row_ptr) {
  int n = blockIdx.x * 256 + threadIdx.x;
  if (n < NT) row_ptr[n] = bbase[n >> 10] + rloc_g[n];
}

__global__ __launch_bounds__(256) void k_fill2(const uint2* __restrict__ part,
                                               const int* __restrict__ gcur,
                                               const int* __restrict__ chunkpre,
                                               const int* __restrict__ row_ptr,
                                               const float* __restrict__ d_inv,
                                               uint2* __restrict__ edges) {
  __shared__ int curs[1024];
  __shared__ float dl[1024];
  int b = blockIdx.x, c = blockIdx.y, tid = threadIdx.x;
  int n0 = b << 10;
  const int* pre = chunkpre + (((size_t)b * NCH + c) << 10);
  for (int i = tid; i < 1024; i += 256) {
    int n = n0 + i;
    if (n < NT) {
      curs[i] = row_ptr[n] + pre[i];
      dl[i] = d_inv[n];
    }
  }
  __syncthreads();
  int m = gcur[b];
  int lo = (int)(((long long)m * c) >> 3);
  int hi = (int)(((long long)m * (c + 1)) >> 3);
  const uint2* pp = part + (size_t)b * BCAP;
  for (int i = lo + tid; i < hi; i += 256) {
    uint2 pe = pp[i];
    int slot = atomicAdd(&curs[pe.x & 1023], 1);
    float g = dl[pe.x & 1023] * d_inv[pe.y];
    uint2 v; v.x = pe.y; v.y = __float_as_uint(g);
    edges[slot] = v;
  }
}

// ---------------- propagation ----------------
// cur/nxt rows: 64 bf16 dims packed as 32 uints (dims 2l,2l+1 in uint l).
__global__ void k_init(const float2* __restrict__ ue, const float2* __restrict__ ie,
                       unsigned* __restrict__ cur, int nU2, int nTot2) {
  int i = blockIdx.x * 256 + threadIdx.x;
  if (i >= nTot2) return;
  float2 v = (i < nU2) ? ue[i] : ie[i - nU2];
  cur[i] = pack2(v.x, v.y);
}

// wave = 2 half-waves; each half-wave serves one edge (128B bf16 row).
// Edge lists padded to x16 with (idx=0, g=0) -> branchless.
// NOTE: flat named registers only — register ARRAYS in this loop get spilled
// to scratch (round 7: 2.18 GB HBM writes, 3.2x regression).
__global__ __launch_bounds__(256) void k_agg(const int* __restrict__ row_ptr,
                                             const uint2* __restrict__ edges,
                                             const unsigned* __restrict__ cur,
                                             unsigned* __restrict__ nxt,
                                             float2* __restrict__ acc,
                                             const float2* __restrict__ egoU,
                                             const float2* __restrict__ egoI,
                                             int first) {
  int node = (blockIdx.x << 2) + (threadIdx.x >> 6);
  unsigned lane = threadIdx.x & 63;
  unsigned l32 = lane & 31;
  unsigned half = lane >> 5;
  int s = row_ptr[node], e = row_ptr[node + 1];
  float s0 = 0.f, s1 = 0.f;
  for (int i = s; i < e; i += 16) {
    const uint4* e4 = (const uint4*)(edges + i);
    uint4 A = e4[0], B = e4[1], C = e4[2], D = e4[3];
    uint4 F = e4[4], G = e4[5], H = e4[6], I = e4[7];
    unsigned i0 = half ? A.z : A.x; float g0 = __uint_as_float(half ? A.w : A.y);
    unsigned i1 = half ? B.z : B.x; float g1 = __uint_as_float(half ? B.w : B.y);
    unsigned i2 = half ? C.z : C.x; float g2 = __uint_as_float(half ? C.w : C.y);
    unsigned i3 = half ? D.z : D.x; float g3 = __uint_as_float(half ? D.w : D.y);
    unsigned i4 = half ? F.z : F.x; float g4 = __uint_as_float(half ? F.w : F.y);
    unsigned i5 = half ? G.z : G.x; float g5 = __uint_as_float(half ? G.w : G.y);
    unsigned i6 = half ? H.z : H.x; float g6 = __uint_as_float(half ? H.w : H.y);
    unsigned i7 = half ? I.z : I.x; float g7 = __uint_as_float(half ? I.w : I.y);
    unsigned v0 = cur[(i0 << 5) + l32];
    unsigned v1 = cur[(i1 << 5) + l32];
    unsigned v2 = cur[(i2 << 5) + l32];
    unsigned v3 = cur[(i3 << 5) + l32];
    unsigned v4 = cur[(i4 << 5) + l32];
    unsigned v5 = cur[(i5 << 5) + l32];
    unsigned v6 = cur[(i6 << 5) + l32];
    unsigned v7 = cur[(i7 << 5) + l32];
    s0 = fmaf(g0, __uint_as_float(v0 << 16), s0);
    s1 = fmaf(g0, __uint_as_float(v0 & 0xffff0000u), s1);
    s0 = fmaf(g1, __uint_as_float(v1 << 16), s0);
    s1 = fmaf(g1, __uint_as_float(v1 & 0xffff0000u), s1);
    s0 = fmaf(g2, __uint_as_float(v2 << 16), s0);
    s1 = fmaf(g2, __uint_as_float(v2 & 0xffff0000u), s1);
    s0 = fmaf(g3, __uint_as_float(v3 << 16), s0);
    s1 = fmaf(g3, __uint_as_float(v3 & 0xffff0000u), s1);
    s0 = fmaf(g4, __uint_as_float(v4 << 16), s0);
    s1 = fmaf(g4, __uint_as_float(v4 & 0xffff0000u), s1);
    s0 = fmaf(g5, __uint_as_float(v5 << 16), s0);
    s1 = fmaf(g5, __uint_as_float(v5 & 0xffff0000u), s1);
    s0 = fmaf(g6, __uint_as_float(v6 << 16), s0);
    s1 = fmaf(g6, __uint_as_float(v6 & 0xffff0000u), s1);
    s0 = fmaf(g7, __uint_as_float(v7 << 16), s0);
    s1 = fmaf(g7, __uint_as_float(v7 & 0xffff0000u), s1);
  }
  // combine the two half-waves (same dims, different edge subsets)
  s0 += __shfl_xor(s0, 32, 64);
  s1 += __shfl_xor(s1, 32, 64);
  unsigned ro = ((unsigned)node << 5) + l32;
  if (half == 0) {
    float2 base;
    if (first) {
      base = (node < NU) ? egoU[ro] : egoI[ro - (unsigned)NU * 32u];
    } else {
      base = acc[ro];
    }
    base.x += s0;
    base.y += s1;
    acc[ro] = base;
  } else {
    nxt[ro] = pack2(s0, s1);
  }
}

// ---------------- losses ----------------
// KL via MFMA: sd = softplus(acc[:, :32]) @ lin_w^T (+lb). One wave per 16
// rows; A = bf16(sp) in native A-frag layout, B = 4 frags of lin_w rows
// (same row-major-x-K pattern as verified k_nce_mfma). Shuffle-broadcast
// version was LDS-pipe bound at 122-137 us (rounds 8/9).
// m^2 contribution summed separately (identical when all kl finite — values
// are O(1), exp cannot overflow here).
__global__ __launch_bounds__(256) void k_kl(const float* __restrict__ acc,
                                            const float* __restrict__ lin_w,
                                            const float* __restrict__ lin_b,
                                            double* __restrict__ accums) {
  int lane = threadIdx.x & 63;
  int wid = threadIdx.x >> 6;
  int n = lane & 15, q = lane >> 4;
  int tile = blockIdx.x * 4 + wid;
  if (tile >= NT / 16) return;
  // B fragments: Bc[k=q*8+j][col n] = lin_w[(c*16+n)*32 + q*8+j]
  bf16x8 B0, B1, B2, B3;
  float lb0, lb1, lb2, lb3;
  {
    const float* w0 = lin_w + (0 * 16 + n) * 32 + q * 8;
    const float* w1 = lin_w + (1 * 16 + n) * 32 + q * 8;
    const float* w2 = lin_w + (2 * 16 + n) * 32 + q * 8;
    const float* w3 = lin_w + (3 * 16 + n) * 32 + q * 8;
#pragma unroll
    for (int j = 0; j < 8; j++) {
      B0[j] = (short)f2b(w0[j]);
      B1[j] = (short)f2b(w1[j]);
      B2[j] = (short)f2b(w2[j]);
      B3[j] = (short)f2b(w3[j]);
    }
    lb0 = lin_b[0 * 16 + n] + 1e-8f;
    lb1 = lin_b[1 * 16 + n] + 1e-8f;
    lb2 = lin_b[2 * 16 + n] + 1e-8f;
    lb3 = lin_b[3 * 16 + n] + 1e-8f;
  }
  // row load: lane (n=row-in-tile, q) takes dims [q*8,q*8+8) and +32
  const float* rowp = acc + (size_t)(tile * 16 + n) * 64 + q * 8;
  float4 a0 = *(const float4*)rowp;
  float4 a1 = *(const float4*)(rowp + 4);
  float4 b0 = *(const float4*)(rowp + 32);
  float4 b1 = *(const float4*)(rowp + 36);
  float msum = a0.x * a0.x + a0.y * a0.y + a0.z * a0.z + a0.w * a0.w
             + a1.x * a1.x + a1.y * a1.y + a1.z * a1.z + a1.w * a1.w
             + b0.x * b0.x + b0.y * b0.y + b0.z * b0.z + b0.w * b0.w
             + b1.x * b1.x + b1.y * b1.y + b1.z * b1.z + b1.w * b1.w;
  bf16x8 Af;
  Af[0] = (short)f2b(softplusf(a0.x));
  Af[1] = (short)f2b(softplusf(a0.y));
  Af[2] = (short)f2b(softplusf(a0.z));
  Af[3] = (short)f2b(softplusf(a0.w));
  Af[4] = (short)f2b(softplusf(a1.x));
  Af[5] = (short)f2b(softplusf(a1.y));
  Af[6] = (short)f2b(softplusf(a1.z));
  Af[7] = (short)f2b(softplusf(a1.w));
  f32x4 z = {0.f, 0.f, 0.f, 0.f};
  f32x4 c0 = __builtin_amdgcn_mfma_f32_16x16x32_bf16(Af, B0, z, 0, 0, 0);
  f32x4 c1 = __builtin_amdgcn_mfma_f32_16x16x32_bf16(Af, B1, z, 0, 0, 0);
  f32x4 c2 = __builtin_amdgcn_mfma_f32_16x16x32_bf16(Af, B2, z, 0, 0, 0);
  f32x4 c3 = __builtin_amdgcn_mfma_f32_16x16x32_bf16(Af, B3, z, 0, 0, 0);
  float ksum = 0.f;
#pragma unroll
  for (int r = 0; r < 4; r++) {
    float s0 = c0[r] + lb0, s1 = c1[r] + lb1, s2 = c2[r] + lb2, s3 = c3[r] + lb3;
    ksum += -0.5f * (1.f + 2.f * s0 - __expf(2.f * s0));
    ksum += -0.5f * (1.f + 2.f * s1 - __expf(2.f * s1));
    ksum += -0.5f * (1.f + 2.f * s2 - __expf(2.f * s2));
    ksum += -0.5f * (1.f + 2.f * s3 - __expf(2.f * s3));
  }
  float tot = wsum(ksum + 0.5f * msum);
  if (lane == 0) atomicAdd(&accums[1], (double)tot);
}

__global__ __launch_bounds__(256) void k_batch_user(
    const float* __restrict__ acc, const float* __restrict__ user_emb,
    const float* __restrict__ eps, const float* __restrict__ intent,
    const float* __restrict__ lin_w, const float* __restrict__ lin_b,
    const int* __restrict__ users, const int* __restrict__ pos_items,
    const int* __restrict__ neg_items,
    float* __restrict__ gen_o, float* __restrict__ int_o,
    unsigned short* __restrict__ gen_b, unsigned short* __restrict__ int_b,
    double* __restrict__ accums) {
  __shared__ float ui[64 * 130];
  __shared__ float lw[64 * 33];
  __shared__ float lb[64];
  __shared__ double red[8];
  for (int i = threadIdx.x; i < 64 * 128; i += 256) ui[(i >> 7) * 130 + (i & 127)] = intent[i];
  for (int i = threadIdx.x; i < 64 * 32; i += 256) lw[(i >> 5) * 33 + (i & 31)] = lin_w[i];
  if (threadIdx.x < 64) lb[threadIdx.x] = lin_b[threadIdx.x];
  __syncthreads();
  int lane = threadIdx.x & 63;
  int wid = threadIdx.x >> 6;
  int b = (blockIdx.x << 2) + wid;
  int u = users[b];
  float m = acc[u * 64 + lane];
  int k0 = lane * 2;
  float l0 = 0.f, l1 = 0.f;
  for (int d = 0; d < 64; d++) {
    float md = __shfl(m, d, 64);
    l0 = fmaf(md, ui[d * 130 + k0], l0);
    l1 = fmaf(md, ui[d * 130 + k0 + 1], l1);
  }
  float mx = wmax(fmaxf(l0, l1));
  float p0 = expf(l0 - mx), p1 = expf(l1 - mx);
  float tot = wsum(p0 + p1);
  p0 /= tot; p1 /= tot;
  float s = 0.f;
  for (int k = 0; k < 128; k++) {
    float pk = __shfl((k & 1) ? p1 : p0, k >> 1, 64);
    s = fmaf(pk, ui[lane * 130 + k], s);
  }
  float nrm = sqrtf(wsum(s * s));
  float io = s / nrm;
  int_o[b * 64 + lane] = io;
  int_b[b * 64 + lane] = f2b(io);
  float sp = softplusf(m);
  float sd = lb[lane] + 1e-8f;
#pragma unroll
  for (int j = 0; j < 32; j++) sd = fmaf(__shfl(sp, j, 64), lw[lane * 33 + j], sd);
  float ge = m + eps[u * 64 + lane] * sd;
  float gn = sqrtf(wsum(ge * ge));
  float go = ge / gn;
  gen_o[b * 64 + lane] = go;
  gen_b[b * 64 + lane] = f2b(go);
  int pi = pos_items[b], ni = neg_items[b];
  float pv = acc[(NU + pi) * 64 + lane];
  float nv = acc[(NU + ni) * 64 + lane];
  float ps = wsum(m * pv);
  float ns = wsum(m * nv);
  float bpr = softplusf(ns - ps);
  float ue = user_emb[u * 64 + lane];
  float es = wsum(ue * ue);
  if (lane == 0) { red[wid] = (double)bpr; red[4 + wid] = (double)es; }
  __syncthreads();
  if (threadIdx.x == 0) {
    atomicAdd(&accums[0], red[0] + red[1] + red[2] + red[3]);
    atomicAdd(&accums[2], red[4] + red[5] + red[6] + red[7]);
  }
}

__global__ __launch_bounds__(256) void k_batch_item(
    const float* __restrict__ acc, const float* __restrict__ item_emb,
    const float* __restrict__ eps, const float* __restrict__ intent,
    const float* __restrict__ lin_w, const float* __restrict__ lin_b,
    const int* __restrict__ pos_items, const int* __restrict__ neg_items,
    float* __restrict__ gen_o, float* __restrict__ int_o,
    unsigned short* __restrict__ gen_b, unsigned short* __restrict__ int_b,
    double* __restrict__ accums) {
  __shared__ float ui[64 * 130];
  __shared__ float lw[64 * 33];
  __shared__ float lb[64];
  __shared__ double red[4];
  for (int i = threadIdx.x; i < 64 * 128; i += 256) ui[(i >> 7) * 130 + (i & 127)] = intent[i];
  for (int i = threadIdx.x; i < 64 * 32; i += 256) lw[(i >> 5) * 33 + (i & 31)] = lin_w[i];
  if (threadIdx.x < 64) lb[threadIdx.x] = lin_b[threadIdx.x];
  __syncthreads();
  int lane = threadIdx.x & 63;
  int wid = threadIdx.x >> 6;
  int b = (blockIdx.x << 2) + wid;
  int pi = pos_items[b], ni = neg_items[b];
  int row = NU + pi;
  float m = acc[row * 64 + lane];
  int k0 = lane * 2;
  float l0 = 0.f, l1 = 0.f;
  for (int d = 0; d < 64; d++) {
    float md = __shfl(m, d, 64);
    l0 = fmaf(md, ui[d * 130 + k0], l0);
    l1 = fmaf(md, ui[d * 130 + k0 + 1], l1);
  }
  float mx = wmax(fmaxf(l0, l1));
  float p0 = expf(l0 - mx), p1 = expf(l1 - mx);
  float tot = wsum(p0 + p1);
  p0 /= tot; p1 /= tot;
  float s = 0.f;
  for (int k = 0; k < 128; k++) {
    float pk = __shfl((k & 1) ? p1 : p0, k >> 1, 64);
    s = fmaf(pk, ui[lane * 130 + k], s);
  }
  float nrm = sqrtf(wsum(s * s));
  float io = s / nrm;
  int_o[b * 64 + lane] = io;
  int_b[b * 64 + lane] = f2b(io);
  float sp = softplusf(m);
  float sd = lb[lane] + 1e-8f;
#pragma unroll
  for (int j = 0; j < 32; j++) sd = fmaf(__shfl(sp, j, 64), lw[lane * 33 + j], sd);
  float ge = m + eps[row * 64 + lane] * sd;
  float gn = sqrtf(wsum(ge * ge));
  float go = ge / gn;
  gen_o[b * 64 + lane] = go;
  gen_b[b * 64 + lane] = f2b(go);
  float a0 = item_emb[pi * 64 + lane];
  float a1 = item_emb[ni * 64 + lane];
  float es = wsum(a0 * a0 + a1 * a1);
  if (lane == 0) red[wid] = (double)es;
  __syncthreads();
  if (threadIdx.x == 0) atomicAdd(&accums[2], red[0] + red[1] + red[2] + red[3]);
}

__global__ void k_int(const float* __restrict__ ui, const float* __restrict__ ii,
                      double* __restrict__ accums) {
  float s = 0.f;
  for (int i = threadIdx.x; i < 64 * 128; i += 256) {
    float a = ui[i], b = ii[i];
    s = fmaf(a, a, s);
    s = fmaf(b, b, s);
  }
  s = wsum(s);
  __shared__ float red[4];
  if ((threadIdx.x & 63) == 0) red[threadIdx.x >> 6] = s;
  __syncthreads();
  if (threadIdx.x == 0) atomicAdd(&accums[3], (double)(red[0] + red[1] + red[2] + red[3]));
}

// ---------------- InfoNCE negatives via bf16 MFMA ----------------
__global__ __launch_bounds__(256) void k_nce_mfma(
    const unsigned short* __restrict__ e1u, const unsigned short* __restrict__ e2u,
    const unsigned short* __restrict__ e1i, const unsigned short* __restrict__ e2i,
    float* __restrict__ negu, float* __restrict__ negi) {
  int pair = blockIdx.y >> 2, jq = blockIdx.y & 3;
  const unsigned short* e1 = pair ? e1i : e1u;
  const unsigned short* e2 = pair ? e2i : e2u;
  float* nego = pair ? negi : negu;
  int wid = threadIdx.x >> 6, lane = threadIdx.x & 63;
  int q = lane >> 4, n = lane & 15;
  int i0 = blockIdx.x * 64 + wid * 16;
  const bf16x8* arow = (const bf16x8*)(e1 + (size_t)(i0 + n) * 64 + q * 8);
  bf16x8 a0 = arow[0];
  bf16x8 a1 = arow[4];
  f32x4 accv = {0.f, 0.f, 0.f, 0.f};
  int j0 = jq * 1024;
  for (int jt = 0; jt < 64; jt++) {
    const bf16x8* brow = (const bf16x8*)(e2 + (size_t)(j0 + jt * 16 + n) * 64 + q * 8);
    bf16x8 b0 = brow[0];
    bf16x8 b1 = brow[4];
    f32x4 c = {0.f, 0.f, 0.f, 0.f};
    c = __builtin_amdgcn_mfma_f32_16x16x32_bf16(a0, b0, c, 0, 0, 0);
    c = __builtin_amdgcn_mfma_f32_16x16x32_bf16(a1, b1, c, 0, 0, 0);
#pragma unroll
    for (int r = 0; r < 4; r++) accv[r] += __expf(5.0f * c[r]);
  }
#pragma unroll
  for (int o = 1; o < 16; o <<= 1) {
#pragma unroll
    for (int r = 0; r < 4; r++) accv[r] += __shfl_xor(accv[r], o, 64);
  }
  if (n == 0) {
#pragma unroll
    for (int r = 0; r < 4; r++) atomicAdd(&nego[i0 + q * 4 + r], accv[r]);
  }
}

__global__ __launch_bounds__(256) void k_nce_final(
    const float* __restrict__ ugen, const float* __restrict__ uio,
    const float* __restrict__ igen, const float* __restrict__ iio,
    const float* __restrict__ negu, const float* __restrict__ negi,
    double* __restrict__ accums) {
  __shared__ double red[4];
  int lane = threadIdx.x & 63, wid = threadIdx.x >> 6;
  int w = blockIdx.x * 4 + wid;
  int pair = w >> 12, i = w & 4095;
  const float* e1 = pair ? igen : ugen;
  const float* e2 = pair ? iio : uio;
  const float* ng = pair ? negi : negu;
  float dot = wsum(e1[i * 64 + lane] * e2[i * 64 + lane]);
  if (lane == 0) {
    float pos = expf(dot * 5.f);
    red[wid] = (double)(-logf(pos / (ng[i] + 1e-8f) + 1e-8f));
  }
  __syncthreads();
  if (threadIdx.x == 0) atomicAdd(&accums[4], red[0] + red[1] + red[2] + red[3]);
}

__global__ void k_fin(const double* __restrict__ accums, float* __restrict__ out) {
  if (threadIdx.x == 0 && blockIdx.x == 0) {
    double bpr = accums[0] / (double)BB;
    double kl = 0.01 * accums[1] / (double)NT;
    out[0] = (float)(bpr + kl);
    out[1] = (float)(0.1 * accums[4] / (double)BB);
    out[2] = (float)(1e-5 * accums[2]);
    out[3] = (float)(1e-5 * accums[3]);
  }
}

extern "C" void kernel_launch(void* const* d_in, const int* in_sizes, int n_in,
                              void* d_out, int out_size, void* d_ws, size_t ws_size,
                              hipStream_t stream) {
  const float* user_emb = (const float*)d_in[0];
  const float* item_emb = (const float*)d_in[1];
  const float* user_int = (const float*)d_in[2];
  const float* item_int = (const float*)d_in[3];
  const float* lin_w = (const float*)d_in[4];
  const float* lin_b = (const float*)d_in[5];
  const float* eps = (const float*)d_in[6];
  const int* h_list = (const int*)d_in[7];
  const int* t_list = (const int*)d_in[8];
  const int* users = (const int*)d_in[9];
  const int* pos_items = (const int*)d_in[10];
  const int* neg_items = (const int*)d_in[11];
  float* out = (float*)d_out;
  const int E = in_sizes[7];
  const size_t Ecap = (size_t)E + 16 * (size_t)NT;  // x16-padded capacity

  char* ws = (char*)d_ws;
  size_t off = 0;
  auto take = [&](size_t bytes) -> char* {
    char* p = ws + off;
    off = (off + bytes + 255) & ~(size_t)255;
    return p;
  };
  int* row_ptr = (int*)take((size_t)(NT + 1) * 4);
  float* d_inv = (float*)take((size_t)NT * 4);
  int* rloc_g = (int*)take((size_t)NT * 4);
  int* cnt_chunk = (int*)take((size_t)NBUCK * NCH * 1024 * 4);
  int* gcur = (int*)take(NBUCK * 4);
  int* btot = (int*)take(NBUCK * 4);
  int* bbase = (int*)take(NBUCK * 4);
  uint2* edges = (uint2*)take(Ecap * 8);
  unsigned* bufA = (unsigned*)take((size_t)NT * 32 * 4);  // bf16-packed rows
  unsigned* bufB = (unsigned*)take((size_t)NT * 32 * 4);  // contiguous after bufA
  float* acc = (float*)take((size_t)NT * 64 * 4);
  float* ugen = (float*)take((size_t)BB * 64 * 4);
  float* igen = (float*)take((size_t)BB * 64 * 4);
  float* uio = (float*)take((size_t)BB * 64 * 4);
  float* iio = (float*)take((size_t)BB * 64 * 4);
  unsigned short* ugen_b = (unsigned short*)take((size_t)BB * 64 * 2);
  unsigned short* igen_b = (unsigned short*)take((size_t)BB * 64 * 2);
  unsigned short* uio_b = (unsigned short*)take((size_t)BB * 64 * 2);
  unsigned short* iio_b = (unsigned short*)take((size_t)BB * 64 * 2);
  float* negu = (float*)take((size_t)BB * 4);
  float* negi = (float*)take((size_t)BB * 4);
  double* accums = (double*)take(64);
  if (off > ws_size) return;
  // part[] (NBUCK*BCAP uint2 = 28.9MB) aliases bufA+bufB (38.4MB contiguous):
  // last read in k_fill2; bufA first written by k_init (after), bufB by k_agg#1.
  uint2* part = (uint2*)bufA;

  hipMemsetAsync(gcur, 0, NBUCK * 4, stream);
  hipMemsetAsync(edges, 0, Ecap * 8, stream);  // pad slots: idx 0, g = 0
  hipMemsetAsync(negu, 0, (size_t)BB * 4, stream);
  hipMemsetAsync(negi, 0, (size_t)BB * 4, stream);
  hipMemsetAsync(accums, 0, 64, stream);

  int gridP = (E + 4095) / 4096;
  k_part<<<gridP, 256, 0, stream>>>(h_list, t_list, gcur, part, E);
  k_count2<<<dim3(NBUCK, NCH), 256, 0, stream>>>(part, gcur, cnt_chunk);
  k_node<<<NBUCK, 256, 0, stream>>>(cnt_chunk, rloc_g, d_inv, btot);
  k_csr_base<<<1, 256, 0, stream>>>(btot, bbase, row_ptr);
  k_rowptr<<<(NT + 255) / 256, 256, 0, stream>>>(bbase, rloc_g, row_ptr);
  k_fill2<<<dim3(NBUCK, NCH), 256, 0, stream>>>(part, gcur, cnt_chunk, row_ptr,
                                                d_inv, edges);

  int nU2 = NU * 32, nTot2 = NT * 32;
  k_init<<<(nTot2 + 255) / 256, 256, 0, stream>>>((const float2*)user_emb,
                                                  (const float2*)item_emb, bufA, nU2, nTot2);
  int gridAgg = NT / 4;
  k_agg<<<gridAgg, 256, 0, stream>>>(row_ptr, edges, bufA, bufB, (float2*)acc,
                                     (const float2*)user_emb, (const float2*)item_emb, 1);
  k_agg<<<gridAgg, 256, 0, stream>>>(row_ptr, edges, bufB, bufA, (float2*)acc,
                                     (const float2*)user_emb, (const float2*)item_emb, 0);
  k_agg<<<gridAgg, 256, 0, stream>>>(row_ptr, edges, bufA, bufB, (float2*)acc,
                                     (const float2*)user_emb, (const float2*)item_emb, 0);

  k_kl<<<(NT / 16 + 3) / 4, 256, 0, stream>>>(acc, lin_w, lin_b, accums);
  k_batch_user<<<BB / 4, 256, 0, stream>>>(acc, user_emb, eps, user_int, lin_w, lin_b,
                                           users, pos_items, neg_items,
                                           ugen, uio, ugen_b, uio_b, accums);
  k_batch_item<<<BB / 4, 256, 0, stream>>>(acc, item_emb, eps, item_int, lin_w, lin_b,
                                           pos_items, neg_items,
                                           igen, iio, igen_b, iio_b, accums);
  k_int<<<1, 256, 0, stream>>>(user_int, item_int, accums);
  k_nce_mfma<<<dim3(64, 8), 256, 0, stream>>>(ugen_b, uio_b, igen_b, iio_b, negu, negi);
  k_nce_final<<<(2 * BB) / 4, 256, 0, stream>>>(ugen, uio, igen, iio, negu, negi, accums);
  k_fin<<<1, 64, 0, stream>>>(accums, out);
}

// Round 11
// 672.389 us; speedup vs baseline: 1.1504x; 1.1398x over previous
//
#include <hip/hip_runtime.h>

#define NU 50000
#define NI 100000
#define NT 150000
#define BB 4096
#define NBUCK 147   // ceil(NT/1024)
#define BCAP 24576  // per-bucket edge capacity: mean 21504, sd ~143 -> +21 sigma
#define NCH 8       // chunks per bucket in CSR build

typedef __attribute__((ext_vector_type(8))) short bf16x8;
typedef __attribute__((ext_vector_type(4))) float f32x4;

__device__ __forceinline__ float softplusf(float x) {
  return fmaxf(x, 0.f) + log1pf(expf(-fabsf(x)));
}
__device__ __forceinline__ float wsum(float v) {
#pragma unroll
  for (int o = 32; o > 0; o >>= 1) v += __shfl_xor(v, o, 64);
  return v;
}
__device__ __forceinline__ float wmax(float v) {
#pragma unroll
  for (int o = 32; o > 0; o >>= 1) v = fmaxf(v, __shfl_xor(v, o, 64));
  return v;
}
__device__ __forceinline__ unsigned short f2b(float x) {
  unsigned u = __float_as_uint(x);
  return (unsigned short)((u + 0x7FFFu + ((u >> 16) & 1u)) >> 16);
}
__device__ __forceinline__ unsigned pack2(float lo, float hi) {
  return ((unsigned)f2b(hi) << 16) | (unsigned)f2b(lo);
}

// ---------------- CSR build ----------------
__global__ __launch_bounds__(256) void k_part(const int* __restrict__ h,
                                              const int* __restrict__ t,
                                              int* __restrict__ gcur,
                                              uint2* __restrict__ part, int E) {
  __shared__ int cnt[NBUCK];
  __shared__ int base[NBUCK];
  for (int b = threadIdx.x; b < NBUCK; b += 256) cnt[b] = 0;
  __syncthreads();
  int e0 = blockIdx.x * 4096 + threadIdx.x * 16;
  int nval = E - e0;
  nval = nval < 0 ? 0 : (nval > 16 ? 16 : nval);
  int hh[16], tt[16];
  if (nval == 16) {
    const int4* hp = (const int4*)(h + e0);
    const int4* tp = (const int4*)(t + e0);
#pragma unroll
    for (int j = 0; j < 4; j++) {
      int4 v = hp[j];
      hh[j * 4] = v.x; hh[j * 4 + 1] = v.y; hh[j * 4 + 2] = v.z; hh[j * 4 + 3] = v.w;
      int4 w = tp[j];
      tt[j * 4] = w.x; tt[j * 4 + 1] = w.y; tt[j * 4 + 2] = w.z; tt[j * 4 + 3] = w.w;
    }
  } else {
    for (int j = 0; j < nval; j++) { hh[j] = h[e0 + j]; tt[j] = t[e0 + j]; }
  }
  for (int j = 0; j < nval; j++) atomicAdd(&cnt[hh[j] >> 10], 1);
  __syncthreads();
  for (int b = threadIdx.x; b < NBUCK; b += 256) {
    int c = cnt[b];
    base[b] = c ? atomicAdd(&gcur[b], c) : 0;
    cnt[b] = 0;
  }
  __syncthreads();
  for (int j = 0; j < nval; j++) {
    int b = hh[j] >> 10;
    int r = atomicAdd(&cnt[b], 1);
    uint2 v; v.x = (unsigned)hh[j]; v.y = (unsigned)tt[j];
    part[(size_t)b * BCAP + base[b] + r] = v;
  }
}

__global__ __launch_bounds__(256) void k_count2(const uint2* __restrict__ part,
                                                const int* __restrict__ gcur,
                                                int* __restrict__ cnt_chunk) {
  __shared__ int hist[1024];
  int b = blockIdx.x, c = blockIdx.y, tid = threadIdx.x;
  for (int i = tid; i < 1024; i += 256) hist[i] = 0;
  __syncthreads();
  int m = gcur[b];
  int lo = (int)(((long long)m * c) >> 3);
  int hi = (int)(((long long)m * (c + 1)) >> 3);
  const uint2* pp = part + (size_t)b * BCAP;
  for (int i = lo + tid; i < hi; i += 256) atomicAdd(&hist[pp[i].x & 1023], 1);
  __syncthreads();
  int* dst = cnt_chunk + (((size_t)b * NCH + c) << 10);
  for (int i = tid; i < 1024; i += 256) dst[i] = hist[i];
}

__global__ __launch_bounds__(256) void k_node(int* __restrict__ cnt_chunk,
                                              int* __restrict__ rloc_g,
                                              float* __restrict__ d_inv,
                                              int* __restrict__ btot) {
  __shared__ int sd[256];
  int b = blockIdx.x, tid = threadIdx.x;
  int n0 = b << 10;
  int pd[4];
  int s = 0;
#pragma unroll
  for (int j = 0; j < 4; j++) {
    int idx = tid * 4 + j;
    int run = 0;
#pragma unroll
    for (int c = 0; c < NCH; c++) {
      size_t a = (((size_t)b * NCH + c) << 10) + idx;
      int v = cnt_chunk[a];
      cnt_chunk[a] = run;
      run += v;
    }
    int n = n0 + idx;
    if (n < NT) {
      d_inv[n] = 1.0f / sqrtf((float)run);  // deg >= 1 (self-loop)
      pd[j] = (run + 15) & ~15;
    } else pd[j] = 0;
    s += pd[j];
  }
  sd[tid] = s;
  __syncthreads();
  for (int o = 1; o < 256; o <<= 1) {
    int x = (tid >= o) ? sd[tid - o] : 0;
    __syncthreads();
    sd[tid] += x;
    __syncthreads();
  }
  int run2 = sd[tid] - s;
#pragma unroll
  for (int j = 0; j < 4; j++) {
    int idx = tid * 4 + j, n = n0 + idx;
    if (n < NT) rloc_g[n] = run2;
    run2 += pd[j];
  }
  if (tid == 255) btot[b] = sd[255];
}

__global__ void k_csr_base(const int* __restrict__ btot, int* __restrict__ bbase,
                           int* __restrict__ row_ptr) {
  __shared__ int sd[256];
  int t = threadIdx.x;
  int v = (t < NBUCK) ? btot[t] : 0;
  sd[t] = v;
  __syncthreads();
  for (int o = 1; o < 256; o <<= 1) {
    int x = (t >= o) ? sd[t - o] : 0;
    __syncthreads();
    sd[t] += x;
    __syncthreads();
  }
  if (t < NBUCK) bbase[t] = sd[t] - v;
  if (t == NBUCK - 1) row_ptr[NT] = sd[t];
}

__global__ void k_rowptr(const int* __restrict__ bbase, const int* __restrict__ rloc_g,
                         int* __restrict__ row_ptr) {
  int n = blockIdx.x * 256 + threadIdx.x;
  if (n < NT) row_ptr[n] = bbase[n >> 10] + rloc_g[n];
}

__global__ __launch_bounds__(256) void k_fill2(const uint2* __restrict__ part,
                                               const int* __restrict__ gcur,
                                               const int* __restrict__ chunkpre,
                                               const int* __restrict__ row_ptr,
                                               const float* __restrict__ d_inv,
                                               uint2* __restrict__ edges) {
  __shared__ int curs[1024];
  __shared__ float dl[1024];
  int b = blockIdx.x, c = blockIdx.y, tid = threadIdx.x;
  int n0 = b << 10;
  const int* pre = chunkpre + (((size_t)b * NCH + c) << 10);
  for (int i = tid; i < 1024; i += 256) {
    int n = n0 + i;
    if (n < NT) {
      curs[i] = row_ptr[n] + pre[i];
      dl[i] = d_inv[n];
    }
  }
  __syncthreads();
  int m = gcur[b];
  int lo = (int)(((long long)m * c) >> 3);
  int hi = (int)(((long long)m * (c + 1)) >> 3);
  const uint2* pp = part + (size_t)b * BCAP;
  for (int i = lo + tid; i < hi; i += 256) {
    uint2 pe = pp[i];
    int slot = atomicAdd(&curs[pe.x & 1023], 1);
    float g = dl[pe.x & 1023] * d_inv[pe.y];
    uint2 v; v.x = pe.y; v.y = __float_as_uint(g);
    edges[slot] = v;
  }
}

// ---------------- propagation ----------------
__global__ void k_init(const float2* __restrict__ ue, const float2* __restrict__ ie,
                       unsigned* __restrict__ cur, int nU2, int nTot2) {
  int i = blockIdx.x * 256 + threadIdx.x;
  if (i >= nTot2) return;
  float2 v = (i < nU2) ? ue[i] : ie[i - nU2];
  cur[i] = pack2(v.x, v.y);
}

// wave = 2 half-waves; each half-wave serves one edge (128B bf16 row).
// Edge lists padded to x16 with (idx=0, g=0) -> branchless.
// NOTE: flat named registers only — register ARRAYS in this loop get spilled
// to scratch (round 7: 2.18 GB HBM writes, 3.2x regression).
__global__ __launch_bounds__(256) void k_agg(const int* __restrict__ row_ptr,
                                             const uint2* __restrict__ edges,
                                             const unsigned* __restrict__ cur,
                                             unsigned* __restrict__ nxt,
                                             float2* __restrict__ acc,
                                             const float2* __restrict__ egoU,
                                             const float2* __restrict__ egoI,
                                             int first) {
  int node = (blockIdx.x << 2) + (threadIdx.x >> 6);
  unsigned lane = threadIdx.x & 63;
  unsigned l32 = lane & 31;
  unsigned half = lane >> 5;
  int s = row_ptr[node], e = row_ptr[node + 1];
  float s0 = 0.f, s1 = 0.f;
  for (int i = s; i < e; i += 16) {
    const uint4* e4 = (const uint4*)(edges + i);
    uint4 A = e4[0], B = e4[1], C = e4[2], D = e4[3];
    uint4 F = e4[4], G = e4[5], H = e4[6], I = e4[7];
    unsigned i0 = half ? A.z : A.x; float g0 = __uint_as_float(half ? A.w : A.y);
    unsigned i1 = half ? B.z : B.x; float g1 = __uint_as_float(half ? B.w : B.y);
    unsigned i2 = half ? C.z : C.x; float g2 = __uint_as_float(half ? C.w : C.y);
    unsigned i3 = half ? D.z : D.x; float g3 = __uint_as_float(half ? D.w : D.y);
    unsigned i4 = half ? F.z : F.x; float g4 = __uint_as_float(half ? F.w : F.y);
    unsigned i5 = half ? G.z : G.x; float g5 = __uint_as_float(half ? G.w : G.y);
    unsigned i6 = half ? H.z : H.x; float g6 = __uint_as_float(half ? H.w : H.y);
    unsigned i7 = half ? I.z : I.x; float g7 = __uint_as_float(half ? I.w : I.y);
    unsigned v0 = cur[(i0 << 5) + l32];
    unsigned v1 = cur[(i1 << 5) + l32];
    unsigned v2 = cur[(i2 << 5) + l32];
    unsigned v3 = cur[(i3 << 5) + l32];
    unsigned v4 = cur[(i4 << 5) + l32];
    unsigned v5 = cur[(i5 << 5) + l32];
    unsigned v6 = cur[(i6 << 5) + l32];
    unsigned v7 = cur[(i7 << 5) + l32];
    s0 = fmaf(g0, __uint_as_float(v0 << 16), s0);
    s1 = fmaf(g0, __uint_as_float(v0 & 0xffff0000u), s1);
    s0 = fmaf(g1, __uint_as_float(v1 << 16), s0);
    s1 = fmaf(g1, __uint_as_float(v1 & 0xffff0000u), s1);
    s0 = fmaf(g2, __uint_as_float(v2 << 16), s0);
    s1 = fmaf(g2, __uint_as_float(v2 & 0xffff0000u), s1);
    s0 = fmaf(g3, __uint_as_float(v3 << 16), s0);
    s1 = fmaf(g3, __uint_as_float(v3 & 0xffff0000u), s1);
    s0 = fmaf(g4, __uint_as_float(v4 << 16), s0);
    s1 = fmaf(g4, __uint_as_float(v4 & 0xffff0000u), s1);
    s0 = fmaf(g5, __uint_as_float(v5 << 16), s0);
    s1 = fmaf(g5, __uint_as_float(v5 & 0xffff0000u), s1);
    s0 = fmaf(g6, __uint_as_float(v6 << 16), s0);
    s1 = fmaf(g6, __uint_as_float(v6 & 0xffff0000u), s1);
    s0 = fmaf(g7, __uint_as_float(v7 << 16), s0);
    s1 = fmaf(g7, __uint_as_float(v7 & 0xffff0000u), s1);
  }
  s0 += __shfl_xor(s0, 32, 64);
  s1 += __shfl_xor(s1, 32, 64);
  unsigned ro = ((unsigned)node << 5) + l32;
  if (half == 0) {
    float2 base;
    if (first) {
      base = (node < NU) ? egoU[ro] : egoI[ro - (unsigned)NU * 32u];
    } else {
      base = acc[ro];
    }
    base.x += s0;
    base.y += s1;
    acc[ro] = base;
  } else {
    nxt[ro] = pack2(s0, s1);
  }
}

// ---------------- losses ----------------
// KL via MFMA (round 10), reduction restructured: grid-stride tiles per wave,
// LDS block-reduce, ONE atomic per block. Round 10's one-atomic-per-wave
// (9375 same-address double atomics) serialized at ~31 cy each = the whole
// 121 us (VALU 13%, MFMA 0.2%, HBM 2% — nothing else was busy).
__global__ __launch_bounds__(256) void k_kl(const float* __restrict__ acc,
                                            const float* __restrict__ lin_w,
                                            const float* __restrict__ lin_b,
                                            double* __restrict__ accums) {
  __shared__ double red[4];
  int lane = threadIdx.x & 63;
  int wid = threadIdx.x >> 6;
  int n = lane & 15, q = lane >> 4;
  // B fragments: Bc[k=q*8+j][col n] = lin_w[(c*16+n)*32 + q*8+j]
  bf16x8 B0, B1, B2, B3;
  float lb0, lb1, lb2, lb3;
  {
    const float* w0 = lin_w + (0 * 16 + n) * 32 + q * 8;
    const float* w1 = lin_w + (1 * 16 + n) * 32 + q * 8;
    const float* w2 = lin_w + (2 * 16 + n) * 32 + q * 8;
    const float* w3 = lin_w + (3 * 16 + n) * 32 + q * 8;
#pragma unroll
    for (int j = 0; j < 8; j++) {
      B0[j] = (short)f2b(w0[j]);
      B1[j] = (short)f2b(w1[j]);
      B2[j] = (short)f2b(w2[j]);
      B3[j] = (short)f2b(w3[j]);
    }
    lb0 = lin_b[0 * 16 + n] + 1e-8f;
    lb1 = lin_b[1 * 16 + n] + 1e-8f;
    lb2 = lin_b[2 * 16 + n] + 1e-8f;
    lb3 = lin_b[3 * 16 + n] + 1e-8f;
  }
  const int TI = NT / 16;  // 9375 tiles
  int w0id = blockIdx.x * 4 + wid;
  int nwv = gridDim.x * 4;
  double dsum = 0.0;
  for (int tile = w0id; tile < TI; tile += nwv) {
    const float* rowp = acc + (size_t)(tile * 16 + n) * 64 + q * 8;
    float4 a0 = *(const float4*)rowp;
    float4 a1 = *(const float4*)(rowp + 4);
    float4 b0 = *(const float4*)(rowp + 32);
    float4 b1 = *(const float4*)(rowp + 36);
    float msum = a0.x * a0.x + a0.y * a0.y + a0.z * a0.z + a0.w * a0.w
               + a1.x * a1.x + a1.y * a1.y + a1.z * a1.z + a1.w * a1.w
               + b0.x * b0.x + b0.y * b0.y + b0.z * b0.z + b0.w * b0.w
               + b1.x * b1.x + b1.y * b1.y + b1.z * b1.z + b1.w * b1.w;
    bf16x8 Af;
    Af[0] = (short)f2b(softplusf(a0.x));
    Af[1] = (short)f2b(softplusf(a0.y));
    Af[2] = (short)f2b(softplusf(a0.z));
    Af[3] = (short)f2b(softplusf(a0.w));
    Af[4] = (short)f2b(softplusf(a1.x));
    Af[5] = (short)f2b(softplusf(a1.y));
    Af[6] = (short)f2b(softplusf(a1.z));
    Af[7] = (short)f2b(softplusf(a1.w));
    f32x4 z = {0.f, 0.f, 0.f, 0.f};
    f32x4 c0 = __builtin_amdgcn_mfma_f32_16x16x32_bf16(Af, B0, z, 0, 0, 0);
    f32x4 c1 = __builtin_amdgcn_mfma_f32_16x16x32_bf16(Af, B1, z, 0, 0, 0);
    f32x4 c2 = __builtin_amdgcn_mfma_f32_16x16x32_bf16(Af, B2, z, 0, 0, 0);
    f32x4 c3 = __builtin_amdgcn_mfma_f32_16x16x32_bf16(Af, B3, z, 0, 0, 0);
    float ksum = 0.f;
#pragma unroll
    for (int r = 0; r < 4; r++) {
      float s0 = c0[r] + lb0, s1 = c1[r] + lb1, s2 = c2[r] + lb2, s3 = c3[r] + lb3;
      ksum += -0.5f * (1.f + 2.f * s0 - __expf(2.f * s0));
      ksum += -0.5f * (1.f + 2.f * s1 - __expf(2.f * s1));
      ksum += -0.5f * (1.f + 2.f * s2 - __expf(2.f * s2));
      ksum += -0.5f * (1.f + 2.f * s3 - __expf(2.f * s3));
    }
    dsum += (double)wsum(ksum + 0.5f * msum);
  }
  if (lane == 0) red[wid] = dsum;
  __syncthreads();
  if (threadIdx.x == 0)
    atomicAdd(&accums[1], red[0] + red[1] + red[2] + red[3]);
}

__global__ __launch_bounds__(256) void k_batch_user(
    const float* __restrict__ acc, const float* __restrict__ user_emb,
    const float* __restrict__ eps, const float* __restrict__ intent,
    const float* __restrict__ lin_w, const float* __restrict__ lin_b,
    const int* __restrict__ users, const int* __restrict__ pos_items,
    const int* __restrict__ neg_items,
    float* __restrict__ gen_o, float* __restrict__ int_o,
    unsigned short* __restrict__ gen_b, unsigned short* __restrict__ int_b,
    double* __restrict__ accums) {
  __shared__ float ui[64 * 130];
  __shared__ float lw[64 * 33];
  __shared__ float lb[64];
  __shared__ double red[8];
  for (int i = threadIdx.x; i < 64 * 128; i += 256) ui[(i >> 7) * 130 + (i & 127)] = intent[i];
  for (int i = threadIdx.x; i < 64 * 32; i += 256) lw[(i >> 5) * 33 + (i & 31)] = lin_w[i];
  if (threadIdx.x < 64) lb[threadIdx.x] = lin_b[threadIdx.x];
  __syncthreads();
  int lane = threadIdx.x & 63;
  int wid = threadIdx.x >> 6;
  int b = (blockIdx.x << 2) + wid;
  int u = users[b];
  float m = acc[u * 64 + lane];
  int k0 = lane * 2;
  float l0 = 0.f, l1 = 0.f;
  for (int d = 0; d < 64; d++) {
    float md = __shfl(m, d, 64);
    l0 = fmaf(md, ui[d * 130 + k0], l0);
    l1 = fmaf(md, ui[d * 130 + k0 + 1], l1);
  }
  float mx = wmax(fmaxf(l0, l1));
  float p0 = expf(l0 - mx), p1 = expf(l1 - mx);
  float tot = wsum(p0 + p1);
  p0 /= tot; p1 /= tot;
  float s = 0.f;
  for (int k = 0; k < 128; k++) {
    float pk = __shfl((k & 1) ? p1 : p0, k >> 1, 64);
    s = fmaf(pk, ui[lane * 130 + k], s);
  }
  float nrm = sqrtf(wsum(s * s));
  float io = s / nrm;
  int_o[b * 64 + lane] = io;
  int_b[b * 64 + lane] = f2b(io);
  float sp = softplusf(m);
  float sd = lb[lane] + 1e-8f;
#pragma unroll
  for (int j = 0; j < 32; j++) sd = fmaf(__shfl(sp, j, 64), lw[lane * 33 + j], sd);
  float ge = m + eps[u * 64 + lane] * sd;
  float gn = sqrtf(wsum(ge * ge));
  float go = ge / gn;
  gen_o[b * 64 + lane] = go;
  gen_b[b * 64 + lane] = f2b(go);
  int pi = pos_items[b], ni = neg_items[b];
  float pv = acc[(NU + pi) * 64 + lane];
  float nv = acc[(NU + ni) * 64 + lane];
  float ps = wsum(m * pv);
  float ns = wsum(m * nv);
  float bpr = softplusf(ns - ps);
  float ue = user_emb[u * 64 + lane];
  float es = wsum(ue * ue);
  if (lane == 0) { red[wid] = (double)bpr; red[4 + wid] = (double)es; }
  __syncthreads();
  if (threadIdx.x == 0) {
    atomicAdd(&accums[0], red[0] + red[1] + red[2] + red[3]);
    atomicAdd(&accums[2], red[4] + red[5] + red[6] + red[7]);
  }
}

__global__ __launch_bounds__(256) void k_batch_item(
    const float* __restrict__ acc, const float* __restrict__ item_emb,
    const float* __restrict__ eps, const float* __restrict__ intent,
    const float* __restrict__ lin_w, const float* __restrict__ lin_b,
    const int* __restrict__ pos_items, const int* __restrict__ neg_items,
    float* __restrict__ gen_o, float* __restrict__ int_o,
    unsigned short* __restrict__ gen_b, unsigned short* __restrict__ int_b,
    double* __restrict__ accums) {
  __shared__ float ui[64 * 130];
  __shared__ float lw[64 * 33];
  __shared__ float lb[64];
  __shared__ double red[4];
  for (int i = threadIdx.x; i < 64 * 128; i += 256) ui[(i >> 7) * 130 + (i & 127)] = intent[i];
  for (int i = threadIdx.x; i < 64 * 32; i += 256) lw[(i >> 5) * 33 + (i & 31)] = lin_w[i];
  if (threadIdx.x < 64) lb[threadIdx.x] = lin_b[threadIdx.x];
  __syncthreads();
  int lane = threadIdx.x & 63;
  int wid = threadIdx.x >> 6;
  int b = (blockIdx.x << 2) + wid;
  int pi = pos_items[b], ni = neg_items[b];
  int row = NU + pi;
  float m = acc[row * 64 + lane];
  int k0 = lane * 2;
  float l0 = 0.f, l1 = 0.f;
  for (int d = 0; d < 64; d++) {
    float md = __shfl(m, d, 64);
    l0 = fmaf(md, ui[d * 130 + k0], l0);
    l1 = fmaf(md, ui[d * 130 + k0 + 1], l1);
  }
  float mx = wmax(fmaxf(l0, l1));
  float p0 = expf(l0 - mx), p1 = expf(l1 - mx);
  float tot = wsum(p0 + p1);
  p0 /= tot; p1 /= tot;
  float s = 0.f;
  for (int k = 0; k < 128; k++) {
    float pk = __shfl((k & 1) ? p1 : p0, k >> 1, 64);
    s = fmaf(pk, ui[lane * 130 + k], s);
  }
  float nrm = sqrtf(wsum(s * s));
  float io = s / nrm;
  int_o[b * 64 + lane] = io;
  int_b[b * 64 + lane] = f2b(io);
  float sp = softplusf(m);
  float sd = lb[lane] + 1e-8f;
#pragma unroll
  for (int j = 0; j < 32; j++) sd = fmaf(__shfl(sp, j, 64), lw[lane * 33 + j], sd);
  float ge = m + eps[row * 64 + lane] * sd;
  float gn = sqrtf(wsum(ge * ge));
  float go = ge / gn;
  gen_o[b * 64 + lane] = go;
  gen_b[b * 64 + lane] = f2b(go);
  float a0 = item_emb[pi * 64 + lane];
  float a1 = item_emb[ni * 64 + lane];
  float es = wsum(a0 * a0 + a1 * a1);
  if (lane == 0) red[wid] = (double)es;
  __syncthreads();
  if (threadIdx.x == 0) atomicAdd(&accums[2], red[0] + red[1] + red[2] + red[3]);
}

__global__ void k_int(const float* __restrict__ ui, const float* __restrict__ ii,
                      double* __restrict__ accums) {
  float s = 0.f;
  for (int i = threadIdx.x; i < 64 * 128; i += 256) {
    float a = ui[i], b = ii[i];
    s = fmaf(a, a, s);
    s = fmaf(b, b, s);
  }
  s = wsum(s);
  __shared__ float red[4];
  if ((threadIdx.x & 63) == 0) red[threadIdx.x >> 6] = s;
  __syncthreads();
  if (threadIdx.x == 0) atomicAdd(&accums[3], (double)(red[0] + red[1] + red[2] + red[3]));
}

// ---------------- InfoNCE negatives via bf16 MFMA ----------------
__global__ __launch_bounds__(256) void k_nce_mfma(
    const unsigned short* __restrict__ e1u, const unsigned short* __restrict__ e2u,
    const unsigned short* __restrict__ e1i, const unsigned short* __restrict__ e2i,
    float* __restrict__ negu, float* __restrict__ negi) {
  int pair = blockIdx.y >> 2, jq = blockIdx.y & 3;
  const unsigned short* e1 = pair ? e1i : e1u;
  const unsigned short* e2 = pair ? e2i : e2u;
  float* nego = pair ? negi : negu;
  int wid = threadIdx.x >> 6, lane = threadIdx.x & 63;
  int q = lane >> 4, n = lane & 15;
  int i0 = blockIdx.x * 64 + wid * 16;
  const bf16x8* arow = (const bf16x8*)(e1 + (size_t)(i0 + n) * 64 + q * 8);
  bf16x8 a0 = arow[0];
  bf16x8 a1 = arow[4];
  f32x4 accv = {0.f, 0.f, 0.f, 0.f};
  int j0 = jq * 1024;
  for (int jt = 0; jt < 64; jt++) {
    const bf16x8* brow = (const bf16x8*)(e2 + (size_t)(j0 + jt * 16 + n) * 64 + q * 8);
    bf16x8 b0 = brow[0];
    bf16x8 b1 = brow[4];
    f32x4 c = {0.f, 0.f, 0.f, 0.f};
    c = __builtin_amdgcn_mfma_f32_16x16x32_bf16(a0, b0, c, 0, 0, 0);
    c = __builtin_amdgcn_mfma_f32_16x16x32_bf16(a1, b1, c, 0, 0, 0);
#pragma unroll
    for (int r = 0; r < 4; r++) accv[r] += __expf(5.0f * c[r]);
  }
#pragma unroll
  for (int o = 1; o < 16; o <<= 1) {
#pragma unroll
    for (int r = 0; r < 4; r++) accv[r] += __shfl_xor(accv[r], o, 64);
  }
  if (n == 0) {
#pragma unroll
    for (int r = 0; r < 4; r++) atomicAdd(&nego[i0 + q * 4 + r], accv[r]);
  }
}

__global__ __launch_bounds__(256) void k_nce_final(
    const float* __restrict__ ugen, const float* __restrict__ uio,
    const float* __restrict__ igen, const float* __restrict__ iio,
    const float* __restrict__ negu, const float* __restrict__ negi,
    double* __restrict__ accums) {
  __shared__ double red[4];
  int lane = threadIdx.x & 63, wid = threadIdx.x >> 6;
  int w = blockIdx.x * 4 + wid;
  int pair = w >> 12, i = w & 4095;
  const float* e1 = pair ? igen : ugen;
  const float* e2 = pair ? iio : uio;
  const float* ng = pair ? negi : negu;
  float dot = wsum(e1[i * 64 + lane] * e2[i * 64 + lane]);
  if (lane == 0) {
    float pos = expf(dot * 5.f);
    red[wid] = (double)(-logf(pos / (ng[i] + 1e-8f) + 1e-8f));
  }
  __syncthreads();
  if (threadIdx.x == 0) atomicAdd(&accums[4], red[0] + red[1] + red[2] + red[3]);
}

__global__ void k_fin(const double* __restrict__ accums, float* __restrict__ out) {
  if (threadIdx.x == 0 && blockIdx.x == 0) {
    double bpr = accums[0] / (double)BB;
    double kl = 0.01 * accums[1] / (double)NT;
    out[0] = (float)(bpr + kl);
    out[1] = (float)(0.1 * accums[4] / (double)BB);
    out[2] = (float)(1e-5 * accums[2]);
    out[3] = (float)(1e-5 * accums[3]);
  }
}

extern "C" void kernel_launch(void* const* d_in, const int* in_sizes, int n_in,
                              void* d_out, int out_size, void* d_ws, size_t ws_size,
                              hipStream_t stream) {
  const float* user_emb = (const float*)d_in[0];
  const float* item_emb = (const float*)d_in[1];
  const float* user_int = (const float*)d_in[2];
  const float* item_int = (const float*)d_in[3];
  const float* lin_w = (const float*)d_in[4];
  const float* lin_b = (const float*)d_in[5];
  const float* eps = (const float*)d_in[6];
  const int* h_list = (const int*)d_in[7];
  const int* t_list = (const int*)d_in[8];
  const int* users = (const int*)d_in[9];
  const int* pos_items = (const int*)d_in[10];
  const int* neg_items = (const int*)d_in[11];
  float* out = (float*)d_out;
  const int E = in_sizes[7];
  const size_t Ecap = (size_t)E + 16 * (size_t)NT;  // x16-padded capacity

  char* ws = (char*)d_ws;
  size_t off = 0;
  auto take = [&](size_t bytes) -> char* {
    char* p = ws + off;
    off = (off + bytes + 255) & ~(size_t)255;
    return p;
  };
  int* row_ptr = (int*)take((size_t)(NT + 1) * 4);
  float* d_inv = (float*)take((size_t)NT * 4);
  int* rloc_g = (int*)take((size_t)NT * 4);
  int* cnt_chunk = (int*)take((size_t)NBUCK * NCH * 1024 * 4);
  int* gcur = (int*)take(NBUCK * 4);
  int* btot = (int*)take(NBUCK * 4);
  int* bbase = (int*)take(NBUCK * 4);
  uint2* edges = (uint2*)take(Ecap * 8);
  unsigned* bufA = (unsigned*)take((size_t)NT * 32 * 4);  // bf16-packed rows
  unsigned* bufB = (unsigned*)take((size_t)NT * 32 * 4);  // contiguous after bufA
  float* acc = (float*)take((size_t)NT * 64 * 4);
  float* ugen = (float*)take((size_t)BB * 64 * 4);
  float* igen = (float*)take((size_t)BB * 64 * 4);
  float* uio = (float*)take((size_t)BB * 64 * 4);
  float* iio = (float*)take((size_t)BB * 64 * 4);
  unsigned short* ugen_b = (unsigned short*)take((size_t)BB * 64 * 2);
  unsigned short* igen_b = (unsigned short*)take((size_t)BB * 64 * 2);
  unsigned short* uio_b = (unsigned short*)take((size_t)BB * 64 * 2);
  unsigned short* iio_b = (unsigned short*)take((size_t)BB * 64 * 2);
  float* negu = (float*)take((size_t)BB * 4);
  float* negi = (float*)take((size_t)BB * 4);
  double* accums = (double*)take(64);
  if (off > ws_size) return;
  // part[] (NBUCK*BCAP uint2 = 28.9MB) aliases bufA+bufB (38.4MB contiguous):
  // last read in k_fill2; bufA first written by k_init (after), bufB by k_agg#1.
  uint2* part = (uint2*)bufA;

  hipMemsetAsync(gcur, 0, NBUCK * 4, stream);
  hipMemsetAsync(edges, 0, Ecap * 8, stream);  // pad slots: idx 0, g = 0
  hipMemsetAsync(negu, 0, (size_t)BB * 4, stream);
  hipMemsetAsync(negi, 0, (size_t)BB * 4, stream);
  hipMemsetAsync(accums, 0, 64, stream);

  int gridP = (E + 4095) / 4096;
  k_part<<<gridP, 256, 0, stream>>>(h_list, t_list, gcur, part, E);
  k_count2<<<dim3(NBUCK, NCH), 256, 0, stream>>>(part, gcur, cnt_chunk);
  k_node<<<NBUCK, 256, 0, stream>>>(cnt_chunk, rloc_g, d_inv, btot);
  k_csr_base<<<1, 256, 0, stream>>>(btot, bbase, row_ptr);
  k_rowptr<<<(NT + 255) / 256, 256, 0, stream>>>(bbase, rloc_g, row_ptr);
  k_fill2<<<dim3(NBUCK, NCH), 256, 0, stream>>>(part, gcur, cnt_chunk, row_ptr,
                                                d_inv, edges);

  int nU2 = NU * 32, nTot2 = NT * 32;
  k_init<<<(nTot2 + 255) / 256, 256, 0, stream>>>((const float2*)user_emb,
                                                  (const float2*)item_emb, bufA, nU2, nTot2);
  int gridAgg = NT / 4;
  k_agg<<<gridAgg, 256, 0, stream>>>(row_ptr, edges, bufA, bufB, (float2*)acc,
                                     (const float2*)user_emb, (const float2*)item_emb, 1);
  k_agg<<<gridAgg, 256, 0, stream>>>(row_ptr, edges, bufB, bufA, (float2*)acc,
                                     (const float2*)user_emb, (const float2*)item_emb, 0);
  k_agg<<<gridAgg, 256, 0, stream>>>(row_ptr, edges, bufA, bufB, (float2*)acc,
                                     (const float2*)user_emb, (const float2*)item_emb, 0);

  k_kl<<<640, 256, 0, stream>>>(acc, lin_w, lin_b, accums);
  k_batch_user<<<BB / 4, 256, 0, stream>>>(acc, user_emb, eps, user_int, lin_w, lin_b,
                                           users, pos_items, neg_items,
                                           ugen, uio, ugen_b, uio_b, accums);
  k_batch_item<<<BB / 4, 256, 0, stream>>>(acc, item_emb, eps, item_int, lin_w, lin_b,
                                           pos_items, neg_items,
                                           igen, iio, igen_b, iio_b, accums);
  k_int<<<1, 256, 0, stream>>>(user_int, item_int, accums);
  k_nce_mfma<<<dim3(64, 8), 256, 0, stream>>>(ugen_b, uio_b, igen_b, iio_b, negu, negi);
  k_nce_final<<<(2 * BB) / 4, 256, 0, stream>>>(ugen, uio, igen, iio, negu, negi, accums);
  k_fin<<<1, 64, 0, stream>>>(accums, out);
}

// Round 12
// 665.621 us; speedup vs baseline: 1.1621x; 1.0102x over previous
//
#include <hip/hip_runtime.h>

#define NU 50000
#define NI 100000
#define NT 150000
#define BB 4096
#define NBUCK 147   // ceil(NT/1024)
#define BCAP 24576  // per-bucket edge capacity: mean 21504, sd ~143 -> +21 sigma
#define NCH 8       // chunks per bucket in CSR build

typedef __attribute__((ext_vector_type(8))) short bf16x8;
typedef __attribute__((ext_vector_type(4))) float f32x4;

__device__ __forceinline__ float softplusf(float x) {
  return fmaxf(x, 0.f) + log1pf(expf(-fabsf(x)));
}
__device__ __forceinline__ float wsum(float v) {
#pragma unroll
  for (int o = 32; o > 0; o >>= 1) v += __shfl_xor(v, o, 64);
  return v;
}
__device__ __forceinline__ float wmax(float v) {
#pragma unroll
  for (int o = 32; o > 0; o >>= 1) v = fmaxf(v, __shfl_xor(v, o, 64));
  return v;
}
__device__ __forceinline__ unsigned short f2b(float x) {
  unsigned u = __float_as_uint(x);
  return (unsigned short)((u + 0x7FFFu + ((u >> 16) & 1u)) >> 16);
}

// ---------------- CSR build ----------------
__global__ __launch_bounds__(256) void k_part(const int* __restrict__ h,
                                              const int* __restrict__ t,
                                              int* __restrict__ gcur,
                                              uint2* __restrict__ part, int E) {
  __shared__ int cnt[NBUCK];
  __shared__ int base[NBUCK];
  for (int b = threadIdx.x; b < NBUCK; b += 256) cnt[b] = 0;
  __syncthreads();
  int e0 = blockIdx.x * 4096 + threadIdx.x * 16;
  int nval = E - e0;
  nval = nval < 0 ? 0 : (nval > 16 ? 16 : nval);
  int hh[16], tt[16];
  if (nval == 16) {
    const int4* hp = (const int4*)(h + e0);
    const int4* tp = (const int4*)(t + e0);
#pragma unroll
    for (int j = 0; j < 4; j++) {
      int4 v = hp[j];
      hh[j * 4] = v.x; hh[j * 4 + 1] = v.y; hh[j * 4 + 2] = v.z; hh[j * 4 + 3] = v.w;
      int4 w = tp[j];
      tt[j * 4] = w.x; tt[j * 4 + 1] = w.y; tt[j * 4 + 2] = w.z; tt[j * 4 + 3] = w.w;
    }
  } else {
    for (int j = 0; j < nval; j++) { hh[j] = h[e0 + j]; tt[j] = t[e0 + j]; }
  }
  for (int j = 0; j < nval; j++) atomicAdd(&cnt[hh[j] >> 10], 1);
  __syncthreads();
  for (int b = threadIdx.x; b < NBUCK; b += 256) {
    int c = cnt[b];
    base[b] = c ? atomicAdd(&gcur[b], c) : 0;
    cnt[b] = 0;
  }
  __syncthreads();
  for (int j = 0; j < nval; j++) {
    int b = hh[j] >> 10;
    int r = atomicAdd(&cnt[b], 1);
    uint2 v; v.x = (unsigned)hh[j]; v.y = (unsigned)tt[j];
    part[(size_t)b * BCAP + base[b] + r] = v;
  }
}

__global__ __launch_bounds__(256) void k_count2(const uint2* __restrict__ part,
                                                const int* __restrict__ gcur,
                                                int* __restrict__ cnt_chunk) {
  __shared__ int hist[1024];
  int b = blockIdx.x, c = blockIdx.y, tid = threadIdx.x;
  for (int i = tid; i < 1024; i += 256) hist[i] = 0;
  __syncthreads();
  int m = gcur[b];
  int lo = (int)(((long long)m * c) >> 3);
  int hi = (int)(((long long)m * (c + 1)) >> 3);
  const uint2* pp = part + (size_t)b * BCAP;
  for (int i = lo + tid; i < hi; i += 256) atomicAdd(&hist[pp[i].x & 1023], 1);
  __syncthreads();
  int* dst = cnt_chunk + (((size_t)b * NCH + c) << 10);
  for (int i = tid; i < 1024; i += 256) dst[i] = hist[i];
}

__global__ __launch_bounds__(256) void k_node(int* __restrict__ cnt_chunk,
                                              int* __restrict__ rloc_g,
                                              float* __restrict__ d_inv,
                                              int* __restrict__ btot) {
  __shared__ int sd[256];
  int b = blockIdx.x, tid = threadIdx.x;
  int n0 = b << 10;
  int pd[4];
  int s = 0;
#pragma unroll
  for (int j = 0; j < 4; j++) {
    int idx = tid * 4 + j;
    int run = 0;
#pragma unroll
    for (int c = 0; c < NCH; c++) {
      size_t a = (((size_t)b * NCH + c) << 10) + idx;
      int v = cnt_chunk[a];
      cnt_chunk[a] = run;
      run += v;
    }
    int n = n0 + idx;
    if (n < NT) {
      d_inv[n] = 1.0f / sqrtf((float)run);  // deg >= 1 (self-loop)
      pd[j] = (run + 15) & ~15;
    } else pd[j] = 0;
    s += pd[j];
  }
  sd[tid] = s;
  __syncthreads();
  for (int o = 1; o < 256; o <<= 1) {
    int x = (tid >= o) ? sd[tid - o] : 0;
    __syncthreads();
    sd[tid] += x;
    __syncthreads();
  }
  int run2 = sd[tid] - s;
#pragma unroll
  for (int j = 0; j < 4; j++) {
    int idx = tid * 4 + j, n = n0 + idx;
    if (n < NT) rloc_g[n] = run2;
    run2 += pd[j];
  }
  if (tid == 255) btot[b] = sd[255];
}

__global__ void k_csr_base(const int* __restrict__ btot, int* __restrict__ bbase,
                           int* __restrict__ row_ptr) {
  __shared__ int sd[256];
  int t = threadIdx.x;
  int v = (t < NBUCK) ? btot[t] : 0;
  sd[t] = v;
  __syncthreads();
  for (int o = 1; o < 256; o <<= 1) {
    int x = (t >= o) ? sd[t - o] : 0;
    __syncthreads();
    sd[t] += x;
    __syncthreads();
  }
  if (t < NBUCK) bbase[t] = sd[t] - v;
  if (t == NBUCK - 1) row_ptr[NT] = sd[t];
}

__global__ void k_rowptr(const int* __restrict__ bbase, const int* __restrict__ rloc_g,
                         int* __restrict__ row_ptr) {
  int n = blockIdx.x * 256 + threadIdx.x;
  if (n < NT) row_ptr[n] = bbase[n >> 10] + rloc_g[n];
}

__global__ __launch_bounds__(256) void k_fill2(const uint2* __restrict__ part,
                                               const int* __restrict__ gcur,
                                               const int* __restrict__ chunkpre,
                                               const int* __restrict__ row_ptr,
                                               const float* __restrict__ d_inv,
                                               uint2* __restrict__ edges) {
  __shared__ int curs[1024];
  __shared__ float dl[1024];
  int b = blockIdx.x, c = blockIdx.y, tid = threadIdx.x;
  int n0 = b << 10;
  const int* pre = chunkpre + (((size_t)b * NCH + c) << 10);
  for (int i = tid; i < 1024; i += 256) {
    int n = n0 + i;
    if (n < NT) {
      curs[i] = row_ptr[n] + pre[i];
      dl[i] = d_inv[n];
    }
  }
  __syncthreads();
  int m = gcur[b];
  int lo = (int)(((long long)m * c) >> 3);
  int hi = (int)(((long long)m * (c + 1)) >> 3);
  const uint2* pp = part + (size_t)b * BCAP;
  for (int i = lo + tid; i < hi; i += 256) {
    uint2 pe = pp[i];
    int slot = atomicAdd(&curs[pe.x & 1023], 1);
    float g = dl[pe.x & 1023] * d_inv[pe.y];
    uint2 v; v.x = pe.y; v.y = __float_as_uint(g);
    edges[slot] = v;
  }
}

// ---------------- propagation ----------------
// cur/nxt rows: 64 fp8(e4m3) dims packed as 32 ushorts (dims 2l,2l+1 in
// ushort l) -> 64B row = ONE cache line per edge gather (bf16 was 2; round 11
// showed k_agg bound by outstanding-line concurrency x latency, not BW/VALU).
__global__ void k_init(const float2* __restrict__ ue, const float2* __restrict__ ie,
                       unsigned short* __restrict__ cur, int nU2, int nTot2) {
  int i = blockIdx.x * 256 + threadIdx.x;
  if (i >= nTot2) return;
  float2 v = (i < nU2) ? ue[i] : ie[i - nU2];
  int p = __builtin_amdgcn_cvt_pk_fp8_f32(v.x, v.y, 0, false);
  cur[i] = (unsigned short)p;
}

// wave = 2 half-waves; each half-wave serves one edge (64B fp8 row).
// Edge lists padded to x16 with (idx=0, g=0) -> branchless.
// Per-half direct uint2 edge loads (no cndmask extraction).
// NOTE: flat named registers only — register ARRAYS here spill (round 7).
__global__ __launch_bounds__(256) void k_agg(const int* __restrict__ row_ptr,
                                             const uint2* __restrict__ edges,
                                             const unsigned short* __restrict__ cur,
                                             unsigned short* __restrict__ nxt,
                                             float2* __restrict__ acc,
                                             const float2* __restrict__ egoU,
                                             const float2* __restrict__ egoI,
                                             int first) {
  int node = (blockIdx.x << 2) + (threadIdx.x >> 6);
  unsigned lane = threadIdx.x & 63;
  unsigned l32 = lane & 31;
  unsigned half = lane >> 5;
  int s = row_ptr[node], e = row_ptr[node + 1];
  float s0 = 0.f, s1 = 0.f;
  for (int i = s; i < e; i += 16) {
    const uint2* ep = edges + i + half;
    uint2 e0 = ep[0];
    uint2 e1 = ep[2];
    uint2 e2 = ep[4];
    uint2 e3 = ep[6];
    uint2 e4v = ep[8];
    uint2 e5 = ep[10];
    uint2 e6 = ep[12];
    uint2 e7 = ep[14];
    unsigned v0 = cur[(e0.x << 5) + l32];
    unsigned v1 = cur[(e1.x << 5) + l32];
    unsigned v2 = cur[(e2.x << 5) + l32];
    unsigned v3 = cur[(e3.x << 5) + l32];
    unsigned v4 = cur[(e4v.x << 5) + l32];
    unsigned v5 = cur[(e5.x << 5) + l32];
    unsigned v6 = cur[(e6.x << 5) + l32];
    unsigned v7 = cur[(e7.x << 5) + l32];
    float g0 = __uint_as_float(e0.y);
    float g1 = __uint_as_float(e1.y);
    float g2 = __uint_as_float(e2.y);
    float g3 = __uint_as_float(e3.y);
    float g4 = __uint_as_float(e4v.y);
    float g5 = __uint_as_float(e5.y);
    float g6 = __uint_as_float(e6.y);
    float g7 = __uint_as_float(e7.y);
    s0 = fmaf(g0, __builtin_amdgcn_cvt_f32_fp8(v0, 0), s0);
    s1 = fmaf(g0, __builtin_amdgcn_cvt_f32_fp8(v0, 1), s1);
    s0 = fmaf(g1, __builtin_amdgcn_cvt_f32_fp8(v1, 0), s0);
    s1 = fmaf(g1, __builtin_amdgcn_cvt_f32_fp8(v1, 1), s1);
    s0 = fmaf(g2, __builtin_amdgcn_cvt_f32_fp8(v2, 0), s0);
    s1 = fmaf(g2, __builtin_amdgcn_cvt_f32_fp8(v2, 1), s1);
    s0 = fmaf(g3, __builtin_amdgcn_cvt_f32_fp8(v3, 0), s0);
    s1 = fmaf(g3, __builtin_amdgcn_cvt_f32_fp8(v3, 1), s1);
    s0 = fmaf(g4, __builtin_amdgcn_cvt_f32_fp8(v4, 0), s0);
    s1 = fmaf(g4, __builtin_amdgcn_cvt_f32_fp8(v4, 1), s1);
    s0 = fmaf(g5, __builtin_amdgcn_cvt_f32_fp8(v5, 0), s0);
    s1 = fmaf(g5, __builtin_amdgcn_cvt_f32_fp8(v5, 1), s1);
    s0 = fmaf(g6, __builtin_amdgcn_cvt_f32_fp8(v6, 0), s0);
    s1 = fmaf(g6, __builtin_amdgcn_cvt_f32_fp8(v6, 1), s1);
    s0 = fmaf(g7, __builtin_amdgcn_cvt_f32_fp8(v7, 0), s0);
    s1 = fmaf(g7, __builtin_amdgcn_cvt_f32_fp8(v7, 1), s1);
  }
  s0 += __shfl_xor(s0, 32, 64);
  s1 += __shfl_xor(s1, 32, 64);
  unsigned ro = ((unsigned)node << 5) + l32;
  if (half == 0) {
    float2 base;
    if (first) {
      base = (node < NU) ? egoU[ro] : egoI[ro - (unsigned)NU * 32u];
    } else {
      base = acc[ro];
    }
    base.x += s0;
    base.y += s1;
    acc[ro] = base;
  } else {
    int p = __builtin_amdgcn_cvt_pk_fp8_f32(s0, s1, 0, false);
    nxt[ro] = (unsigned short)p;
  }
}

// ---------------- losses ----------------
// KL via MFMA; grid-stride + one atomic per block (round 11: per-wave
// same-address double atomics serialized at ~31 cy = 121 us wall).
__global__ __launch_bounds__(256) void k_kl(const float* __restrict__ acc,
                                            const float* __restrict__ lin_w,
                                            const float* __restrict__ lin_b,
                                            double* __restrict__ accums) {
  __shared__ double red[4];
  int lane = threadIdx.x & 63;
  int wid = threadIdx.x >> 6;
  int n = lane & 15, q = lane >> 4;
  bf16x8 B0, B1, B2, B3;
  float lb0, lb1, lb2, lb3;
  {
    const float* w0 = lin_w + (0 * 16 + n) * 32 + q * 8;
    const float* w1 = lin_w + (1 * 16 + n) * 32 + q * 8;
    const float* w2 = lin_w + (2 * 16 + n) * 32 + q * 8;
    const float* w3 = lin_w + (3 * 16 + n) * 32 + q * 8;
#pragma unroll
    for (int j = 0; j < 8; j++) {
      B0[j] = (short)f2b(w0[j]);
      B1[j] = (short)f2b(w1[j]);
      B2[j] = (short)f2b(w2[j]);
      B3[j] = (short)f2b(w3[j]);
    }
    lb0 = lin_b[0 * 16 + n] + 1e-8f;
    lb1 = lin_b[1 * 16 + n] + 1e-8f;
    lb2 = lin_b[2 * 16 + n] + 1e-8f;
    lb3 = lin_b[3 * 16 + n] + 1e-8f;
  }
  const int TI = NT / 16;
  int w0id = blockIdx.x * 4 + wid;
  int nwv = gridDim.x * 4;
  double dsum = 0.0;
  for (int tile = w0id; tile < TI; tile += nwv) {
    const float* rowp = acc + (size_t)(tile * 16 + n) * 64 + q * 8;
    float4 a0 = *(const float4*)rowp;
    float4 a1 = *(const float4*)(rowp + 4);
    float4 b0 = *(const float4*)(rowp + 32);
    float4 b1 = *(const float4*)(rowp + 36);
    float msum = a0.x * a0.x + a0.y * a0.y + a0.z * a0.z + a0.w * a0.w
               + a1.x * a1.x + a1.y * a1.y + a1.z * a1.z + a1.w * a1.w
               + b0.x * b0.x + b0.y * b0.y + b0.z * b0.z + b0.w * b0.w
               + b1.x * b1.x + b1.y * b1.y + b1.z * b1.z + b1.w * b1.w;
    bf16x8 Af;
    Af[0] = (short)f2b(softplusf(a0.x));
    Af[1] = (short)f2b(softplusf(a0.y));
    Af[2] = (short)f2b(softplusf(a0.z));
    Af[3] = (short)f2b(softplusf(a0.w));
    Af[4] = (short)f2b(softplusf(a1.x));
    Af[5] = (short)f2b(softplusf(a1.y));
    Af[6] = (short)f2b(softplusf(a1.z));
    Af[7] = (short)f2b(softplusf(a1.w));
    f32x4 z = {0.f, 0.f, 0.f, 0.f};
    f32x4 c0 = __builtin_amdgcn_mfma_f32_16x16x32_bf16(Af, B0, z, 0, 0, 0);
    f32x4 c1 = __builtin_amdgcn_mfma_f32_16x16x32_bf16(Af, B1, z, 0, 0, 0);
    f32x4 c2 = __builtin_amdgcn_mfma_f32_16x16x32_bf16(Af, B2, z, 0, 0, 0);
    f32x4 c3 = __builtin_amdgcn_mfma_f32_16x16x32_bf16(Af, B3, z, 0, 0, 0);
    float ksum = 0.f;
#pragma unroll
    for (int r = 0; r < 4; r++) {
      float s0 = c0[r] + lb0, s1 = c1[r] + lb1, s2 = c2[r] + lb2, s3 = c3[r] + lb3;
      ksum += -0.5f * (1.f + 2.f * s0 - __expf(2.f * s0));
      ksum += -0.5f * (1.f + 2.f * s1 - __expf(2.f * s1));
      ksum += -0.5f * (1.f + 2.f * s2 - __expf(2.f * s2));
      ksum += -0.5f * (1.f + 2.f * s3 - __expf(2.f * s3));
    }
    dsum += (double)wsum(ksum + 0.5f * msum);
  }
  if (lane == 0) red[wid] = dsum;
  __syncthreads();
  if (threadIdx.x == 0)
    atomicAdd(&accums[1], red[0] + red[1] + red[2] + red[3]);
}

__global__ __launch_bounds__(256) void k_batch_user(
    const float* __restrict__ acc, const float* __restrict__ user_emb,
    const float* __restrict__ eps, const float* __restrict__ intent,
    const float* __restrict__ lin_w, const float* __restrict__ lin_b,
    const int* __restrict__ users, const int* __restrict__ pos_items,
    const int* __restrict__ neg_items,
    float* __restrict__ gen_o, float* __restrict__ int_o,
    unsigned short* __restrict__ gen_b, unsigned short* __restrict__ int_b,
    double* __restrict__ accums) {
  __shared__ float ui[64 * 130];
  __shared__ float lw[64 * 33];
  __shared__ float lb[64];
  __shared__ double red[8];
  for (int i = threadIdx.x; i < 64 * 128; i += 256) ui[(i >> 7) * 130 + (i & 127)] = intent[i];
  for (int i = threadIdx.x; i < 64 * 32; i += 256) lw[(i >> 5) * 33 + (i & 31)] = lin_w[i];
  if (threadIdx.x < 64) lb[threadIdx.x] = lin_b[threadIdx.x];
  __syncthreads();
  int lane = threadIdx.x & 63;
  int wid = threadIdx.x >> 6;
  int b = (blockIdx.x << 2) + wid;
  int u = users[b];
  float m = acc[u * 64 + lane];
  int k0 = lane * 2;
  float l0 = 0.f, l1 = 0.f;
  for (int d = 0; d < 64; d++) {
    float md = __shfl(m, d, 64);
    l0 = fmaf(md, ui[d * 130 + k0], l0);
    l1 = fmaf(md, ui[d * 130 + k0 + 1], l1);
  }
  float mx = wmax(fmaxf(l0, l1));
  float p0 = expf(l0 - mx), p1 = expf(l1 - mx);
  float tot = wsum(p0 + p1);
  p0 /= tot; p1 /= tot;
  float s = 0.f;
  for (int k = 0; k < 128; k++) {
    float pk = __shfl((k & 1) ? p1 : p0, k >> 1, 64);
    s = fmaf(pk, ui[lane * 130 + k], s);
  }
  float nrm = sqrtf(wsum(s * s));
  float io = s / nrm;
  int_o[b * 64 + lane] = io;
  int_b[b * 64 + lane] = f2b(io);
  float sp = softplusf(m);
  float sd = lb[lane] + 1e-8f;
#pragma unroll
  for (int j = 0; j < 32; j++) sd = fmaf(__shfl(sp, j, 64), lw[lane * 33 + j], sd);
  float ge = m + eps[u * 64 + lane] * sd;
  float gn = sqrtf(wsum(ge * ge));
  float go = ge / gn;
  gen_o[b * 64 + lane] = go;
  gen_b[b * 64 + lane] = f2b(go);
  int pi = pos_items[b], ni = neg_items[b];
  float pv = acc[(NU + pi) * 64 + lane];
  float nv = acc[(NU + ni) * 64 + lane];
  float ps = wsum(m * pv);
  float ns = wsum(m * nv);
  float bpr = softplusf(ns - ps);
  float ue = user_emb[u * 64 + lane];
  float es = wsum(ue * ue);
  if (lane == 0) { red[wid] = (double)bpr; red[4 + wid] = (double)es; }
  __syncthreads();
  if (threadIdx.x == 0) {
    atomicAdd(&accums[0], red[0] + red[1] + red[2] + red[3]);
    atomicAdd(&accums[2], red[4] + red[5] + red[6] + red[7]);
  }
}

__global__ __launch_bounds__(256) void k_batch_item(
    const float* __restrict__ acc, const float* __restrict__ item_emb,
    const float* __restrict__ eps, const float* __restrict__ intent,
    const float* __restrict__ lin_w, const float* __restrict__ lin_b,
    const int* __restrict__ pos_items, const int* __restrict__ neg_items,
    float* __restrict__ gen_o, float* __restrict__ int_o,
    unsigned short* __restrict__ gen_b, unsigned short* __restrict__ int_b,
    double* __restrict__ accums) {
  __shared__ float ui[64 * 130];
  __shared__ float lw[64 * 33];
  __shared__ float lb[64];
  __shared__ double red[4];
  for (int i = threadIdx.x; i < 64 * 128; i += 256) ui[(i >> 7) * 130 + (i & 127)] = intent[i];
  for (int i = threadIdx.x; i < 64 * 32; i += 256) lw[(i >> 5) * 33 + (i & 31)] = lin_w[i];
  if (threadIdx.x < 64) lb[threadIdx.x] = lin_b[threadIdx.x];
  __syncthreads();
  int lane = threadIdx.x & 63;
  int wid = threadIdx.x >> 6;
  int b = (blockIdx.x << 2) + wid;
  int pi = pos_items[b], ni = neg_items[b];
  int row = NU + pi;
  float m = acc[row * 64 + lane];
  int k0 = lane * 2;
  float l0 = 0.f, l1 = 0.f;
  for (int d = 0; d < 64; d++) {
    float md = __shfl(m, d, 64);
    l0 = fmaf(md, ui[d * 130 + k0], l0);
    l1 = fmaf(md, ui[d * 130 + k0 + 1], l1);
  }
  float mx = wmax(fmaxf(l0, l1));
  float p0 = expf(l0 - mx), p1 = expf(l1 - mx);
  float tot = wsum(p0 + p1);
  p0 /= tot; p1 /= tot;
  float s = 0.f;
  for (int k = 0; k < 128; k++) {
    float pk = __shfl((k & 1) ? p1 : p0, k >> 1, 64);
    s = fmaf(pk, ui[lane * 130 + k], s);
  }
  float nrm = sqrtf(wsum(s * s));
  float io = s / nrm;
  int_o[b * 64 + lane] = io;
  int_b[b * 64 + lane] = f2b(io);
  float sp = softplusf(m);
  float sd = lb[lane] + 1e-8f;
#pragma unroll
  for (int j = 0; j < 32; j++) sd = fmaf(__shfl(sp, j, 64), lw[lane * 33 + j], sd);
  float ge = m + eps[row * 64 + lane] * sd;
  float gn = sqrtf(wsum(ge * ge));
  float go = ge / gn;
  gen_o[b * 64 + lane] = go;
  gen_b[b * 64 + lane] = f2b(go);
  float a0 = item_emb[pi * 64 + lane];
  float a1 = item_emb[ni * 64 + lane];
  float es = wsum(a0 * a0 + a1 * a1);
  if (lane == 0) red[wid] = (double)es;
  __syncthreads();
  if (threadIdx.x == 0) atomicAdd(&accums[2], red[0] + red[1] + red[2] + red[3]);
}

// ---------------- InfoNCE negatives via bf16 MFMA ----------------
__global__ __launch_bounds__(256) void k_nce_mfma(
    const unsigned short* __restrict__ e1u, const unsigned short* __restrict__ e2u,
    const unsigned short* __restrict__ e1i, const unsigned short* __restrict__ e2i,
    float* __restrict__ negu, float* __restrict__ negi) {
  int pair = blockIdx.y >> 2, jq = blockIdx.y & 3;
  const unsigned short* e1 = pair ? e1i : e1u;
  const unsigned short* e2 = pair ? e2i : e2u;
  float* nego = pair ? negi : negu;
  int wid = threadIdx.x >> 6, lane = threadIdx.x & 63;
  int q = lane >> 4, n = lane & 15;
  int i0 = blockIdx.x * 64 + wid * 16;
  const bf16x8* arow = (const bf16x8*)(e1 + (size_t)(i0 + n) * 64 + q * 8);
  bf16x8 a0 = arow[0];
  bf16x8 a1 = arow[4];
  f32x4 accv = {0.f, 0.f, 0.f, 0.f};
  int j0 = jq * 1024;
  for (int jt = 0; jt < 64; jt++) {
    const bf16x8* brow = (const bf16x8*)(e2 + (size_t)(j0 + jt * 16 + n) * 64 + q * 8);
    bf16x8 b0 = brow[0];
    bf16x8 b1 = brow[4];
    f32x4 c = {0.f, 0.f, 0.f, 0.f};
    c = __builtin_amdgcn_mfma_f32_16x16x32_bf16(a0, b0, c, 0, 0, 0);
    c = __builtin_amdgcn_mfma_f32_16x16x32_bf16(a1, b1, c, 0, 0, 0);
#pragma unroll
    for (int r = 0; r < 4; r++) accv[r] += __expf(5.0f * c[r]);
  }
#pragma unroll
  for (int o = 1; o < 16; o <<= 1) {
#pragma unroll
    for (int r = 0; r < 4; r++) accv[r] += __shfl_xor(accv[r], o, 64);
  }
  if (n == 0) {
#pragma unroll
    for (int r = 0; r < 4; r++) atomicAdd(&nego[i0 + q * 4 + r], accv[r]);
  }
}

__global__ __launch_bounds__(256) void k_nce_final(
    const float* __restrict__ ugen, const float* __restrict__ uio,
    const float* __restrict__ igen, const float* __restrict__ iio,
    const float* __restrict__ negu, const float* __restrict__ negi,
    double* __restrict__ accums) {
  __shared__ double red[4];
  int lane = threadIdx.x & 63, wid = threadIdx.x >> 6;
  int w = blockIdx.x * 4 + wid;
  int pair = w >> 12, i = w & 4095;
  const float* e1 = pair ? igen : ugen;
  const float* e2 = pair ? iio : uio;
  const float* ng = pair ? negi : negu;
  float dot = wsum(e1[i * 64 + lane] * e2[i * 64 + lane]);
  if (lane == 0) {
    float pos = expf(dot * 5.f);
    red[wid] = (double)(-logf(pos / (ng[i] + 1e-8f) + 1e-8f));
  }
  __syncthreads();
  if (threadIdx.x == 0) atomicAdd(&accums[4], red[0] + red[1] + red[2] + red[3]);
}

// final: also folds the tiny int_loss reduction (was k_int, saves a launch)
__global__ __launch_bounds__(256) void k_fin(const float* __restrict__ ui,
                                             const float* __restrict__ ii,
                                             const double* __restrict__ accums,
                                             float* __restrict__ out) {
  __shared__ float red[4];
  float s = 0.f;
  for (int i = threadIdx.x; i < 64 * 128; i += 256) {
    float a = ui[i], b = ii[i];
    s = fmaf(a, a, s);
    s = fmaf(b, b, s);
  }
  s = wsum(s);
  if ((threadIdx.x & 63) == 0) red[threadIdx.x >> 6] = s;
  __syncthreads();
  if (threadIdx.x == 0) {
    double ints = (double)(red[0] + red[1] + red[2] + red[3]);
    double bpr = accums[0] / (double)BB;
    double kl = 0.01 * accums[1] / (double)NT;
    out[0] = (float)(bpr + kl);
    out[1] = (float)(0.1 * accums[4] / (double)BB);
    out[2] = (float)(1e-5 * accums[2]);
    out[3] = (float)(1e-5 * ints);
  }
}

extern "C" void kernel_launch(void* const* d_in, const int* in_sizes, int n_in,
                              void* d_out, int out_size, void* d_ws, size_t ws_size,
                              hipStream_t stream) {
  const float* user_emb = (const float*)d_in[0];
  const float* item_emb = (const float*)d_in[1];
  const float* user_int = (const float*)d_in[2];
  const float* item_int = (const float*)d_in[3];
  const float* lin_w = (const float*)d_in[4];
  const float* lin_b = (const float*)d_in[5];
  const float* eps = (const float*)d_in[6];
  const int* h_list = (const int*)d_in[7];
  const int* t_list = (const int*)d_in[8];
  const int* users = (const int*)d_in[9];
  const int* pos_items = (const int*)d_in[10];
  const int* neg_items = (const int*)d_in[11];
  float* out = (float*)d_out;
  const int E = in_sizes[7];
  const size_t Ecap = (size_t)E + 16 * (size_t)NT;  // x16-padded capacity

  char* ws = (char*)d_ws;
  size_t off = 0;
  auto take = [&](size_t bytes) -> char* {
    char* p = ws + off;
    off = (off + bytes + 255) & ~(size_t)255;
    return p;
  };
  int* row_ptr = (int*)take((size_t)(NT + 1) * 4);
  float* d_inv = (float*)take((size_t)NT * 4);
  int* rloc_g = (int*)take((size_t)NT * 4);
  int* cnt_chunk = (int*)take((size_t)NBUCK * NCH * 1024 * 4);
  int* gcur = (int*)take(NBUCK * 4);
  int* btot = (int*)take(NBUCK * 4);
  int* bbase = (int*)take(NBUCK * 4);
  uint2* edges = (uint2*)take(Ecap * 8);
  unsigned short* bufA = (unsigned short*)take((size_t)NT * 32 * 2);  // fp8 rows
  unsigned short* bufB = (unsigned short*)take((size_t)NT * 32 * 2);
  float* acc = (float*)take((size_t)NT * 64 * 4);
  float* ugen = (float*)take((size_t)BB * 64 * 4);
  float* igen = (float*)take((size_t)BB * 64 * 4);
  float* uio = (float*)take((size_t)BB * 64 * 4);
  float* iio = (float*)take((size_t)BB * 64 * 4);
  unsigned short* ugen_b = (unsigned short*)take((size_t)BB * 64 * 2);
  unsigned short* igen_b = (unsigned short*)take((size_t)BB * 64 * 2);
  unsigned short* uio_b = (unsigned short*)take((size_t)BB * 64 * 2);
  unsigned short* iio_b = (unsigned short*)take((size_t)BB * 64 * 2);
  float* negu = (float*)take((size_t)BB * 4);
  float* negi = (float*)take((size_t)BB * 4);
  double* accums = (double*)take(64);
  if (off > ws_size) return;
  // part[] (28.9 MB) aliases acc (38.4 MB): part's last read is k_fill2;
  // acc is first WRITTEN in k_agg#1 (first=1 -> no acc read). bufA/bufB are
  // now fp8 (9.6 MB each) and too small to host part.
  uint2* part = (uint2*)acc;

  hipMemsetAsync(gcur, 0, NBUCK * 4, stream);
  hipMemsetAsync(edges, 0, Ecap * 8, stream);  // pad slots: idx 0, g = 0
  hipMemsetAsync(negu, 0, (size_t)BB * 4, stream);
  hipMemsetAsync(negi, 0, (size_t)BB * 4, stream);
  hipMemsetAsync(accums, 0, 64, stream);

  int gridP = (E + 4095) / 4096;
  k_part<<<gridP, 256, 0, stream>>>(h_list, t_list, gcur, part, E);
  k_count2<<<dim3(NBUCK, NCH), 256, 0, stream>>>(part, gcur, cnt_chunk);
  k_node<<<NBUCK, 256, 0, stream>>>(cnt_chunk, rloc_g, d_inv, btot);
  k_csr_base<<<1, 256, 0, stream>>>(btot, bbase, row_ptr);
  k_rowptr<<<(NT + 255) / 256, 256, 0, stream>>>(bbase, rloc_g, row_ptr);
  k_fill2<<<dim3(NBUCK, NCH), 256, 0, stream>>>(part, gcur, cnt_chunk, row_ptr,
                                                d_inv, edges);

  int nU2 = NU * 32, nTot2 = NT * 32;
  k_init<<<(nTot2 + 255) / 256, 256, 0, stream>>>((const float2*)user_emb,
                                                  (const float2*)item_emb, bufA, nU2, nTot2);
  int gridAgg = NT / 4;
  k_agg<<<gridAgg, 256, 0, stream>>>(row_ptr, edges, bufA, bufB, (float2*)acc,
                                     (const float2*)user_emb, (const float2*)item_emb, 1);
  k_agg<<<gridAgg, 256, 0, stream>>>(row_ptr, edges, bufB, bufA, (float2*)acc,
                                     (const float2*)user_emb, (const float2*)item_emb, 0);
  k_agg<<<gridAgg, 256, 0, stream>>>(row_ptr, edges, bufA, bufB, (float2*)acc,
                                     (const float2*)user_emb, (const float2*)item_emb, 0);

  k_kl<<<640, 256, 0, stream>>>(acc, lin_w, lin_b, accums);
  k_batch_user<<<BB / 4, 256, 0, stream>>>(acc, user_emb, eps, user_int, lin_w, lin_b,
                                           users, pos_items, neg_items,
                                           ugen, uio, ugen_b, uio_b, accums);
  k_batch_item<<<BB / 4, 256, 0, stream>>>(acc, item_emb, eps, item_int, lin_w, lin_b,
                                           pos_items, neg_items,
                                           igen, iio, igen_b, iio_b, accums);
  k_nce_mfma<<<dim3(64, 8), 256, 0, stream>>>(ugen_b, uio_b, igen_b, iio_b, negu, negi);
  k_nce_final<<<(2 * BB) / 4, 256, 0, stream>>>(ugen, uio, igen, iio, negu, negi, accums);
  k_fin<<<1, 256, 0, stream>>>(user_int, item_int, accums, out);
}

// Round 13
// 586.213 us; speedup vs baseline: 1.3195x; 1.1355x over previous
//
#include <hip/hip_runtime.h>

#define NU 50000
#define NI 100000
#define NT 150000
#define BB 4096
#define NBUCK 147   // ceil(NT/1024)
#define BCAP 24576  // per-bucket edge capacity: mean 21504, sd ~143 -> +21 sigma
#define NCH 8       // chunks per bucket in CSR build

typedef __attribute__((ext_vector_type(8))) short bf16x8;
typedef __attribute__((ext_vector_type(4))) float f32x4;

__device__ __forceinline__ float softplusf(float x) {
  return fmaxf(x, 0.f) + log1pf(expf(-fabsf(x)));
}
__device__ __forceinline__ float wsum(float v) {
#pragma unroll
  for (int o = 32; o > 0; o >>= 1) v += __shfl_xor(v, o, 64);
  return v;
}
__device__ __forceinline__ float wmax(float v) {
#pragma unroll
  for (int o = 32; o > 0; o >>= 1) v = fmaxf(v, __shfl_xor(v, o, 64));
  return v;
}
__device__ __forceinline__ unsigned short f2b(float x) {
  unsigned u = __float_as_uint(x);
  return (unsigned short)((u + 0x7FFFu + ((u >> 16) & 1u)) >> 16);
}

// ---------------- CSR build ----------------
__global__ __launch_bounds__(256) void k_part(const int* __restrict__ h,
                                              const int* __restrict__ t,
                                              int* __restrict__ gcur,
                                              uint2* __restrict__ part, int E) {
  __shared__ int cnt[NBUCK];
  __shared__ int base[NBUCK];
  for (int b = threadIdx.x; b < NBUCK; b += 256) cnt[b] = 0;
  __syncthreads();
  int e0 = blockIdx.x * 4096 + threadIdx.x * 16;
  int nval = E - e0;
  nval = nval < 0 ? 0 : (nval > 16 ? 16 : nval);
  int hh[16], tt[16];
  if (nval == 16) {
    const int4* hp = (const int4*)(h + e0);
    const int4* tp = (const int4*)(t + e0);
#pragma unroll
    for (int j = 0; j < 4; j++) {
      int4 v = hp[j];
      hh[j * 4] = v.x; hh[j * 4 + 1] = v.y; hh[j * 4 + 2] = v.z; hh[j * 4 + 3] = v.w;
      int4 w = tp[j];
      tt[j * 4] = w.x; tt[j * 4 + 1] = w.y; tt[j * 4 + 2] = w.z; tt[j * 4 + 3] = w.w;
    }
  } else {
    for (int j = 0; j < nval; j++) { hh[j] = h[e0 + j]; tt[j] = t[e0 + j]; }
  }
  for (int j = 0; j < nval; j++) atomicAdd(&cnt[hh[j] >> 10], 1);
  __syncthreads();
  for (int b = threadIdx.x; b < NBUCK; b += 256) {
    int c = cnt[b];
    base[b] = c ? atomicAdd(&gcur[b], c) : 0;
    cnt[b] = 0;
  }
  __syncthreads();
  for (int j = 0; j < nval; j++) {
    int b = hh[j] >> 10;
    int r = atomicAdd(&cnt[b], 1);
    uint2 v; v.x = (unsigned)hh[j]; v.y = (unsigned)tt[j];
    part[(size_t)b * BCAP + base[b] + r] = v;
  }
}

__global__ __launch_bounds__(256) void k_count2(const uint2* __restrict__ part,
                                                const int* __restrict__ gcur,
                                                int* __restrict__ cnt_chunk) {
  __shared__ int hist[1024];
  int b = blockIdx.x, c = blockIdx.y, tid = threadIdx.x;
  for (int i = tid; i < 1024; i += 256) hist[i] = 0;
  __syncthreads();
  int m = gcur[b];
  int lo = (int)(((long long)m * c) >> 3);
  int hi = (int)(((long long)m * (c + 1)) >> 3);
  const uint2* pp = part + (size_t)b * BCAP;
  for (int i = lo + tid; i < hi; i += 256) atomicAdd(&hist[pp[i].x & 1023], 1);
  __syncthreads();
  int* dst = cnt_chunk + (((size_t)b * NCH + c) << 10);
  for (int i = tid; i < 1024; i += 256) dst[i] = hist[i];
}

__global__ __launch_bounds__(256) void k_node(int* __restrict__ cnt_chunk,
                                              int* __restrict__ rloc_g,
                                              float* __restrict__ d_inv,
                                              int* __restrict__ btot) {
  __shared__ int sd[256];
  int b = blockIdx.x, tid = threadIdx.x;
  int n0 = b << 10;
  int pd[4];
  int s = 0;
#pragma unroll
  for (int j = 0; j < 4; j++) {
    int idx = tid * 4 + j;
    int run = 0;
#pragma unroll
    for (int c = 0; c < NCH; c++) {
      size_t a = (((size_t)b * NCH + c) << 10) + idx;
      int v = cnt_chunk[a];
      cnt_chunk[a] = run;
      run += v;
    }
    int n = n0 + idx;
    if (n < NT) {
      d_inv[n] = 1.0f / sqrtf((float)run);  // deg >= 1 (self-loop)
      pd[j] = (run + 15) & ~15;
    } else pd[j] = 0;
    s += pd[j];
  }
  sd[tid] = s;
  __syncthreads();
  for (int o = 1; o < 256; o <<= 1) {
    int x = (tid >= o) ? sd[tid - o] : 0;
    __syncthreads();
    sd[tid] += x;
    __syncthreads();
  }
  int run2 = sd[tid] - s;
#pragma unroll
  for (int j = 0; j < 4; j++) {
    int idx = tid * 4 + j, n = n0 + idx;
    if (n < NT) rloc_g[n] = run2;
    run2 += pd[j];
  }
  if (tid == 255) btot[b] = sd[255];
}

__global__ void k_csr_base(const int* __restrict__ btot, int* __restrict__ bbase,
                           int* __restrict__ row_ptr) {
  __shared__ int sd[256];
  int t = threadIdx.x;
  int v = (t < NBUCK) ? btot[t] : 0;
  sd[t] = v;
  __syncthreads();
  for (int o = 1; o < 256; o <<= 1) {
    int x = (t >= o) ? sd[t - o] : 0;
    __syncthreads();
    sd[t] += x;
    __syncthreads();
  }
  if (t < NBUCK) bbase[t] = sd[t] - v;
  if (t == NBUCK - 1) row_ptr[NT] = sd[t];
}

__global__ void k_rowptr(const int* __restrict__ bbase, const int* __restrict__ rloc_g,
                         int* __restrict__ row_ptr) {
  int n = blockIdx.x * 256 + threadIdx.x;
  if (n < NT) row_ptr[n] = bbase[n >> 10] + rloc_g[n];
}

__global__ __launch_bounds__(256) void k_fill2(const uint2* __restrict__ part,
                                               const int* __restrict__ gcur,
                                               const int* __restrict__ chunkpre,
                                               const int* __restrict__ row_ptr,
                                               const float* __restrict__ d_inv,
                                               uint2* __restrict__ edges) {
  __shared__ int curs[1024];
  __shared__ float dl[1024];
  int b = blockIdx.x, c = blockIdx.y, tid = threadIdx.x;
  int n0 = b << 10;
  const int* pre = chunkpre + (((size_t)b * NCH + c) << 10);
  for (int i = tid; i < 1024; i += 256) {
    int n = n0 + i;
    if (n < NT) {
      curs[i] = row_ptr[n] + pre[i];
      dl[i] = d_inv[n];
    }
  }
  __syncthreads();
  int m = gcur[b];
  int lo = (int)(((long long)m * c) >> 3);
  int hi = (int)(((long long)m * (c + 1)) >> 3);
  const uint2* pp = part + (size_t)b * BCAP;
  for (int i = lo + tid; i < hi; i += 256) {
    uint2 pe = pp[i];
    int slot = atomicAdd(&curs[pe.x & 1023], 1);
    float g = dl[pe.x & 1023] * d_inv[pe.y];
    uint2 v; v.x = pe.y; v.y = __float_as_uint(g);
    edges[slot] = v;
  }
}

// ---------------- propagation ----------------
// cur/nxt rows: 64 fp8(e4m3) dims packed as 16 dwords (dims 4d..4d+3 in
// dword d) -> 64B row, ONE line per edge, FOUR rows per wave64 dword-gather.
__global__ void k_init(const float4* __restrict__ ue, const float4* __restrict__ ie,
                       unsigned* __restrict__ cur, int nU4, int nTot4) {
  int i = blockIdx.x * 256 + threadIdx.x;
  if (i >= nTot4) return;
  float4 v = (i < nU4) ? ue[i] : ie[i - nU4];
  int p = __builtin_amdgcn_cvt_pk_fp8_f32(v.x, v.y, 0, false);
  p = __builtin_amdgcn_cvt_pk_fp8_f32(v.z, v.w, p, true);
  cur[i] = (unsigned)p;
}

// wave = 4 quarter-groups; lane = (g = edge-group 0..3, d = dword 0..15).
// One dword-gather instruction serves 4 edges (16 lanes x 4B = full 64B row).
// Per 16-edge iteration: 4 edge-record loads + 4 gathers = 8 vmem instrs
// (rounds 11/12 had 16 -> vmem-instruction pipeline was the binder; byte
// halvings at constant instr count changed nothing).
// Edge lists padded to x16 with (idx=0, g=0) -> branchless.
// NOTE: flat named registers only — register ARRAYS here spill (round 7).
__global__ __launch_bounds__(256) void k_agg(const int* __restrict__ row_ptr,
                                             const uint2* __restrict__ edges,
                                             const unsigned* __restrict__ cur,
                                             unsigned* __restrict__ nxt,
                                             float4* __restrict__ acc4,
                                             const float4* __restrict__ egoU,
                                             const float4* __restrict__ egoI,
                                             int first) {
  int node = (blockIdx.x << 2) + (threadIdx.x >> 6);
  unsigned lane = threadIdx.x & 63;
  unsigned d = lane & 15;
  unsigned g = lane >> 4;
  int s = row_ptr[node], e = row_ptr[node + 1];
  float a0 = 0.f, a1 = 0.f, a2 = 0.f, a3 = 0.f;
  for (int i = s; i < e; i += 16) {
    const uint2* ep = edges + i + g;
    uint2 e0 = ep[0];
    uint2 e1 = ep[4];
    uint2 e2 = ep[8];
    uint2 e3 = ep[12];
    unsigned v0 = cur[(e0.x << 4) + d];
    unsigned v1 = cur[(e1.x << 4) + d];
    unsigned v2 = cur[(e2.x << 4) + d];
    unsigned v3 = cur[(e3.x << 4) + d];
    float g0 = __uint_as_float(e0.y);
    float g1 = __uint_as_float(e1.y);
    float g2 = __uint_as_float(e2.y);
    float g3 = __uint_as_float(e3.y);
    a0 = fmaf(g0, __builtin_amdgcn_cvt_f32_fp8(v0, 0), a0);
    a1 = fmaf(g0, __builtin_amdgcn_cvt_f32_fp8(v0, 1), a1);
    a2 = fmaf(g0, __builtin_amdgcn_cvt_f32_fp8(v0, 2), a2);
    a3 = fmaf(g0, __builtin_amdgcn_cvt_f32_fp8(v0, 3), a3);
    a0 = fmaf(g1, __builtin_amdgcn_cvt_f32_fp8(v1, 0), a0);
    a1 = fmaf(g1, __builtin_amdgcn_cvt_f32_fp8(v1, 1), a1);
    a2 = fmaf(g1, __builtin_amdgcn_cvt_f32_fp8(v1, 2), a2);
    a3 = fmaf(g1, __builtin_amdgcn_cvt_f32_fp8(v1, 3), a3);
    a0 = fmaf(g2, __builtin_amdgcn_cvt_f32_fp8(v2, 0), a0);
    a1 = fmaf(g2, __builtin_amdgcn_cvt_f32_fp8(v2, 1), a1);
    a2 = fmaf(g2, __builtin_amdgcn_cvt_f32_fp8(v2, 2), a2);
    a3 = fmaf(g2, __builtin_amdgcn_cvt_f32_fp8(v2, 3), a3);
    a0 = fmaf(g3, __builtin_amdgcn_cvt_f32_fp8(v3, 0), a0);
    a1 = fmaf(g3, __builtin_amdgcn_cvt_f32_fp8(v3, 1), a1);
    a2 = fmaf(g3, __builtin_amdgcn_cvt_f32_fp8(v3, 2), a2);
    a3 = fmaf(g3, __builtin_amdgcn_cvt_f32_fp8(v3, 3), a3);
  }
  // butterfly across the 4 edge-groups: all lanes end with full dim sums
  a0 += __shfl_xor(a0, 16, 64);
  a1 += __shfl_xor(a1, 16, 64);
  a2 += __shfl_xor(a2, 16, 64);
  a3 += __shfl_xor(a3, 16, 64);
  a0 += __shfl_xor(a0, 32, 64);
  a1 += __shfl_xor(a1, 32, 64);
  a2 += __shfl_xor(a2, 32, 64);
  a3 += __shfl_xor(a3, 32, 64);
  unsigned ro = ((unsigned)node << 4) + d;
  if (g == 0) {
    float4 base;
    if (first) {
      base = (node < NU) ? egoU[ro] : egoI[ro - (unsigned)NU * 16u];
    } else {
      base = acc4[ro];
    }
    base.x += a0;
    base.y += a1;
    base.z += a2;
    base.w += a3;
    acc4[ro] = base;
  } else if (g == 1) {
    int p = __builtin_amdgcn_cvt_pk_fp8_f32(a0, a1, 0, false);
    p = __builtin_amdgcn_cvt_pk_fp8_f32(a2, a3, p, true);
    nxt[ro] = (unsigned)p;
  }
}

// ---------------- losses ----------------
// KL via MFMA; grid-stride + one atomic per block (round 11: per-wave
// same-address double atomics serialized at ~31 cy = 121 us wall).
__global__ __launch_bounds__(256) void k_kl(const float* __restrict__ acc,
                                            const float* __restrict__ lin_w,
                                            const float* __restrict__ lin_b,
                                            double* __restrict__ accums) {
  __shared__ double red[4];
  int lane = threadIdx.x & 63;
  int wid = threadIdx.x >> 6;
  int n = lane & 15, q = lane >> 4;
  bf16x8 B0, B1, B2, B3;
  float lb0, lb1, lb2, lb3;
  {
    const float* w0 = lin_w + (0 * 16 + n) * 32 + q * 8;
    const float* w1 = lin_w + (1 * 16 + n) * 32 + q * 8;
    const float* w2 = lin_w + (2 * 16 + n) * 32 + q * 8;
    const float* w3 = lin_w + (3 * 16 + n) * 32 + q * 8;
#pragma unroll
    for (int j = 0; j < 8; j++) {
      B0[j] = (short)f2b(w0[j]);
      B1[j] = (short)f2b(w1[j]);
      B2[j] = (short)f2b(w2[j]);
      B3[j] = (short)f2b(w3[j]);
    }
    lb0 = lin_b[0 * 16 + n] + 1e-8f;
    lb1 = lin_b[1 * 16 + n] + 1e-8f;
    lb2 = lin_b[2 * 16 + n] + 1e-8f;
    lb3 = lin_b[3 * 16 + n] + 1e-8f;
  }
  const int TI = NT / 16;
  int w0id = blockIdx.x * 4 + wid;
  int nwv = gridDim.x * 4;
  double dsum = 0.0;
  for (int tile = w0id; tile < TI; tile += nwv) {
    const float* rowp = acc + (size_t)(tile * 16 + n) * 64 + q * 8;
    float4 a0 = *(const float4*)rowp;
    float4 a1 = *(const float4*)(rowp + 4);
    float4 b0 = *(const float4*)(rowp + 32);
    float4 b1 = *(const float4*)(rowp + 36);
    float msum = a0.x * a0.x + a0.y * a0.y + a0.z * a0.z + a0.w * a0.w
               + a1.x * a1.x + a1.y * a1.y + a1.z * a1.z + a1.w * a1.w
               + b0.x * b0.x + b0.y * b0.y + b0.z * b0.z + b0.w * b0.w
               + b1.x * b1.x + b1.y * b1.y + b1.z * b1.z + b1.w * b1.w;
    bf16x8 Af;
    Af[0] = (short)f2b(softplusf(a0.x));
    Af[1] = (short)f2b(softplusf(a0.y));
    Af[2] = (short)f2b(softplusf(a0.z));
    Af[3] = (short)f2b(softplusf(a0.w));
    Af[4] = (short)f2b(softplusf(a1.x));
    Af[5] = (short)f2b(softplusf(a1.y));
    Af[6] = (short)f2b(softplusf(a1.z));
    Af[7] = (short)f2b(softplusf(a1.w));
    f32x4 z = {0.f, 0.f, 0.f, 0.f};
    f32x4 c0 = __builtin_amdgcn_mfma_f32_16x16x32_bf16(Af, B0, z, 0, 0, 0);
    f32x4 c1 = __builtin_amdgcn_mfma_f32_16x16x32_bf16(Af, B1, z, 0, 0, 0);
    f32x4 c2 = __builtin_amdgcn_mfma_f32_16x16x32_bf16(Af, B2, z, 0, 0, 0);
    f32x4 c3 = __builtin_amdgcn_mfma_f32_16x16x32_bf16(Af, B3, z, 0, 0, 0);
    float ksum = 0.f;
#pragma unroll
    for (int r = 0; r < 4; r++) {
      float s0 = c0[r] + lb0, s1 = c1[r] + lb1, s2 = c2[r] + lb2, s3 = c3[r] + lb3;
      ksum += -0.5f * (1.f + 2.f * s0 - __expf(2.f * s0));
      ksum += -0.5f * (1.f + 2.f * s1 - __expf(2.f * s1));
      ksum += -0.5f * (1.f + 2.f * s2 - __expf(2.f * s2));
      ksum += -0.5f * (1.f + 2.f * s3 - __expf(2.f * s3));
    }
    dsum += (double)wsum(ksum + 0.5f * msum);
  }
  if (lane == 0) red[wid] = dsum;
  __syncthreads();
  if (threadIdx.x == 0)
    atomicAdd(&accums[1], red[0] + red[1] + red[2] + red[3]);
}

__global__ __launch_bounds__(256) void k_batch_user(
    const float* __restrict__ acc, const float* __restrict__ user_emb,
    const float* __restrict__ eps, const float* __restrict__ intent,
    const float* __restrict__ lin_w, const float* __restrict__ lin_b,
    const int* __restrict__ users, const int* __restrict__ pos_items,
    const int* __restrict__ neg_items,
    float* __restrict__ gen_o, float* __restrict__ int_o,
    unsigned short* __restrict__ gen_b, unsigned short* __restrict__ int_b,
    double* __restrict__ accums) {
  __shared__ float ui[64 * 130];
  __shared__ float lw[64 * 33];
  __shared__ float lb[64];
  __shared__ double red[8];
  for (int i = threadIdx.x; i < 64 * 128; i += 256) ui[(i >> 7) * 130 + (i & 127)] = intent[i];
  for (int i = threadIdx.x; i < 64 * 32; i += 256) lw[(i >> 5) * 33 + (i & 31)] = lin_w[i];
  if (threadIdx.x < 64) lb[threadIdx.x] = lin_b[threadIdx.x];
  __syncthreads();
  int lane = threadIdx.x & 63;
  int wid = threadIdx.x >> 6;
  int b = (blockIdx.x << 2) + wid;
  int u = users[b];
  float m = acc[u * 64 + lane];
  int k0 = lane * 2;
  float l0 = 0.f, l1 = 0.f;
  for (int d = 0; d < 64; d++) {
    float md = __shfl(m, d, 64);
    l0 = fmaf(md, ui[d * 130 + k0], l0);
    l1 = fmaf(md, ui[d * 130 + k0 + 1], l1);
  }
  float mx = wmax(fmaxf(l0, l1));
  float p0 = expf(l0 - mx), p1 = expf(l1 - mx);
  float tot = wsum(p0 + p1);
  p0 /= tot; p1 /= tot;
  float s = 0.f;
  for (int k = 0; k < 128; k++) {
    float pk = __shfl((k & 1) ? p1 : p0, k >> 1, 64);
    s = fmaf(pk, ui[lane * 130 + k], s);
  }
  float nrm = sqrtf(wsum(s * s));
  float io = s / nrm;
  int_o[b * 64 + lane] = io;
  int_b[b * 64 + lane] = f2b(io);
  float sp = softplusf(m);
  float sd = lb[lane] + 1e-8f;
#pragma unroll
  for (int j = 0; j < 32; j++) sd = fmaf(__shfl(sp, j, 64), lw[lane * 33 + j], sd);
  float ge = m + eps[u * 64 + lane] * sd;
  float gn = sqrtf(wsum(ge * ge));
  float go = ge / gn;
  gen_o[b * 64 + lane] = go;
  gen_b[b * 64 + lane] = f2b(go);
  int pi = pos_items[b], ni = neg_items[b];
  float pv = acc[(NU + pi) * 64 + lane];
  float nv = acc[(NU + ni) * 64 + lane];
  float ps = wsum(m * pv);
  float ns = wsum(m * nv);
  float bpr = softplusf(ns - ps);
  float ue = user_emb[u * 64 + lane];
  float es = wsum(ue * ue);
  if (lane == 0) { red[wid] = (double)bpr; red[4 + wid] = (double)es; }
  __syncthreads();
  if (threadIdx.x == 0) {
    atomicAdd(&accums[0], red[0] + red[1] + red[2] + red[3]);
    atomicAdd(&accums[2], red[4] + red[5] + red[6] + red[7]);
  }
}

__global__ __launch_bounds__(256) void k_batch_item(
    const float* __restrict__ acc, const float* __restrict__ item_emb,
    const float* __restrict__ eps, const float* __restrict__ intent,
    const float* __restrict__ lin_w, const float* __restrict__ lin_b,
    const int* __restrict__ pos_items, const int* __restrict__ neg_items,
    float* __restrict__ gen_o, float* __restrict__ int_o,
    unsigned short* __restrict__ gen_b, unsigned short* __restrict__ int_b,
    double* __restrict__ accums) {
  __shared__ float ui[64 * 130];
  __shared__ float lw[64 * 33];
  __shared__ float lb[64];
  __shared__ double red[4];
  for (int i = threadIdx.x; i < 64 * 128; i += 256) ui[(i >> 7) * 130 + (i & 127)] = intent[i];
  for (int i = threadIdx.x; i < 64 * 32; i += 256) lw[(i >> 5) * 33 + (i & 31)] = lin_w[i];
  if (threadIdx.x < 64) lb[threadIdx.x] = lin_b[threadIdx.x];
  __syncthreads();
  int lane = threadIdx.x & 63;
  int wid = threadIdx.x >> 6;
  int b = (blockIdx.x << 2) + wid;
  int pi = pos_items[b], ni = neg_items[b];
  int row = NU + pi;
  float m = acc[row * 64 + lane];
  int k0 = lane * 2;
  float l0 = 0.f, l1 = 0.f;
  for (int d = 0; d < 64; d++) {
    float md = __shfl(m, d, 64);
    l0 = fmaf(md, ui[d * 130 + k0], l0);
    l1 = fmaf(md, ui[d * 130 + k0 + 1], l1);
  }
  float mx = wmax(fmaxf(l0, l1));
  float p0 = expf(l0 - mx), p1 = expf(l1 - mx);
  float tot = wsum(p0 + p1);
  p0 /= tot; p1 /= tot;
  float s = 0.f;
  for (int k = 0; k < 128; k++) {
    float pk = __shfl((k & 1) ? p1 : p0, k >> 1, 64);
    s = fmaf(pk, ui[lane * 130 + k], s);
  }
  float nrm = sqrtf(wsum(s * s));
  float io = s / nrm;
  int_o[b * 64 + lane] = io;
  int_b[b * 64 + lane] = f2b(io);
  float sp = softplusf(m);
  float sd = lb[lane] + 1e-8f;
#pragma unroll
  for (int j = 0; j < 32; j++) sd = fmaf(__shfl(sp, j, 64), lw[lane * 33 + j], sd);
  float ge = m + eps[row * 64 + lane] * sd;
  float gn = sqrtf(wsum(ge * ge));
  float go = ge / gn;
  gen_o[b * 64 + lane] = go;
  gen_b[b * 64 + lane] = f2b(go);
  float a0 = item_emb[pi * 64 + lane];
  float a1 = item_emb[ni * 64 + lane];
  float es = wsum(a0 * a0 + a1 * a1);
  if (lane == 0) red[wid] = (double)es;
  __syncthreads();
  if (threadIdx.x == 0) atomicAdd(&accums[2], red[0] + red[1] + red[2] + red[3]);
}

// ---------------- InfoNCE negatives via bf16 MFMA ----------------
__global__ __launch_bounds__(256) void k_nce_mfma(
    const unsigned short* __restrict__ e1u, const unsigned short* __restrict__ e2u,
    const unsigned short* __restrict__ e1i, const unsigned short* __restrict__ e2i,
    float* __restrict__ negu, float* __restrict__ negi) {
  int pair = blockIdx.y >> 2, jq = blockIdx.y & 3;
  const unsigned short* e1 = pair ? e1i : e1u;
  const unsigned short* e2 = pair ? e2i : e2u;
  float* nego = pair ? negi : negu;
  int wid = threadIdx.x >> 6, lane = threadIdx.x & 63;
  int q = lane >> 4, n = lane & 15;
  int i0 = blockIdx.x * 64 + wid * 16;
  const bf16x8* arow = (const bf16x8*)(e1 + (size_t)(i0 + n) * 64 + q * 8);
  bf16x8 a0 = arow[0];
  bf16x8 a1 = arow[4];
  f32x4 accv = {0.f, 0.f, 0.f, 0.f};
  int j0 = jq * 1024;
  for (int jt = 0; jt < 64; jt++) {
    const bf16x8* brow = (const bf16x8*)(e2 + (size_t)(j0 + jt * 16 + n) * 64 + q * 8);
    bf16x8 b0 = brow[0];
    bf16x8 b1 = brow[4];
    f32x4 c = {0.f, 0.f, 0.f, 0.f};
    c = __builtin_amdgcn_mfma_f32_16x16x32_bf16(a0, b0, c, 0, 0, 0);
    c = __builtin_amdgcn_mfma_f32_16x16x32_bf16(a1, b1, c, 0, 0, 0);
#pragma unroll
    for (int r = 0; r < 4; r++) accv[r] += __expf(5.0f * c[r]);
  }
#pragma unroll
  for (int o = 1; o < 16; o <<= 1) {
#pragma unroll
    for (int r = 0; r < 4; r++) accv[r] += __shfl_xor(accv[r], o, 64);
  }
  if (n == 0) {
#pragma unroll
    for (int r = 0; r < 4; r++) atomicAdd(&nego[i0 + q * 4 + r], accv[r]);
  }
}

__global__ __launch_bounds__(256) void k_nce_final(
    const float* __restrict__ ugen, const float* __restrict__ uio,
    const float* __restrict__ igen, const float* __restrict__ iio,
    const float* __restrict__ negu, const float* __restrict__ negi,
    double* __restrict__ accums) {
  __shared__ double red[4];
  int lane = threadIdx.x & 63, wid = threadIdx.x >> 6;
  int w = blockIdx.x * 4 + wid;
  int pair = w >> 12, i = w & 4095;
  const float* e1 = pair ? igen : ugen;
  const float* e2 = pair ? iio : uio;
  const float* ng = pair ? negi : negu;
  float dot = wsum(e1[i * 64 + lane] * e2[i * 64 + lane]);
  if (lane == 0) {
    float pos = expf(dot * 5.f);
    red[wid] = (double)(-logf(pos / (ng[i] + 1e-8f) + 1e-8f));
  }
  __syncthreads();
  if (threadIdx.x == 0) atomicAdd(&accums[4], red[0] + red[1] + red[2] + red[3]);
}

// final: also folds the tiny int_loss reduction (was k_int, saves a launch)
__global__ __launch_bounds__(256) void k_fin(const float* __restrict__ ui,
                                             const float* __restrict__ ii,
                                             const double* __restrict__ accums,
                                             float* __restrict__ out) {
  __shared__ float red[4];
  float s = 0.f;
  for (int i = threadIdx.x; i < 64 * 128; i += 256) {
    float a = ui[i], b = ii[i];
    s = fmaf(a, a, s);
    s = fmaf(b, b, s);
  }
  s = wsum(s);
  if ((threadIdx.x & 63) == 0) red[threadIdx.x >> 6] = s;
  __syncthreads();
  if (threadIdx.x == 0) {
    double ints = (double)(red[0] + red[1] + red[2] + red[3]);
    double bpr = accums[0] / (double)BB;
    double kl = 0.01 * accums[1] / (double)NT;
    out[0] = (float)(bpr + kl);
    out[1] = (float)(0.1 * accums[4] / (double)BB);
    out[2] = (float)(1e-5 * accums[2]);
    out[3] = (float)(1e-5 * ints);
  }
}

extern "C" void kernel_launch(void* const* d_in, const int* in_sizes, int n_in,
                              void* d_out, int out_size, void* d_ws, size_t ws_size,
                              hipStream_t stream) {
  const float* user_emb = (const float*)d_in[0];
  const float* item_emb = (const float*)d_in[1];
  const float* user_int = (const float*)d_in[2];
  const float* item_int = (const float*)d_in[3];
  const float* lin_w = (const float*)d_in[4];
  const float* lin_b = (const float*)d_in[5];
  const float* eps = (const float*)d_in[6];
  const int* h_list = (const int*)d_in[7];
  const int* t_list = (const int*)d_in[8];
  const int* users = (const int*)d_in[9];
  const int* pos_items = (const int*)d_in[10];
  const int* neg_items = (const int*)d_in[11];
  float* out = (float*)d_out;
  const int E = in_sizes[7];
  const size_t Ecap = (size_t)E + 16 * (size_t)NT;  // x16-padded capacity

  char* ws = (char*)d_ws;
  size_t off = 0;
  auto take = [&](size_t bytes) -> char* {
    char* p = ws + off;
    off = (off + bytes + 255) & ~(size_t)255;
    return p;
  };
  int* row_ptr = (int*)take((size_t)(NT + 1) * 4);
  float* d_inv = (float*)take((size_t)NT * 4);
  int* rloc_g = (int*)take((size_t)NT * 4);
  int* cnt_chunk = (int*)take((size_t)NBUCK * NCH * 1024 * 4);
  int* gcur = (int*)take(NBUCK * 4);
  int* btot = (int*)take(NBUCK * 4);
  int* bbase = (int*)take(NBUCK * 4);
  uint2* edges = (uint2*)take(Ecap * 8);
  unsigned* bufA = (unsigned*)take((size_t)NT * 16 * 4);  // fp8 rows (16 dwords)
  unsigned* bufB = (unsigned*)take((size_t)NT * 16 * 4);
  float* acc = (float*)take((size_t)NT * 64 * 4);
  float* ugen = (float*)take((size_t)BB * 64 * 4);
  float* igen = (float*)take((size_t)BB * 64 * 4);
  float* uio = (float*)take((size_t)BB * 64 * 4);
  float* iio = (float*)take((size_t)BB * 64 * 4);
  unsigned short* ugen_b = (unsigned short*)take((size_t)BB * 64 * 2);
  unsigned short* igen_b = (unsigned short*)take((size_t)BB * 64 * 2);
  unsigned short* uio_b = (unsigned short*)take((size_t)BB * 64 * 2);
  unsigned short* iio_b = (unsigned short*)take((size_t)BB * 64 * 2);
  float* negu = (float*)take((size_t)BB * 4);
  float* negi = (float*)take((size_t)BB * 4);
  double* accums = (double*)take(64);
  if (off > ws_size) return;
  // part[] (28.9 MB) aliases acc (38.4 MB): part's last read is k_fill2;
  // acc is first WRITTEN in k_agg#1 (first=1 -> no acc read).
  uint2* part = (uint2*)acc;

  hipMemsetAsync(gcur, 0, NBUCK * 4, stream);
  hipMemsetAsync(edges, 0, Ecap * 8, stream);  // pad slots: idx 0, g = 0
  hipMemsetAsync(negu, 0, (size_t)BB * 4, stream);
  hipMemsetAsync(negi, 0, (size_t)BB * 4, stream);
  hipMemsetAsync(accums, 0, 64, stream);

  int gridP = (E + 4095) / 4096;
  k_part<<<gridP, 256, 0, stream>>>(h_list, t_list, gcur, part, E);
  k_count2<<<dim3(NBUCK, NCH), 256, 0, stream>>>(part, gcur, cnt_chunk);
  k_node<<<NBUCK, 256, 0, stream>>>(cnt_chunk, rloc_g, d_inv, btot);
  k_csr_base<<<1, 256, 0, stream>>>(btot, bbase, row_ptr);
  k_rowptr<<<(NT + 255) / 256, 256, 0, stream>>>(bbase, rloc_g, row_ptr);
  k_fill2<<<dim3(NBUCK, NCH), 256, 0, stream>>>(part, gcur, cnt_chunk, row_ptr,
                                                d_inv, edges);

  int nU4 = NU * 16, nTot4 = NT * 16;
  k_init<<<(nTot4 + 255) / 256, 256, 0, stream>>>((const float4*)user_emb,
                                                  (const float4*)item_emb, bufA, nU4, nTot4);
  int gridAgg = NT / 4;
  k_agg<<<gridAgg, 256, 0, stream>>>(row_ptr, edges, bufA, bufB, (float4*)acc,
                                     (const float4*)user_emb, (const float4*)item_emb, 1);
  k_agg<<<gridAgg, 256, 0, stream>>>(row_ptr, edges, bufB, bufA, (float4*)acc,
                                     (const float4*)user_emb, (const float4*)item_emb, 0);
  k_agg<<<gridAgg, 256, 0, stream>>>(row_ptr, edges, bufA, bufB, (float4*)acc,
                                     (const float4*)user_emb, (const float4*)item_emb, 0);

  k_kl<<<640, 256, 0, stream>>>(acc, lin_w, lin_b, accums);
  k_batch_user<<<BB / 4, 256, 0, stream>>>(acc, user_emb, eps, user_int, lin_w, lin_b,
                                           users, pos_items, neg_items,
                                           ugen, uio, ugen_b, uio_b, accums);
  k_batch_item<<<BB / 4, 256, 0, stream>>>(acc, item_emb, eps, item_int, lin_w, lin_b,
                                           pos_items, neg_items,
                                           igen, iio, igen_b, iio_b, accums);
  k_nce_mfma<<<dim3(64, 8), 256, 0, stream>>>(ugen_b, uio_b, igen_b, iio_b, negu, negi);
  k_nce_final<<<(2 * BB) / 4, 256, 0, stream>>>(ugen, uio, igen, iio, negu, negi, accums);
  k_fin<<<1, 256, 0, stream>>>(user_int, item_int, accums, out);
}

// Round 14
// 584.105 us; speedup vs baseline: 1.3242x; 1.0036x over previous
//
#include <hip/hip_runtime.h>

#define NU 50000
#define NI 100000
#define NT 150000
#define BB 4096
#define NBUCK 147   // ceil(NT/1024)
#define BCAP 24576  // per-bucket edge capacity: mean 21504, sd ~143 -> +21 sigma
#define NCH 8       // chunks per bucket in CSR build

typedef __attribute__((ext_vector_type(8))) short bf16x8;
typedef __attribute__((ext_vector_type(4))) float f32x4;

__device__ __forceinline__ float softplusf(float x) {
  return fmaxf(x, 0.f) + log1pf(expf(-fabsf(x)));
}
__device__ __forceinline__ float wsum(float v) {
#pragma unroll
  for (int o = 32; o > 0; o >>= 1) v += __shfl_xor(v, o, 64);
  return v;
}
__device__ __forceinline__ float wmax(float v) {
#pragma unroll
  for (int o = 32; o > 0; o >>= 1) v = fmaxf(v, __shfl_xor(v, o, 64));
  return v;
}
__device__ __forceinline__ unsigned short f2b(float x) {
  unsigned u = __float_as_uint(x);
  return (unsigned short)((u + 0x7FFFu + ((u >> 16) & 1u)) >> 16);
}

// ---------------- CSR build ----------------
__global__ __launch_bounds__(256) void k_part(const int* __restrict__ h,
                                              const int* __restrict__ t,
                                              int* __restrict__ gcur,
                                              uint2* __restrict__ part, int E) {
  __shared__ int cnt[NBUCK];
  __shared__ int base[NBUCK];
  for (int b = threadIdx.x; b < NBUCK; b += 256) cnt[b] = 0;
  __syncthreads();
  int e0 = blockIdx.x * 4096 + threadIdx.x * 16;
  int nval = E - e0;
  nval = nval < 0 ? 0 : (nval > 16 ? 16 : nval);
  int hh[16], tt[16];
  if (nval == 16) {
    const int4* hp = (const int4*)(h + e0);
    const int4* tp = (const int4*)(t + e0);
#pragma unroll
    for (int j = 0; j < 4; j++) {
      int4 v = hp[j];
      hh[j * 4] = v.x; hh[j * 4 + 1] = v.y; hh[j * 4 + 2] = v.z; hh[j * 4 + 3] = v.w;
      int4 w = tp[j];
      tt[j * 4] = w.x; tt[j * 4 + 1] = w.y; tt[j * 4 + 2] = w.z; tt[j * 4 + 3] = w.w;
    }
  } else {
    for (int j = 0; j < nval; j++) { hh[j] = h[e0 + j]; tt[j] = t[e0 + j]; }
  }
  for (int j = 0; j < nval; j++) atomicAdd(&cnt[hh[j] >> 10], 1);
  __syncthreads();
  for (int b = threadIdx.x; b < NBUCK; b += 256) {
    int c = cnt[b];
    base[b] = c ? atomicAdd(&gcur[b], c) : 0;
    cnt[b] = 0;
  }
  __syncthreads();
  for (int j = 0; j < nval; j++) {
    int b = hh[j] >> 10;
    int r = atomicAdd(&cnt[b], 1);
    uint2 v; v.x = (unsigned)hh[j]; v.y = (unsigned)tt[j];
    part[(size_t)b * BCAP + base[b] + r] = v;
  }
}

// cnt_chunk layout: [(b<<10)+n][c] (node-major, chunk-minor) so k_node's
// 8-chunk loop is 32B contiguous (old [b][c][n] gave it 4KB strides on
// only 147 blocks — a serialized hidden cost).
__global__ __launch_bounds__(256) void k_count2(const uint2* __restrict__ part,
                                                const int* __restrict__ gcur,
                                                int* __restrict__ cnt_chunk) {
  __shared__ int hist[1024];
  int b = blockIdx.x, c = blockIdx.y, tid = threadIdx.x;
  for (int i = tid; i < 1024; i += 256) hist[i] = 0;
  __syncthreads();
  int m = gcur[b];
  int lo = (int)(((long long)m * c) >> 3);
  int hi = (int)(((long long)m * (c + 1)) >> 3);
  const uint2* pp = part + (size_t)b * BCAP;
  for (int i = lo + tid; i < hi; i += 256) atomicAdd(&hist[pp[i].x & 1023], 1);
  __syncthreads();
  for (int i = tid; i < 1024; i += 256)
    cnt_chunk[((((size_t)b << 10) + i) << 3) + c] = hist[i];
}

__global__ __launch_bounds__(256) void k_node(int* __restrict__ cnt_chunk,
                                              int* __restrict__ rloc_g,
                                              float* __restrict__ d_inv,
                                              int* __restrict__ btot) {
  __shared__ int sd[256];
  int b = blockIdx.x, tid = threadIdx.x;
  int n0 = b << 10;
  int pd[4];
  int s = 0;
#pragma unroll
  for (int j = 0; j < 4; j++) {
    int idx = tid * 4 + j;
    size_t base = ((size_t)(n0 + idx)) << 3;
    int run = 0;
#pragma unroll
    for (int c = 0; c < NCH; c++) {
      int v = cnt_chunk[base + c];
      cnt_chunk[base + c] = run;
      run += v;
    }
    int n = n0 + idx;
    if (n < NT) {
      d_inv[n] = 1.0f / sqrtf((float)run);  // deg >= 1 (self-loop)
      pd[j] = (run + 15) & ~15;
    } else pd[j] = 0;
    s += pd[j];
  }
  sd[tid] = s;
  __syncthreads();
  for (int o = 1; o < 256; o <<= 1) {
    int x = (tid >= o) ? sd[tid - o] : 0;
    __syncthreads();
    sd[tid] += x;
    __syncthreads();
  }
  int run2 = sd[tid] - s;
#pragma unroll
  for (int j = 0; j < 4; j++) {
    int idx = tid * 4 + j, n = n0 + idx;
    if (n < NT) rloc_g[n] = run2;
    run2 += pd[j];
  }
  if (tid == 255) btot[b] = sd[255];
}

// merged: per-block redundant scan of 147 bucket totals + row_ptr write
__global__ __launch_bounds__(256) void k_rowptr(const int* __restrict__ btot,
                                                const int* __restrict__ rloc_g,
                                                int* __restrict__ row_ptr) {
  __shared__ int sd[256];
  __shared__ int ex[256];
  int t = threadIdx.x;
  int v = (t < NBUCK) ? btot[t] : 0;
  sd[t] = v;
  __syncthreads();
  for (int o = 1; o < 256; o <<= 1) {
    int x = (t >= o) ? sd[t - o] : 0;
    __syncthreads();
    sd[t] += x;
    __syncthreads();
  }
  ex[t] = sd[t] - v;
  __syncthreads();
  int n = blockIdx.x * 256 + t;
  if (n < NT) row_ptr[n] = ex[n >> 10] + rloc_g[n];
  if (blockIdx.x == 0 && t == 0) row_ptr[NT] = sd[NBUCK - 1];
}

__global__ __launch_bounds__(256) void k_fill2(const uint2* __restrict__ part,
                                               const int* __restrict__ gcur,
                                               const int* __restrict__ chunkpre,
                                               const int* __restrict__ row_ptr,
                                               const float* __restrict__ d_inv,
                                               uint2* __restrict__ edges) {
  __shared__ int curs[1024];
  __shared__ float dl[1024];
  int b = blockIdx.x, c = blockIdx.y, tid = threadIdx.x;
  int n0 = b << 10;
  for (int i = tid; i < 1024; i += 256) {
    int n = n0 + i;
    if (n < NT) {
      curs[i] = row_ptr[n] + chunkpre[((((size_t)b << 10) + i) << 3) + c];
      dl[i] = d_inv[n];
    }
  }
  __syncthreads();
  int m = gcur[b];
  int lo = (int)(((long long)m * c) >> 3);
  int hi = (int)(((long long)m * (c + 1)) >> 3);
  const uint2* pp = part + (size_t)b * BCAP;
  for (int i = lo + tid; i < hi; i += 256) {
    uint2 pe = pp[i];
    int slot = atomicAdd(&curs[pe.x & 1023], 1);
    float g = dl[pe.x & 1023] * d_inv[pe.y];
    uint2 v; v.x = pe.y; v.y = __float_as_uint(g);
    edges[slot] = v;
  }
}

// ---------------- propagation ----------------
// cur/nxt rows: 64 fp8(e4m3) dims packed as 16 dwords -> 64B row, ONE line
// per edge, FOUR rows per wave64 dword-gather.
__global__ void k_init(const float4* __restrict__ ue, const float4* __restrict__ ie,
                       unsigned* __restrict__ cur, int nU4, int nTot4) {
  int i = blockIdx.x * 256 + threadIdx.x;
  if (i >= nTot4) return;
  float4 v = (i < nU4) ? ue[i] : ie[i - nU4];
  int p = __builtin_amdgcn_cvt_pk_fp8_f32(v.x, v.y, 0, false);
  p = __builtin_amdgcn_cvt_pk_fp8_f32(v.z, v.w, p, true);
  cur[i] = (unsigned)p;
}

// wave = 4 quarter-groups; lane = (g = edge-group 0..3, d = dword 0..15).
// Per 16-edge iteration: ONE record load (lanes 0-15 pattern, 2 line-trans)
// + 8 shfl broadcasts (idle LDS pipe) + 4 gathers = 5 vmem instrs / 18 line
// transactions (round 13: 8/20 -> 69.6us; fitted cost model predicts ~57us).
// Gathers are AT the 1-line-per-edge floor.
// Edge lists padded to x16 with (idx=0, g=0) -> branchless.
// NOTE: flat named registers only — register ARRAYS here spill (round 7).
__global__ __launch_bounds__(256) void k_agg(const int* __restrict__ row_ptr,
                                             const uint2* __restrict__ edges,
                                             const unsigned* __restrict__ cur,
                                             unsigned* __restrict__ nxt,
                                             float4* __restrict__ acc4,
                                             const float4* __restrict__ egoU,
                                             const float4* __restrict__ egoI,
                                             int first) {
  int node = (blockIdx.x << 2) + (threadIdx.x >> 6);
  unsigned lane = threadIdx.x & 63;
  unsigned d = lane & 15;
  unsigned g = lane >> 4;
  int b4 = (int)(g << 2);
  int s = row_ptr[node], e = row_ptr[node + 1];
  float a0 = 0.f, a1 = 0.f, a2 = 0.f, a3 = 0.f;
  for (int i = s; i < e; i += 16) {
    uint2 rec = edges[i + d];
    unsigned rx = rec.x, ry = rec.y;
    unsigned i0 = __shfl(rx, b4 + 0, 64); float g0 = __uint_as_float(__shfl(ry, b4 + 0, 64));
    unsigned i1 = __shfl(rx, b4 + 1, 64); float g1 = __uint_as_float(__shfl(ry, b4 + 1, 64));
    unsigned i2 = __shfl(rx, b4 + 2, 64); float g2 = __uint_as_float(__shfl(ry, b4 + 2, 64));
    unsigned i3 = __shfl(rx, b4 + 3, 64); float g3 = __uint_as_float(__shfl(ry, b4 + 3, 64));
    unsigned v0 = cur[(i0 << 4) + d];
    unsigned v1 = cur[(i1 << 4) + d];
    unsigned v2 = cur[(i2 << 4) + d];
    unsigned v3 = cur[(i3 << 4) + d];
    a0 = fmaf(g0, __builtin_amdgcn_cvt_f32_fp8(v0, 0), a0);
    a1 = fmaf(g0, __builtin_amdgcn_cvt_f32_fp8(v0, 1), a1);
    a2 = fmaf(g0, __builtin_amdgcn_cvt_f32_fp8(v0, 2), a2);
    a3 = fmaf(g0, __builtin_amdgcn_cvt_f32_fp8(v0, 3), a3);
    a0 = fmaf(g1, __builtin_amdgcn_cvt_f32_fp8(v1, 0), a0);
    a1 = fmaf(g1, __builtin_amdgcn_cvt_f32_fp8(v1, 1), a1);
    a2 = fmaf(g1, __builtin_amdgcn_cvt_f32_fp8(v1, 2), a2);
    a3 = fmaf(g1, __builtin_amdgcn_cvt_f32_fp8(v1, 3), a3);
    a0 = fmaf(g2, __builtin_amdgcn_cvt_f32_fp8(v2, 0), a0);
    a1 = fmaf(g2, __builtin_amdgcn_cvt_f32_fp8(v2, 1), a1);
    a2 = fmaf(g2, __builtin_amdgcn_cvt_f32_fp8(v2, 2), a2);
    a3 = fmaf(g2, __builtin_amdgcn_cvt_f32_fp8(v2, 3), a3);
    a0 = fmaf(g3, __builtin_amdgcn_cvt_f32_fp8(v3, 0), a0);
    a1 = fmaf(g3, __builtin_amdgcn_cvt_f32_fp8(v3, 1), a1);
    a2 = fmaf(g3, __builtin_amdgcn_cvt_f32_fp8(v3, 2), a2);
    a3 = fmaf(g3, __builtin_amdgcn_cvt_f32_fp8(v3, 3), a3);
  }
  a0 += __shfl_xor(a0, 16, 64);
  a1 += __shfl_xor(a1, 16, 64);
  a2 += __shfl_xor(a2, 16, 64);
  a3 += __shfl_xor(a3, 16, 64);
  a0 += __shfl_xor(a0, 32, 64);
  a1 += __shfl_xor(a1, 32, 64);
  a2 += __shfl_xor(a2, 32, 64);
  a3 += __shfl_xor(a3, 32, 64);
  unsigned ro = ((unsigned)node << 4) + d;
  if (g == 0) {
    float4 base;
    if (first) {
      base = (node < NU) ? egoU[ro] : egoI[ro - (unsigned)NU * 16u];
    } else {
      base = acc4[ro];
    }
    base.x += a0;
    base.y += a1;
    base.z += a2;
    base.w += a3;
    acc4[ro] = base;
  } else if (g == 1) {
    int p = __builtin_amdgcn_cvt_pk_fp8_f32(a0, a1, 0, false);
    p = __builtin_amdgcn_cvt_pk_fp8_f32(a2, a3, p, true);
    nxt[ro] = (unsigned)p;
  }
}

// ---------------- losses ----------------
// KL via MFMA; grid-stride + one atomic per block (round 11: per-wave
// same-address double atomics serialized at ~31 cy = 121 us wall).
__global__ __launch_bounds__(256) void k_kl(const float* __restrict__ acc,
                                            const float* __restrict__ lin_w,
                                            const float* __restrict__ lin_b,
                                            double* __restrict__ accums) {
  __shared__ double red[4];
  int lane = threadIdx.x & 63;
  int wid = threadIdx.x >> 6;
  int n = lane & 15, q = lane >> 4;
  bf16x8 B0, B1, B2, B3;
  float lb0, lb1, lb2, lb3;
  {
    const float* w0 = lin_w + (0 * 16 + n) * 32 + q * 8;
    const float* w1 = lin_w + (1 * 16 + n) * 32 + q * 8;
    const float* w2 = lin_w + (2 * 16 + n) * 32 + q * 8;
    const float* w3 = lin_w + (3 * 16 + n) * 32 + q * 8;
#pragma unroll
    for (int j = 0; j < 8; j++) {
      B0[j] = (short)f2b(w0[j]);
      B1[j] = (short)f2b(w1[j]);
      B2[j] = (short)f2b(w2[j]);
      B3[j] = (short)f2b(w3[j]);
    }
    lb0 = lin_b[0 * 16 + n] + 1e-8f;
    lb1 = lin_b[1 * 16 + n] + 1e-8f;
    lb2 = lin_b[2 * 16 + n] + 1e-8f;
    lb3 = lin_b[3 * 16 + n] + 1e-8f;
  }
  const int TI = NT / 16;
  int w0id = blockIdx.x * 4 + wid;
  int nwv = gridDim.x * 4;
  double dsum = 0.0;
  for (int tile = w0id; tile < TI; tile += nwv) {
    const float* rowp = acc + (size_t)(tile * 16 + n) * 64 + q * 8;
    float4 a0 = *(const float4*)rowp;
    float4 a1 = *(const float4*)(rowp + 4);
    float4 b0 = *(const float4*)(rowp + 32);
    float4 b1 = *(const float4*)(rowp + 36);
    float msum = a0.x * a0.x + a0.y * a0.y + a0.z * a0.z + a0.w * a0.w
               + a1.x * a1.x + a1.y * a1.y + a1.z * a1.z + a1.w * a1.w
               + b0.x * b0.x + b0.y * b0.y + b0.z * b0.z + b0.w * b0.w
               + b1.x * b1.x + b1.y * b1.y + b1.z * b1.z + b1.w * b1.w;
    bf16x8 Af;
    Af[0] = (short)f2b(softplusf(a0.x));
    Af[1] = (short)f2b(softplusf(a0.y));
    Af[2] = (short)f2b(softplusf(a0.z));
    Af[3] = (short)f2b(softplusf(a0.w));
    Af[4] = (short)f2b(softplusf(a1.x));
    Af[5] = (short)f2b(softplusf(a1.y));
    Af[6] = (short)f2b(softplusf(a1.z));
    Af[7] = (short)f2b(softplusf(a1.w));
    f32x4 z = {0.f, 0.f, 0.f, 0.f};
    f32x4 c0 = __builtin_amdgcn_mfma_f32_16x16x32_bf16(Af, B0, z, 0, 0, 0);
    f32x4 c1 = __builtin_amdgcn_mfma_f32_16x16x32_bf16(Af, B1, z, 0, 0, 0);
    f32x4 c2 = __builtin_amdgcn_mfma_f32_16x16x32_bf16(Af, B2, z, 0, 0, 0);
    f32x4 c3 = __builtin_amdgcn_mfma_f32_16x16x32_bf16(Af, B3, z, 0, 0, 0);
    float ksum = 0.f;
#pragma unroll
    for (int r = 0; r < 4; r++) {
      float s0 = c0[r] + lb0, s1 = c1[r] + lb1, s2 = c2[r] + lb2, s3 = c3[r] + lb3;
      ksum += -0.5f * (1.f + 2.f * s0 - __expf(2.f * s0));
      ksum += -0.5f * (1.f + 2.f * s1 - __expf(2.f * s1));
      ksum += -0.5f * (1.f + 2.f * s2 - __expf(2.f * s2));
      ksum += -0.5f * (1.f + 2.f * s3 - __expf(2.f * s3));
    }
    dsum += (double)wsum(ksum + 0.5f * msum);
  }
  if (lane == 0) red[wid] = dsum;
  __syncthreads();
  if (threadIdx.x == 0)
    atomicAdd(&accums[1], red[0] + red[1] + red[2] + red[3]);
}

__global__ __launch_bounds__(256) void k_batch_user(
    const float* __restrict__ acc, const float* __restrict__ user_emb,
    const float* __restrict__ eps, const float* __restrict__ intent,
    const float* __restrict__ lin_w, const float* __restrict__ lin_b,
    const int* __restrict__ users, const int* __restrict__ pos_items,
    const int* __restrict__ neg_items,
    float* __restrict__ gen_o, float* __restrict__ int_o,
    unsigned short* __restrict__ gen_b, unsigned short* __restrict__ int_b,
    double* __restrict__ accums) {
  __shared__ float ui[64 * 130];
  __shared__ float lw[64 * 33];
  __shared__ float lb[64];
  __shared__ double red[8];
  for (int i = threadIdx.x; i < 64 * 128; i += 256) ui[(i >> 7) * 130 + (i & 127)] = intent[i];
  for (int i = threadIdx.x; i < 64 * 32; i += 256) lw[(i >> 5) * 33 + (i & 31)] = lin_w[i];
  if (threadIdx.x < 64) lb[threadIdx.x] = lin_b[threadIdx.x];
  __syncthreads();
  int lane = threadIdx.x & 63;
  int wid = threadIdx.x >> 6;
  int b = (blockIdx.x << 2) + wid;
  int u = users[b];
  float m = acc[u * 64 + lane];
  int k0 = lane * 2;
  float l0 = 0.f, l1 = 0.f;
  for (int d = 0; d < 64; d++) {
    float md = __shfl(m, d, 64);
    l0 = fmaf(md, ui[d * 130 + k0], l0);
    l1 = fmaf(md, ui[d * 130 + k0 + 1], l1);
  }
  float mx = wmax(fmaxf(l0, l1));
  float p0 = expf(l0 - mx), p1 = expf(l1 - mx);
  float tot = wsum(p0 + p1);
  p0 /= tot; p1 /= tot;
  float s = 0.f;
  for (int k = 0; k < 128; k++) {
    float pk = __shfl((k & 1) ? p1 : p0, k >> 1, 64);
    s = fmaf(pk, ui[lane * 130 + k], s);
  }
  float nrm = sqrtf(wsum(s * s));
  float io = s / nrm;
  int_o[b * 64 + lane] = io;
  int_b[b * 64 + lane] = f2b(io);
  float sp = softplusf(m);
  float sd = lb[lane] + 1e-8f;
#pragma unroll
  for (int j = 0; j < 32; j++) sd = fmaf(__shfl(sp, j, 64), lw[lane * 33 + j], sd);
  float ge = m + eps[u * 64 + lane] * sd;
  float gn = sqrtf(wsum(ge * ge));
  float go = ge / gn;
  gen_o[b * 64 + lane] = go;
  gen_b[b * 64 + lane] = f2b(go);
  int pi = pos_items[b], ni = neg_items[b];
  float pv = acc[(NU + pi) * 64 + lane];
  float nv = acc[(NU + ni) * 64 + lane];
  float ps = wsum(m * pv);
  float ns = wsum(m * nv);
  float bpr = softplusf(ns - ps);
  float ue = user_emb[u * 64 + lane];
  float es = wsum(ue * ue);
  if (lane == 0) { red[wid] = (double)bpr; red[4 + wid] = (double)es; }
  __syncthreads();
  if (threadIdx.x == 0) {
    atomicAdd(&accums[0], red[0] + red[1] + red[2] + red[3]);
    atomicAdd(&accums[2], red[4] + red[5] + red[6] + red[7]);
  }
}

__global__ __launch_bounds__(256) void k_batch_item(
    const float* __restrict__ acc, const float* __restrict__ item_emb,
    const float* __restrict__ eps, const float* __restrict__ intent,
    const float* __restrict__ lin_w, const float* __restrict__ lin_b,
    const int* __restrict__ pos_items, const int* __restrict__ neg_items,
    float* __restrict__ gen_o, float* __restrict__ int_o,
    unsigned short* __restrict__ gen_b, unsigned short* __restrict__ int_b,
    double* __restrict__ accums) {
  __shared__ float ui[64 * 130];
  __shared__ float lw[64 * 33];
  __shared__ float lb[64];
  __shared__ double red[4];
  for (int i = threadIdx.x; i < 64 * 128; i += 256) ui[(i >> 7) * 130 + (i & 127)] = intent[i];
  for (int i = threadIdx.x; i < 64 * 32; i += 256) lw[(i >> 5) * 33 + (i & 31)] = lin_w[i];
  if (threadIdx.x < 64) lb[threadIdx.x] = lin_b[threadIdx.x];
  __syncthreads();
  int lane = threadIdx.x & 63;
  int wid = threadIdx.x >> 6;
  int b = (blockIdx.x << 2) + wid;
  int pi = pos_items[b], ni = neg_items[b];
  int row = NU + pi;
  float m = acc[row * 64 + lane];
  int k0 = lane * 2;
  float l0 = 0.f, l1 = 0.f;
  for (int d = 0; d < 64; d++) {
    float md = __shfl(m, d, 64);
    l0 = fmaf(md, ui[d * 130 + k0], l0);
    l1 = fmaf(md, ui[d * 130 + k0 + 1], l1);
  }
  float mx = wmax(fmaxf(l0, l1));
  float p0 = expf(l0 - mx), p1 = expf(l1 - mx);
  float tot = wsum(p0 + p1);
  p0 /= tot; p1 /= tot;
  float s = 0.f;
  for (int k = 0; k < 128; k++) {
    float pk = __shfl((k & 1) ? p1 : p0, k >> 1, 64);
    s = fmaf(pk, ui[lane * 130 + k], s);
  }
  float nrm = sqrtf(wsum(s * s));
  float io = s / nrm;
  int_o[b * 64 + lane] = io;
  int_b[b * 64 + lane] = f2b(io);
  float sp = softplusf(m);
  float sd = lb[lane] + 1e-8f;
#pragma unroll
  for (int j = 0; j < 32; j++) sd = fmaf(__shfl(sp, j, 64), lw[lane * 33 + j], sd);
  float ge = m + eps[row * 64 + lane] * sd;
  float gn = sqrtf(wsum(ge * ge));
  float go = ge / gn;
  gen_o[b * 64 + lane] = go;
  gen_b[b * 64 + lane] = f2b(go);
  float a0 = item_emb[pi * 64 + lane];
  float a1 = item_emb[ni * 64 + lane];
  float es = wsum(a0 * a0 + a1 * a1);
  if (lane == 0) red[wid] = (double)es;
  __syncthreads();
  if (threadIdx.x == 0) atomicAdd(&accums[2], red[0] + red[1] + red[2] + red[3]);
}

// ---------------- InfoNCE negatives via bf16 MFMA ----------------
__global__ __launch_bounds__(256) void k_nce_mfma(
    const unsigned short* __restrict__ e1u, const unsigned short* __restrict__ e2u,
    const unsigned short* __restrict__ e1i, const unsigned short* __restrict__ e2i,
    float* __restrict__ negu, float* __restrict__ negi) {
  int pair = blockIdx.y >> 2, jq = blockIdx.y & 3;
  const unsigned short* e1 = pair ? e1i : e1u;
  const unsigned short* e2 = pair ? e2i : e2u;
  float* nego = pair ? negi : negu;
  int wid = threadIdx.x >> 6, lane = threadIdx.x & 63;
  int q = lane >> 4, n = lane & 15;
  int i0 = blockIdx.x * 64 + wid * 16;
  const bf16x8* arow = (const bf16x8*)(e1 + (size_t)(i0 + n) * 64 + q * 8);
  bf16x8 a0 = arow[0];
  bf16x8 a1 = arow[4];
  f32x4 accv = {0.f, 0.f, 0.f, 0.f};
  int j0 = jq * 1024;
  for (int jt = 0; jt < 64; jt++) {
    const bf16x8* brow = (const bf16x8*)(e2 + (size_t)(j0 + jt * 16 + n) * 64 + q * 8);
    bf16x8 b0 = brow[0];
    bf16x8 b1 = brow[4];
    f32x4 c = {0.f, 0.f, 0.f, 0.f};
    c = __builtin_amdgcn_mfma_f32_16x16x32_bf16(a0, b0, c, 0, 0, 0);
    c = __builtin_amdgcn_mfma_f32_16x16x32_bf16(a1, b1, c, 0, 0, 0);
#pragma unroll
    for (int r = 0; r < 4; r++) accv[r] += __expf(5.0f * c[r]);
  }
#pragma unroll
  for (int o = 1; o < 16; o <<= 1) {
#pragma unroll
    for (int r = 0; r < 4; r++) accv[r] += __shfl_xor(accv[r], o, 64);
  }
  if (n == 0) {
#pragma unroll
    for (int r = 0; r < 4; r++) atomicAdd(&nego[i0 + q * 4 + r], accv[r]);
  }
}

__global__ __launch_bounds__(256) void k_nce_final(
    const float* __restrict__ ugen, const float* __restrict__ uio,
    const float* __restrict__ igen, const float* __restrict__ iio,
    const float* __restrict__ negu, const float* __restrict__ negi,
    double* __restrict__ accums) {
  __shared__ double red[4];
  int lane = threadIdx.x & 63, wid = threadIdx.x >> 6;
  int w = blockIdx.x * 4 + wid;
  int pair = w >> 12, i = w & 4095;
  const float* e1 = pair ? igen : ugen;
  const float* e2 = pair ? iio : uio;
  const float* ng = pair ? negi : negu;
  float dot = wsum(e1[i * 64 + lane] * e2[i * 64 + lane]);
  if (lane == 0) {
    float pos = expf(dot * 5.f);
    red[wid] = (double)(-logf(pos / (ng[i] + 1e-8f) + 1e-8f));
  }
  __syncthreads();
  if (threadIdx.x == 0) atomicAdd(&accums[4], red[0] + red[1] + red[2] + red[3]);
}

// final: also folds the tiny int_loss reduction
__global__ __launch_bounds__(256) void k_fin(const float* __restrict__ ui,
                                             const float* __restrict__ ii,
                                             const double* __restrict__ accums,
                                             float* __restrict__ out) {
  __shared__ float red[4];
  float s = 0.f;
  for (int i = threadIdx.x; i < 64 * 128; i += 256) {
    float a = ui[i], b = ii[i];
    s = fmaf(a, a, s);
    s = fmaf(b, b, s);
  }
  s = wsum(s);
  if ((threadIdx.x & 63) == 0) red[threadIdx.x >> 6] = s;
  __syncthreads();
  if (threadIdx.x == 0) {
    double ints = (double)(red[0] + red[1] + red[2] + red[3]);
    double bpr = accums[0] / (double)BB;
    double kl = 0.01 * accums[1] / (double)NT;
    out[0] = (float)(bpr + kl);
    out[1] = (float)(0.1 * accums[4] / (double)BB);
    out[2] = (float)(1e-5 * accums[2]);
    out[3] = (float)(1e-5 * ints);
  }
}

extern "C" void kernel_launch(void* const* d_in, const int* in_sizes, int n_in,
                              void* d_out, int out_size, void* d_ws, size_t ws_size,
                              hipStream_t stream) {
  const float* user_emb = (const float*)d_in[0];
  const float* item_emb = (const float*)d_in[1];
  const float* user_int = (const float*)d_in[2];
  const float* item_int = (const float*)d_in[3];
  const float* lin_w = (const float*)d_in[4];
  const float* lin_b = (const float*)d_in[5];
  const float* eps = (const float*)d_in[6];
  const int* h_list = (const int*)d_in[7];
  const int* t_list = (const int*)d_in[8];
  const int* users = (const int*)d_in[9];
  const int* pos_items = (const int*)d_in[10];
  const int* neg_items = (const int*)d_in[11];
  float* out = (float*)d_out;
  const int E = in_sizes[7];
  const size_t Ecap = (size_t)E + 16 * (size_t)NT;  // x16-padded capacity

  char* ws = (char*)d_ws;
  size_t off = 0;
  auto take = [&](size_t bytes) -> char* {
    char* p = ws + off;
    off = (off + bytes + 255) & ~(size_t)255;
    return p;
  };
  int* row_ptr = (int*)take((size_t)(NT + 1) * 4);
  float* d_inv = (float*)take((size_t)NT * 4);
  int* rloc_g = (int*)take((size_t)NT * 4);
  int* cnt_chunk = (int*)take((size_t)NBUCK * NCH * 1024 * 4);
  int* gcur = (int*)take(NBUCK * 4);
  int* btot = (int*)take(NBUCK * 4);
  uint2* edges = (uint2*)take(Ecap * 8);
  unsigned* bufA = (unsigned*)take((size_t)NT * 16 * 4);  // fp8 rows (16 dwords)
  unsigned* bufB = (unsigned*)take((size_t)NT * 16 * 4);
  float* acc = (float*)take((size_t)NT * 64 * 4);
  float* ugen = (float*)take((size_t)BB * 64 * 4);
  float* igen = (float*)take((size_t)BB * 64 * 4);
  float* uio = (float*)take((size_t)BB * 64 * 4);
  float* iio = (float*)take((size_t)BB * 64 * 4);
  unsigned short* ugen_b = (unsigned short*)take((size_t)BB * 64 * 2);
  unsigned short* igen_b = (unsigned short*)take((size_t)BB * 64 * 2);
  unsigned short* uio_b = (unsigned short*)take((size_t)BB * 64 * 2);
  unsigned short* iio_b = (unsigned short*)take((size_t)BB * 64 * 2);
  float* negu = (float*)take((size_t)BB * 4);
  float* negi = (float*)take((size_t)BB * 4);
  double* accums = (double*)take(64);
  if (off > ws_size) return;
  // part[] (28.9 MB) aliases acc (38.4 MB): part's last read is k_fill2;
  // acc is first WRITTEN in k_agg#1 (first=1 -> no acc read).
  uint2* part = (uint2*)acc;

  hipMemsetAsync(gcur, 0, NBUCK * 4, stream);
  hipMemsetAsync(edges, 0, Ecap * 8, stream);  // pad slots: idx 0, g = 0
  hipMemsetAsync(negu, 0, (size_t)BB * 4, stream);
  hipMemsetAsync(negi, 0, (size_t)BB * 4, stream);
  hipMemsetAsync(accums, 0, 64, stream);

  int gridP = (E + 4095) / 4096;
  k_part<<<gridP, 256, 0, stream>>>(h_list, t_list, gcur, part, E);
  k_count2<<<dim3(NBUCK, NCH), 256, 0, stream>>>(part, gcur, cnt_chunk);
  k_node<<<NBUCK, 256, 0, stream>>>(cnt_chunk, rloc_g, d_inv, btot);
  k_rowptr<<<(NT + 255) / 256, 256, 0, stream>>>(btot, rloc_g, row_ptr);
  k_fill2<<<dim3(NBUCK, NCH), 256, 0, stream>>>(part, gcur, cnt_chunk, row_ptr,
                                                d_inv, edges);

  int nU4 = NU * 16, nTot4 = NT * 16;
  k_init<<<(nTot4 + 255) / 256, 256, 0, stream>>>((const float4*)user_emb,
                                                  (const float4*)item_emb, bufA, nU4, nTot4);
  int gridAgg = NT / 4;
  k_agg<<<gridAgg, 256, 0, stream>>>(row_ptr, edges, bufA, bufB, (float4*)acc,
                                     (const float4*)user_emb, (const float4*)item_emb, 1);
  k_agg<<<gridAgg, 256, 0, stream>>>(row_ptr, edges, bufB, bufA, (float4*)acc,
                                     (const float4*)user_emb, (const float4*)item_emb, 0);
  k_agg<<<gridAgg, 256, 0, stream>>>(row_ptr, edges, bufA, bufB, (float4*)acc,
                                     (const float4*)user_emb, (const float4*)item_emb, 0);

  k_kl<<<640, 256, 0, stream>>>(acc, lin_w, lin_b, accums);
  k_batch_user<<<BB / 4, 256, 0, stream>>>(acc, user_emb, eps, user_int, lin_w, lin_b,
                                           users, pos_items, neg_items,
                                           ugen, uio, ugen_b, uio_b, accums);
  k_batch_item<<<BB / 4, 256, 0, stream>>>(acc, item_emb, eps, item_int, lin_w, lin_b,
                                           pos_items, neg_items,
                                           igen, iio, igen_b, iio_b, accums);
  k_nce_mfma<<<dim3(64, 8), 256, 0, stream>>>(ugen_b, uio_b, igen_b, iio_b, negu, negi);
  k_nce_final<<<(2 * BB) / 4, 256, 0, stream>>>(ugen, uio, igen, iio, negu, negi, accums);
  k_fin<<<1, 256, 0, stream>>>(user_int, item_int, accums, out);
}